// Round 6
// baseline (7867.841 us; speedup 1.0000x reference)
//
#include <hip/hip_runtime.h>
#include <hip/hip_bf16.h>

#define B_    8
#define NG    16906
#define KSEL  2048
#define D_    256
#define H_    8
#define DH    32
#define M_    110
#define DEPTH_ 6
#define DFF_  1024
#define N_    2049
#define BN_   (B_*N_)
#define CTXN  (64*M_*33)

static constexpr float DN    = 0.42044820762685725f;  // 32^-0.25
static constexpr float DN2   = 0.17677669529663687f;  // 32^-0.5
static constexpr float RATIO = 0.09534625892455922f;  // 110^-0.5

__device__ __forceinline__ unsigned floatToOrdered(float f){
  unsigned b = __float_as_uint(f);
  return (b & 0x80000000u) ? ~b : (b | 0x80000000u);
}
__device__ __forceinline__ float orderedToFloat(unsigned u){
  unsigned b = (u & 0x80000000u) ? (u & 0x7FFFFFFFu) : ~u;
  return __uint_as_float(b);
}

// ---------------- top-k (radix select on float bits; all inputs >= 0) ----------------
__global__ __launch_bounds__(256) void topk_k(const float* __restrict__ expr,
                                              float* __restrict__ selected)
{
  __shared__ unsigned hist[256];
  __shared__ unsigned sPrefix;
  __shared__ int sKK;
  __shared__ unsigned cGT, cEQ;
  int b = blockIdx.x, tid = threadIdx.x;
  const float* row = expr + (long)b*NG;
  if (tid == 0){ sPrefix = 0u; sKK = KSEL; }
  __syncthreads();
  for (int pass = 0; pass < 4; ++pass){
    int shift = 24 - pass*8;
    hist[tid] = 0u;
    __syncthreads();
    unsigned pref = sPrefix;
    for (int i = tid; i < NG; i += 256){
      unsigned bits = __float_as_uint(row[i]);
      bool ok = (pass == 0) || ((bits >> (shift + 8)) == pref);
      if (ok) atomicAdd(&hist[(bits >> shift) & 255u], 1u);
    }
    __syncthreads();
    if (tid == 0){
      int kk = sKK; unsigned cum = 0; int sel = 0;
      for (int j = 255; j >= 0; --j){
        unsigned c = hist[j];
        if (cum + c >= (unsigned)kk){ sel = j; break; }
        cum += c;
      }
      sPrefix = (pref << 8) | (unsigned)sel;
      sKK = kk - (int)cum;
    }
    __syncthreads();
  }
  unsigned T = sPrefix; int needEQ = sKK; int base = KSEL - needEQ;
  if (tid == 0){ cGT = 0u; cEQ = 0u; }
  __syncthreads();
  for (int i = tid; i < NG; i += 256){
    float v = row[i];
    unsigned bits = __float_as_uint(v);
    if (bits > T){
      unsigned p = atomicAdd(&cGT, 1u);
      selected[(long)b*KSEL + p] = v;
    } else if (bits == T){
      unsigned p = atomicAdd(&cEQ, 1u);
      if ((int)p < needEQ) selected[(long)b*KSEL + base + p] = v;
    }
  }
}

// ---------------- per-batch sum + max of selected ----------------
__global__ __launch_bounds__(256) void nsum_k(const float* __restrict__ selected,
                                              float* __restrict__ bsum, float* __restrict__ bv0)
{
  __shared__ float rs[256], rm[256];
  int b = blockIdx.x, tid = threadIdx.x;
  float s = 0.f, m = -INFINITY;
  for (int i = tid; i < KSEL; i += 256){ float v = selected[(long)b*KSEL + i]; s += v; m = fmaxf(m, v); }
  rs[tid] = s; rm[tid] = m; __syncthreads();
  for (int k = 128; k > 0; k >>= 1){
    if (tid < k){ rs[tid] += rs[tid + k]; rm[tid] = fmaxf(rm[tid], rm[tid + k]); }
    __syncthreads();
  }
  if (tid == 0){ bsum[b] = rs[0]; bv0[b] = rm[0]; }
}

// ---------------- global max of e = log1p(v0/sum*1e4) ----------------
__global__ __launch_bounds__(64) void emax_k(const float* __restrict__ bsum,
                                             const float* __restrict__ bv0,
                                             float* __restrict__ emaxp)
{
  int tid = threadIdx.x;
  float e = -INFINITY;
  if (tid < B_) e = log1pf(bv0[tid] / fmaxf(bsum[tid], 1e-12f) * 10000.0f);
  #pragma unroll
  for (int m = 1; m < 64; m <<= 1) e = fmaxf(e, __shfl_xor(e, m));
  if (tid == 0) emaxp[0] = e;
}

// ---------------- tokenize + embed ----------------
__global__ __launch_bounds__(64) void embed_k(const float* __restrict__ selected,
    const float* __restrict__ bsum, const float* __restrict__ emaxp,
    const float* __restrict__ temb, const float* __restrict__ cls,
    float* __restrict__ x)
{
  int rowi = blockIdx.x;
  int b = rowi / N_, n = rowi % N_;
  int tid = threadIdx.x;
  const float* src;
  if (n == 0){
    src = cls;
  } else {
    float val = selected[(long)b*KSEL + (n - 1)];
    float e = log1pf(val / fmaxf(bsum[b], 1e-12f) * 10000.0f);
    float step = emaxp[0] / 7.0f;              // matches jnp.linspace step
    int cnt = 0;
    #pragma unroll
    for (int i = 0; i < 7; i++) cnt += (((float)i * step) < e) ? 1 : 0;  // searchsorted 'left'
    int tok = cnt > 6 ? 6 : cnt;
    src = temb + (long)tok * D_;
  }
  float4 o = *(const float4*)(src + tid*4);
  *(float4*)(x + (long)rowi*D_ + tid*4) = o;
}

// ---------------- LayerNorm: one wave per row ----------------
__global__ __launch_bounds__(256) void ln_k(const float* __restrict__ x, float* __restrict__ out,
    const float* __restrict__ g, const float* __restrict__ bb)
{
  int row = blockIdx.x*4 + (threadIdx.x >> 6);
  int lane = threadIdx.x & 63;
  float4 v = *(const float4*)(x + (long)row*D_ + lane*4);
  float s = v.x + v.y + v.z + v.w;
  float q = v.x*v.x + v.y*v.y + v.z*v.z + v.w*v.w;
  #pragma unroll
  for (int m = 1; m < 64; m <<= 1){ s += __shfl_xor(s, m); q += __shfl_xor(q, m); }
  float mu  = s * (1.0f/D_);
  float var = q * (1.0f/D_) - mu*mu;
  float inv = 1.0f / sqrtf(fmaxf(var, 0.f) + 1e-5f);
  float4 gu = *(const float4*)(g + lane*4);
  float4 bu = *(const float4*)(bb + lane*4);
  float4 o;
  o.x = (v.x - mu)*inv*gu.x + bu.x;
  o.y = (v.y - mu)*inv*gu.y + bu.y;
  o.z = (v.z - mu)*inv*gu.z + bu.z;
  o.w = (v.w - mu)*inv*gu.w + bu.w;
  *(float4*)(out + (long)row*D_ + lane*4) = o;
}

// ---------------- generic tiled fp32 GEMM: C = act(A@Bw + bias) [+ res] ----------------
// ACT: 0=none, 1=gelu-exact. RES: add res.
// B element (k, col) at Bw[k*ldb + col]; C row stride = Nn.
template<int ACT, int RES>
__global__ __launch_bounds__(256) void gemm_k(
    const float* __restrict__ A, long lda,
    const float* __restrict__ Bw, long ldb,
    const float* __restrict__ bias,
    const float* __restrict__ res,
    float* __restrict__ Cf,
    int M, int Nn, int K)
{
  __shared__ float As[16][64];
  __shared__ float Bs[16][64];
  int tid = threadIdx.x;
  int tx = tid & 15, ty = tid >> 4;
  int rowBlk = blockIdx.x * 64, colBlk = blockIdx.y * 64;
  int am = tid >> 2, ak = (tid & 3) * 4;
  int bk = tid >> 4, bc = (tid & 15) * 4;
  float acc[4][4];
  #pragma unroll
  for (int i = 0; i < 4; i++)
    #pragma unroll
    for (int j = 0; j < 4; j++) acc[i][j] = 0.f;

  for (int kt = 0; kt < K; kt += 16){
    float4 av = make_float4(0.f, 0.f, 0.f, 0.f);
    int ar = rowBlk + am;
    if (ar < M) av = *(const float4*)(A + (long)ar*lda + kt + ak);
    As[ak+0][am] = av.x; As[ak+1][am] = av.y; As[ak+2][am] = av.z; As[ak+3][am] = av.w;
    float4 bv4 = *(const float4*)(Bw + (long)(kt + bk)*ldb + colBlk + bc);
    Bs[bk][bc+0] = bv4.x; Bs[bk][bc+1] = bv4.y;
    Bs[bk][bc+2] = bv4.z; Bs[bk][bc+3] = bv4.w;
    __syncthreads();
    #pragma unroll
    for (int kk = 0; kk < 16; kk++){
      float4 a4 = *(const float4*)&As[kk][ty*4];
      float4 b4 = *(const float4*)&Bs[kk][tx*4];
      acc[0][0] += a4.x*b4.x; acc[0][1] += a4.x*b4.y; acc[0][2] += a4.x*b4.z; acc[0][3] += a4.x*b4.w;
      acc[1][0] += a4.y*b4.x; acc[1][1] += a4.y*b4.y; acc[1][2] += a4.y*b4.z; acc[1][3] += a4.y*b4.w;
      acc[2][0] += a4.z*b4.x; acc[2][1] += a4.z*b4.y; acc[2][2] += a4.z*b4.z; acc[2][3] += a4.z*b4.w;
      acc[3][0] += a4.w*b4.x; acc[3][1] += a4.w*b4.y; acc[3][2] += a4.w*b4.z; acc[3][3] += a4.w*b4.w;
    }
    __syncthreads();
  }
  int r0 = rowBlk + ty*4, c0 = colBlk + tx*4;
  float bz[4];
  #pragma unroll
  for (int j = 0; j < 4; j++) bz[j] = bias[c0 + j];
  #pragma unroll
  for (int i = 0; i < 4; i++){
    int r = r0 + i;
    if (r < M){
      #pragma unroll
      for (int j = 0; j < 4; j++){
        float c = acc[i][j] + bz[j];
        if (ACT == 1) c = 0.5f * c * (1.0f + erff(c * 0.70710678118654752f));
        if (RES) c += res[(long)r*Nn + c0 + j];
        Cf[(long)r*Nn + c0 + j] = c;
      }
    }
  }
}

// ---------------- per-layer zero: kmax + ctx accumulator ----------------
__global__ __launch_bounds__(256) void zeroctx_k(float* __restrict__ ctxf,
                                                 unsigned* __restrict__ kmaxb)
{
  int i = blockIdx.x*256 + threadIdx.x;
  if (i == 0) kmaxb[0] = 0u;
  if (i < CTXN) ctxf[i] = 0.f;
}

__global__ __launch_bounds__(256) void zerob_k(float* __restrict__ zbias)
{
  zbias[threadIdx.x] = 0.f;
}

// ---------------- attention: global key-stab max ----------------
__global__ __launch_bounds__(256) void kmax_k(const float* __restrict__ kb,
    const float* __restrict__ proj, unsigned* __restrict__ kmaxb)
{
  __shared__ float projs[M_*33];
  __shared__ float red[256];
  int c = blockIdx.x, h = blockIdx.y, b = blockIdx.z;
  int tid = threadIdx.x;
  for (int i = tid; i < M_*33; i += 256){
    int m = i / 33, d = i - m*33;
    projs[i] = (d < 32) ? proj[m*32 + d] : 0.f;
  }
  __syncthreads();
  float mx = -INFINITY;
  int n0 = c * 228;
  for (int it = tid; it < 228*M_; it += 256){
    int dn_ = it / M_; int m = it - dn_*M_;
    int n = n0 + dn_;
    if (n < N_){
      const float* kr = kb + ((long)(b*N_ + n))*D_ + h*DH;
      float s = 0.f;
      #pragma unroll
      for (int d = 0; d < 32; d++) s += kr[d] * projs[m*33 + d];
      mx = fmaxf(mx, s * DN);
    }
  }
  red[tid] = mx; __syncthreads();
  for (int m2 = 128; m2 > 0; m2 >>= 1){
    if (tid < m2) red[tid] = fmaxf(red[tid], red[tid + m2]);
    __syncthreads();
  }
  if (tid == 0) atomicMax(kmaxb, floatToOrdered(red[0]));
}

// ---------------- attention: streaming ctx[m][d] + ksum, atomicAdd into ctxf ----------------
__global__ __launch_bounds__(128) void ctx_k(const float* __restrict__ kb,
    const float* __restrict__ vb, const float* __restrict__ proj,
    const unsigned* __restrict__ kmaxb, float* __restrict__ ctxf)
{
  __shared__ float projs[M_*33];
  __shared__ float acc[M_*33];      // col 32 = ksum
  __shared__ float kr[32], vr[32];
  __shared__ float sdiag;
  int c = blockIdx.x, h = blockIdx.y, b = blockIdx.z;
  int tid = threadIdx.x;
  for (int i = tid; i < M_*33; i += 128){
    int m = i / 33, d = i - m*33;
    projs[i] = (d < 32) ? proj[m*32 + d] : 0.f;
    acc[i] = 0.f;
  }
  __syncthreads();
  float kmax = orderedToFloat(kmaxb[0]);
  int n0 = c*257, n1 = min(N_, n0 + 257);
  for (int n = n0; n < n1; n++){
    long base = ((long)(b*N_ + n))*D_ + h*DH;
    if (tid < 32) kr[tid] = kb[base + tid];
    else if (tid < 64) vr[tid - 32] = vb[base + tid - 32];
    __syncthreads();
    if (tid < 64){
      float t = (tid < 32) ? kr[tid] : 0.f;
      float sq = t*t;
      #pragma unroll
      for (int m2 = 1; m2 < 64; m2 <<= 1) sq += __shfl_xor(sq, m2);
      if (tid == 0) sdiag = 0.5f * DN2 * sq;
    }
    __syncthreads();
    if (tid < M_){
      float s = 0.f;
      #pragma unroll
      for (int d = 0; d < 32; d++) s += kr[d] * projs[tid*33 + d];
      float kp = RATIO * (expf(s*DN - sdiag - kmax) + 1e-3f);
      acc[tid*33 + 32] += kp;
      #pragma unroll
      for (int d = 0; d < 32; d++) acc[tid*33 + d] += kp * vr[d];
    }
    __syncthreads();   // wave 0 must not overwrite kr/vr while wave 1 reads
  }
  long cb = ((long)(b*H_ + h))*(M_*33);
  for (int i = tid; i < M_*33; i += 128) atomicAdd(&ctxf[cb + i], acc[i]);
}

// ---------------- attention output: uniform-shfl, no read/write LDS ----------------
__global__ __launch_bounds__(256) void attn_out_k(const float* __restrict__ qb,
    const float* __restrict__ ctxf, const float* __restrict__ proj,
    float* __restrict__ ob)
{
  __shared__ float projs[M_*33];
  __shared__ float ctxs[M_*33];     // col 32 = ksum
  int t = blockIdx.x, h = blockIdx.y, b = blockIdx.z;
  int tid = threadIdx.x;
  for (int i = tid; i < M_*33; i += 256){
    int m = i / 33, d = i - m*33;
    projs[i] = (d < 32) ? proj[m*32 + d] : 0.f;
    ctxs[i] = ctxf[((long)(b*H_ + h))*(M_*33) + i];
  }
  __syncthreads();
  int w = tid >> 6, lane = tid & 63;
  int m1 = lane;                 // 0..63
  int m2 = lane + 64;            // 64..127
  bool m2v = (m2 < M_);
  int m2c = m2v ? m2 : 0;
  for (int r = 0; r < 16; r++){
    int n = t*64 + w*16 + r;
    if (n >= N_) break;
    long base = ((long)(b*N_ + n))*D_ + h*DH;
    float qv = (lane < 32) ? qb[base + lane] : 0.f;
    float sq = qv * qv;
    #pragma unroll
    for (int mk = 1; mk < 64; mk <<= 1) sq += __shfl_xor(sq, mk);
    float diag = 0.5f * DN2 * sq;
    float xd1 = 0.f, xd2 = 0.f;
    #pragma unroll
    for (int d = 0; d < 32; d++){
      float qd = __shfl(qv, d);
      xd1 += qd * projs[m1*33 + d];
      xd2 += qd * projs[m2c*33 + d];
    }
    xd1 *= DN; xd2 *= DN;
    float rm = fmaxf(xd1, m2v ? xd2 : -INFINITY);
    #pragma unroll
    for (int mk = 1; mk < 64; mk <<= 1) rm = fmaxf(rm, __shfl_xor(rm, mk));
    float qp1 = RATIO * (expf(xd1 - diag - rm) + 1e-3f);
    float qp2 = m2v ? (RATIO * (expf(xd2 - diag - rm) + 1e-3f)) : 0.f;
    float dv = qp1 * ctxs[m1*33 + 32] + qp2 * ctxs[m2c*33 + 32];
    #pragma unroll
    for (int mk = 1; mk < 64; mk <<= 1) dv += __shfl_xor(dv, mk);
    float dinv = 1.0f / dv;
    int d = lane & 31;
    float o = 0.f;
    for (int src = 0; src < 64; src++){
      float qpa = __shfl(qp1, src);   // m = src        (0..63)
      float qpb = __shfl(qp2, src);   // m = 64 + src   (valid src<46)
      float c1 = ctxs[src*33 + d];
      float c2 = (src < 46) ? ctxs[(64+src)*33 + d] : 0.f;
      o += (lane < 32) ? (qpa * c1) : (qpb * c2);
    }
    o += __shfl_xor(o, 32);
    if (lane < 32) ob[base + d] = o * dinv;
  }
}

// ---------------- diagnostic: encode ws_size into output (fp32 now) ----------------
__global__ __launch_bounds__(256) void diag_k(float* __restrict__ out, float v)
{
  int i = blockIdx.x*256 + threadIdx.x;
  if (i < 2048) out[i] = v;
}

// ---------------- host ----------------
extern "C" void kernel_launch(void* const* d_in, const int* in_sizes, int n_in,
                              void* d_out, int out_size, void* d_ws, size_t ws_size,
                              hipStream_t stream)
{
  const float* expr = (const float*)d_in[0];
  const float* temb = (const float*)d_in[1];
  const float* cls  = (const float*)d_in[2];
  const float* ln1g = (const float*)d_in[3];
  const float* ln1b = (const float*)d_in[4];
  const float* Wq   = (const float*)d_in[5];
  const float* bq   = (const float*)d_in[6];
  const float* Wk   = (const float*)d_in[7];
  const float* bk   = (const float*)d_in[8];
  const float* Wv   = (const float*)d_in[9];
  const float* bv   = (const float*)d_in[10];
  const float* Wo   = (const float*)d_in[11];
  const float* bo   = (const float*)d_in[12];
  const float* ln2g = (const float*)d_in[13];
  const float* ln2b = (const float*)d_in[14];
  const float* W1   = (const float*)d_in[15];
  const float* b1   = (const float*)d_in[16];
  const float* W2   = (const float*)d_in[17];
  const float* b2   = (const float*)d_in[18];
  const float* proj = (const float*)d_in[19];
  const float* Wp   = (const float*)d_in[20];
  const float* bp   = (const float*)d_in[21];
  (void)in_sizes; (void)n_in; (void)out_size;

  char* w = (char*)d_ws;
  size_t off = 0;
  auto alloc = [&](size_t bytes) -> char* {
    char* p = w + off;
    off = (off + bytes + 255) & ~(size_t)255;
    return p;
  };
  float*    selected = (float*)alloc((size_t)B_*KSEL*4);
  float*    bsum     = (float*)alloc(B_*4);
  float*    bv0      = (float*)alloc(B_*4);
  float*    emaxp    = (float*)alloc(4);
  unsigned* kmaxb    = (unsigned*)alloc(4);
  float*    zbias    = (float*)alloc(256*4);
  float*    ctxf     = (float*)alloc((size_t)CTXN*4);
  float*    x        = (float*)alloc((size_t)BN_*D_*4);
  float*    h        = (float*)alloc((size_t)BN_*D_*4);
  float*    q        = (float*)alloc((size_t)BN_*D_*4);
  float*    k        = (float*)alloc((size_t)BN_*D_*4);
  float*    v        = (float*)alloc((size_t)BN_*D_*4);
  float*    ffi      = k;   // FFN intermediate chunk [BN,256] aliases k (dead during FFN)

  // workspace tripwire (known: ws_size >= 88 MiB, layout ~81 MiB — should never fire)
  if (ws_size < off){
    diag_k<<<8, 256, 0, stream>>>((float*)d_out, (float)((double)ws_size / 1048576.0));
    return;
  }

  zerob_k<<<1, 256, 0, stream>>>(zbias);
  topk_k<<<B_, 256, 0, stream>>>(expr, selected);
  nsum_k<<<B_, 256, 0, stream>>>(selected, bsum, bv0);
  emax_k<<<1, 64, 0, stream>>>(bsum, bv0, emaxp);
  embed_k<<<BN_, 64, 0, stream>>>(selected, bsum, emaxp, temb, cls, x);

  for (int L = 0; L < DEPTH_; L++){
    const float* pj = proj + (size_t)L*M_*DH;
    ln_k<<<BN_/4, 256, 0, stream>>>(x, h, ln1g + L*D_, ln1b + L*D_);
    gemm_k<0,0><<<dim3(257,4), 256, 0, stream>>>(h, D_, Wq + (size_t)L*D_*D_, D_, bq + L*D_, nullptr, q, BN_, D_, D_);
    gemm_k<0,0><<<dim3(257,4), 256, 0, stream>>>(h, D_, Wk + (size_t)L*D_*D_, D_, bk + L*D_, nullptr, k, BN_, D_, D_);
    gemm_k<0,0><<<dim3(257,4), 256, 0, stream>>>(h, D_, Wv + (size_t)L*D_*D_, D_, bv + L*D_, nullptr, v, BN_, D_, D_);
    zeroctx_k<<<(CTXN + 255)/256, 256, 0, stream>>>(ctxf, kmaxb);
    kmax_k<<<dim3(9, H_, B_), 256, 0, stream>>>(k, pj, kmaxb);
    ctx_k<<<dim3(8, H_, B_), 128, 0, stream>>>(k, v, pj, kmaxb, ctxf);
    attn_out_k<<<dim3(33, H_, B_), 256, 0, stream>>>(q, ctxf, pj, h);   // h := o
    gemm_k<0,1><<<dim3(257,4), 256, 0, stream>>>(h, D_, Wo + (size_t)L*D_*D_, D_, bo + L*D_, x, x, BN_, D_, D_);
    ln_k<<<BN_/4, 256, 0, stream>>>(x, h, ln2g + L*D_, ln2b + L*D_);
    for (int c4 = 0; c4 < 4; c4++){
      gemm_k<1,0><<<dim3(257,4), 256, 0, stream>>>(h, D_,
          W1 + (size_t)L*D_*DFF_ + (size_t)c4*256, DFF_,
          b1 + (size_t)L*DFF_ + (size_t)c4*256, nullptr, ffi, BN_, 256, D_);
      gemm_k<0,1><<<dim3(257,4), 256, 0, stream>>>(ffi, 256,
          W2 + (size_t)L*DFF_*D_ + (size_t)c4*256*D_, D_,
          (c4 == 0) ? (b2 + L*D_) : zbias, x, x, BN_, D_, 256);
    }
  }
  // final head: OUTPUT IS FP32 (reference returns jnp.float32)
  gemm_k<0,0><<<dim3(1,4), 256, 0, stream>>>(x, (long)N_*D_, Wp, D_, bp, nullptr,
                                             (float*)d_out, B_, D_, D_);
}

// Round 7
// 4717.818 us; speedup vs baseline: 1.6677x; 1.6677x over previous
//
#include <hip/hip_runtime.h>
#include <hip/hip_bf16.h>

#define B_    8
#define NG    16906
#define KSEL  2048
#define D_    256
#define H_    8
#define DH    32
#define M_    110
#define DEPTH_ 6
#define DFF_  1024
#define N_    2049
#define BN_   (B_*N_)
#define NTOK  64
#define NC    16          // ctx chunks
#define CHUNK 129         // ceil(2049/16)
#define CTXE  (M_*33)     // 3630 per (b,h)
#define CTXN2 (64*CTXE)   // 232320

static constexpr float DN    = 0.42044820762685725f;  // 32^-0.25
static constexpr float DN2   = 0.17677669529663687f;  // 32^-0.5
static constexpr float RATIO = 0.09534625892455922f;  // 110^-0.5

__device__ __forceinline__ unsigned floatToOrdered(float f){
  unsigned b = __float_as_uint(f);
  return (b & 0x80000000u) ? ~b : (b | 0x80000000u);
}
__device__ __forceinline__ float orderedToFloat(unsigned u){
  unsigned b = (u & 0x80000000u) ? (u & 0x7FFFFFFFu) : ~u;
  return __uint_as_float(b);
}

// ---------------- top-k (radix select on float bits; all inputs >= 0) ----------------
__global__ __launch_bounds__(256) void topk_k(const float* __restrict__ expr,
                                              float* __restrict__ selected)
{
  __shared__ unsigned hist[256];
  __shared__ unsigned sPrefix;
  __shared__ int sKK;
  __shared__ unsigned cGT, cEQ;
  int b = blockIdx.x, tid = threadIdx.x;
  const float* row = expr + (long)b*NG;
  if (tid == 0){ sPrefix = 0u; sKK = KSEL; }
  __syncthreads();
  for (int pass = 0; pass < 4; ++pass){
    int shift = 24 - pass*8;
    hist[tid] = 0u;
    __syncthreads();
    unsigned pref = sPrefix;
    for (int i = tid; i < NG; i += 256){
      unsigned bits = __float_as_uint(row[i]);
      bool ok = (pass == 0) || ((bits >> (shift + 8)) == pref);
      if (ok) atomicAdd(&hist[(bits >> shift) & 255u], 1u);
    }
    __syncthreads();
    if (tid == 0){
      int kk = sKK; unsigned cum = 0; int sel = 0;
      for (int j = 255; j >= 0; --j){
        unsigned c = hist[j];
        if (cum + c >= (unsigned)kk){ sel = j; break; }
        cum += c;
      }
      sPrefix = (pref << 8) | (unsigned)sel;
      sKK = kk - (int)cum;
    }
    __syncthreads();
  }
  unsigned T = sPrefix; int needEQ = sKK; int base = KSEL - needEQ;
  if (tid == 0){ cGT = 0u; cEQ = 0u; }
  __syncthreads();
  for (int i = tid; i < NG; i += 256){
    float v = row[i];
    unsigned bits = __float_as_uint(v);
    if (bits > T){
      unsigned p = atomicAdd(&cGT, 1u);
      selected[(long)b*KSEL + p] = v;
    } else if (bits == T){
      unsigned p = atomicAdd(&cEQ, 1u);
      if ((int)p < needEQ) selected[(long)b*KSEL + base + p] = v;
    }
  }
}

// ---------------- per-batch sum + max of selected ----------------
__global__ __launch_bounds__(256) void nsum_k(const float* __restrict__ selected,
                                              float* __restrict__ bsum, float* __restrict__ bv0)
{
  __shared__ float rs[256], rm[256];
  int b = blockIdx.x, tid = threadIdx.x;
  float s = 0.f, m = -INFINITY;
  for (int i = tid; i < KSEL; i += 256){ float v = selected[(long)b*KSEL + i]; s += v; m = fmaxf(m, v); }
  rs[tid] = s; rm[tid] = m; __syncthreads();
  for (int k = 128; k > 0; k >>= 1){
    if (tid < k){ rs[tid] += rs[tid + k]; rm[tid] = fmaxf(rm[tid], rm[tid + k]); }
    __syncthreads();
  }
  if (tid == 0){ bsum[b] = rs[0]; bv0[b] = rm[0]; }
}

// ---------------- global max of e = log1p(v0/sum*1e4) ----------------
__global__ __launch_bounds__(64) void emax_k(const float* __restrict__ bsum,
                                             const float* __restrict__ bv0,
                                             float* __restrict__ emaxp)
{
  int tid = threadIdx.x;
  float e = -INFINITY;
  if (tid < B_) e = log1pf(bv0[tid] / fmaxf(bsum[tid], 1e-12f) * 10000.0f);
  #pragma unroll
  for (int m = 1; m < 64; m <<= 1) e = fmaxf(e, __shfl_xor(e, m));
  if (tid == 0) emaxp[0] = e;
}

// ---------------- tokenize + embed ----------------
__global__ __launch_bounds__(64) void embed_k(const float* __restrict__ selected,
    const float* __restrict__ bsum, const float* __restrict__ emaxp,
    const float* __restrict__ temb, const float* __restrict__ cls,
    float* __restrict__ x)
{
  int rowi = blockIdx.x;
  int b = rowi / N_, n = rowi % N_;
  int tid = threadIdx.x;
  const float* src;
  if (n == 0){
    src = cls;
  } else {
    float val = selected[(long)b*KSEL + (n - 1)];
    float e = log1pf(val / fmaxf(bsum[b], 1e-12f) * 10000.0f);
    float step = emaxp[0] / 7.0f;              // matches jnp.linspace step
    int cnt = 0;
    #pragma unroll
    for (int i = 0; i < 7; i++) cnt += (((float)i * step) < e) ? 1 : 0;  // searchsorted 'left'
    int tok = cnt > 6 ? 6 : cnt;
    src = temb + (long)tok * D_;
  }
  float4 o = *(const float4*)(src + tid*4);
  *(float4*)(x + (long)rowi*D_ + tid*4) = o;
}

// ---------------- LayerNorm: one wave per row ----------------
__global__ __launch_bounds__(256) void ln_k(const float* __restrict__ x, float* __restrict__ out,
    const float* __restrict__ g, const float* __restrict__ bb)
{
  int row = blockIdx.x*4 + (threadIdx.x >> 6);
  int lane = threadIdx.x & 63;
  float4 v = *(const float4*)(x + (long)row*D_ + lane*4);
  float s = v.x + v.y + v.z + v.w;
  float q = v.x*v.x + v.y*v.y + v.z*v.z + v.w*v.w;
  #pragma unroll
  for (int m = 1; m < 64; m <<= 1){ s += __shfl_xor(s, m); q += __shfl_xor(q, m); }
  float mu  = s * (1.0f/D_);
  float var = q * (1.0f/D_) - mu*mu;
  float inv = 1.0f / sqrtf(fmaxf(var, 0.f) + 1e-5f);
  float4 gu = *(const float4*)(g + lane*4);
  float4 bu = *(const float4*)(bb + lane*4);
  float4 o;
  o.x = (v.x - mu)*inv*gu.x + bu.x;
  o.y = (v.y - mu)*inv*gu.y + bu.y;
  o.z = (v.z - mu)*inv*gu.z + bu.z;
  o.w = (v.w - mu)*inv*gu.w + bu.w;
  *(float4*)(out + (long)row*D_ + lane*4) = o;
}

// ---------------- generic tiled fp32 GEMM (unchanged from round 6) ----------------
template<int ACT, int RES>
__global__ __launch_bounds__(256) void gemm_k(
    const float* __restrict__ A, long lda,
    const float* __restrict__ Bw, long ldb,
    const float* __restrict__ bias,
    const float* __restrict__ res,
    float* __restrict__ Cf,
    int M, int Nn, int K)
{
  __shared__ float As[16][64];
  __shared__ float Bs[16][64];
  int tid = threadIdx.x;
  int tx = tid & 15, ty = tid >> 4;
  int rowBlk = blockIdx.x * 64, colBlk = blockIdx.y * 64;
  int am = tid >> 2, ak = (tid & 3) * 4;
  int bk = tid >> 4, bc = (tid & 15) * 4;
  float acc[4][4];
  #pragma unroll
  for (int i = 0; i < 4; i++)
    #pragma unroll
    for (int j = 0; j < 4; j++) acc[i][j] = 0.f;

  for (int kt = 0; kt < K; kt += 16){
    float4 av = make_float4(0.f, 0.f, 0.f, 0.f);
    int ar = rowBlk + am;
    if (ar < M) av = *(const float4*)(A + (long)ar*lda + kt + ak);
    As[ak+0][am] = av.x; As[ak+1][am] = av.y; As[ak+2][am] = av.z; As[ak+3][am] = av.w;
    float4 bv4 = *(const float4*)(Bw + (long)(kt + bk)*ldb + colBlk + bc);
    Bs[bk][bc+0] = bv4.x; Bs[bk][bc+1] = bv4.y;
    Bs[bk][bc+2] = bv4.z; Bs[bk][bc+3] = bv4.w;
    __syncthreads();
    #pragma unroll
    for (int kk = 0; kk < 16; kk++){
      float4 a4 = *(const float4*)&As[kk][ty*4];
      float4 b4 = *(const float4*)&Bs[kk][tx*4];
      acc[0][0] += a4.x*b4.x; acc[0][1] += a4.x*b4.y; acc[0][2] += a4.x*b4.z; acc[0][3] += a4.x*b4.w;
      acc[1][0] += a4.y*b4.x; acc[1][1] += a4.y*b4.y; acc[1][2] += a4.y*b4.z; acc[1][3] += a4.y*b4.w;
      acc[2][0] += a4.z*b4.x; acc[2][1] += a4.z*b4.y; acc[2][2] += a4.z*b4.z; acc[2][3] += a4.z*b4.w;
      acc[3][0] += a4.w*b4.x; acc[3][1] += a4.w*b4.y; acc[3][2] += a4.w*b4.z; acc[3][3] += a4.w*b4.w;
    }
    __syncthreads();
  }
  int r0 = rowBlk + ty*4, c0 = colBlk + tx*4;
  float bz[4];
  #pragma unroll
  for (int j = 0; j < 4; j++) bz[j] = bias[c0 + j];
  #pragma unroll
  for (int i = 0; i < 4; i++){
    int r = r0 + i;
    if (r < M){
      #pragma unroll
      for (int j = 0; j < 4; j++){
        float c = acc[i][j] + bz[j];
        if (ACT == 1) c = 0.5f * c * (1.0f + erff(c * 0.70710678118654752f));
        if (RES) c += res[(long)r*Nn + c0 + j];
        Cf[(long)r*Nn + c0 + j] = c;
      }
    }
  }
}

// ---------------- small helpers ----------------
__global__ void initkm_k(unsigned* kmaxb){ kmaxb[0] = 0u; }
__global__ __launch_bounds__(256) void zerob_k(float* __restrict__ zbias){ zbias[threadIdx.x] = 0.f; }

// ---------------- attention: global key-stab max (unchanged) ----------------
__global__ __launch_bounds__(256) void kmax_k(const float* __restrict__ kb,
    const float* __restrict__ proj, unsigned* __restrict__ kmaxb)
{
  __shared__ float projs[M_*33];
  __shared__ float red[256];
  int c = blockIdx.x, h = blockIdx.y, b = blockIdx.z;
  int tid = threadIdx.x;
  for (int i = tid; i < M_*33; i += 256){
    int m = i / 33, d = i - m*33;
    projs[i] = (d < 32) ? proj[m*32 + d] : 0.f;
  }
  __syncthreads();
  float mx = -INFINITY;
  int n0 = c * 228;
  for (int it = tid; it < 228*M_; it += 256){
    int dn_ = it / M_; int m = it - dn_*M_;
    int n = n0 + dn_;
    if (n < N_){
      const float* kr = kb + ((long)(b*N_ + n))*D_ + h*DH;
      float s = 0.f;
      #pragma unroll
      for (int d = 0; d < 32; d++) s += kr[d] * projs[m*33 + d];
      mx = fmaxf(mx, s * DN);
    }
  }
  red[tid] = mx; __syncthreads();
  for (int m2 = 128; m2 > 0; m2 >>= 1){
    if (tid < m2) red[tid] = fmaxf(red[tid], red[tid + m2]);
    __syncthreads();
  }
  if (tid == 0) atomicMax(kmaxb, floatToOrdered(red[0]));
}

// ---------------- ctx v2: token-parallel, proj in VGPRs, partials out ----------------
// thread t: mslot = t>>1 (m), dhalf = t&1 (d in [dhalf*16, +16)). 220 active.
__global__ __launch_bounds__(256) void ctx2_k(const float* __restrict__ kb,
    const float* __restrict__ vb, const float* __restrict__ proj,
    const unsigned* __restrict__ kmaxb, float* __restrict__ partials)
{
  __shared__ float ks[NTOK*36];
  __shared__ float vs[NTOK*36];
  int c = blockIdx.x, h = blockIdx.y, b = blockIdx.z;
  int tid = threadIdx.x;
  int mslot = tid >> 1, dh = tid & 1, d0 = dh*16;
  bool act = (mslot < M_);
  int m = act ? mslot : 0;
  float kmax = orderedToFloat(kmaxb[0]);
  float pm[32];
  #pragma unroll
  for (int j = 0; j < 8; j++){
    float4 p4 = *(const float4*)(proj + m*DH + j*4);
    pm[j*4+0]=p4.x; pm[j*4+1]=p4.y; pm[j*4+2]=p4.z; pm[j*4+3]=p4.w;
  }
  float acc[16];
  #pragma unroll
  for (int j = 0; j < 16; j++) acc[j] = 0.f;
  float ksacc = 0.f;

  int n0 = c*CHUNK, n1 = min(N_, n0 + CHUNK);
  for (int t0 = n0; t0 < n1; t0 += NTOK){
    int nt = min(NTOK, n1 - t0);
    __syncthreads();                       // prev-tile readers done
    #pragma unroll
    for (int it = 0; it < 2; it++){
      int tok = it*32 + (tid >> 3);
      int d4  = tid & 7;
      int ncl = t0 + min(tok, nt - 1);
      long gb = ((long)(b*N_ + ncl))*D_ + h*DH + d4*4;
      float4 kv = *(const float4*)(kb + gb);
      float4 vv = *(const float4*)(vb + gb);
      *(float4*)(ks + tok*36 + d4*4) = kv;
      *(float4*)(vs + tok*36 + d4*4) = vv;
    }
    __syncthreads();
    for (int n = 0; n < nt; n++){
      float s = 0.f, sq = 0.f;
      #pragma unroll
      for (int j = 0; j < 8; j++){
        float4 k4 = *(const float4*)(ks + n*36 + j*4);
        s  += k4.x*pm[j*4+0] + k4.y*pm[j*4+1] + k4.z*pm[j*4+2] + k4.w*pm[j*4+3];
        sq += k4.x*k4.x + k4.y*k4.y + k4.z*k4.z + k4.w*k4.w;
      }
      float kp = RATIO * (expf(s*DN - 0.5f*DN2*sq - kmax) + 1e-3f);
      ksacc += kp;
      #pragma unroll
      for (int j = 0; j < 4; j++){
        float4 v4 = *(const float4*)(vs + n*36 + d0 + j*4);
        acc[j*4+0] += kp*v4.x; acc[j*4+1] += kp*v4.y;
        acc[j*4+2] += kp*v4.z; acc[j*4+3] += kp*v4.w;
      }
    }
  }
  if (act){
    long pb = ((long)c*64 + (b*H_ + h))*CTXE;
    #pragma unroll
    for (int j = 0; j < 16; j++) partials[pb + m*33 + d0 + j] = acc[j];
    if (dh == 0) partials[pb + m*33 + 32] = ksacc;
  }
}

// ---------------- ctx partial reduce: ctxf[i] = sum_c partials[c][i] ----------------
__global__ __launch_bounds__(256) void ctxred2_k(const float* __restrict__ partials,
                                                 float* __restrict__ ctxf)
{
  int i = blockIdx.x*256 + threadIdx.x;
  if (i >= CTXN2) return;
  float s = 0.f;
  #pragma unroll
  for (int c = 0; c < NC; c++) s += partials[(long)c*CTXN2 + i];
  ctxf[i] = s;
}

// ---------------- attn v2: 64-token blocks, qp in LDS, in-place output ----------------
__global__ __launch_bounds__(256) void attn2_k(const float* __restrict__ qb,
    const float* __restrict__ ctxf, const float* __restrict__ proj,
    float* __restrict__ ob)
{
  __shared__ float qs[NTOK*36];
  __shared__ float xp[NTOK*113];     // xd, then qp (in place)
  __shared__ float cs[M_*36];        // ctx staged, col 32 = ksum
  __shared__ float rmx[NTOK], dg[NTOK];
  int t = blockIdx.x, h = blockIdx.y, b = blockIdx.z;
  int tid = threadIdx.x;
  long cbase = ((long)(b*H_ + h))*CTXE;
  for (int i = tid; i < CTXE; i += 256){
    int mm = i / 33, dd = i - mm*33;
    cs[mm*36 + dd] = ctxf[cbase + i];
  }
  int n0 = t*NTOK;
  int nt = min(NTOK, N_ - n0);
  #pragma unroll
  for (int it = 0; it < 2; it++){
    int tok = it*32 + (tid >> 3);
    int d4  = tid & 7;
    int ncl = n0 + min(tok, nt - 1);
    float4 qv = *(const float4*)(qb + ((long)(b*N_ + ncl))*D_ + h*DH + d4*4);
    *(float4*)(qs + tok*36 + d4*4) = qv;
  }
  int mslot = tid >> 1, dh = tid & 1;
  bool act = (mslot < M_);
  int m = act ? mslot : 0;
  float pm[32];
  #pragma unroll
  for (int j = 0; j < 8; j++){
    float4 p4 = *(const float4*)(proj + m*DH + j*4);
    pm[j*4+0]=p4.x; pm[j*4+1]=p4.y; pm[j*4+2]=p4.z; pm[j*4+3]=p4.w;
  }
  __syncthreads();
  // stage 1: xd[n][m]  (dh splits tokens by parity)
  if (act){
    for (int n = dh; n < nt; n += 2){
      float s = 0.f;
      #pragma unroll
      for (int j = 0; j < 8; j++){
        float4 q4 = *(const float4*)(qs + n*36 + j*4);
        s += q4.x*pm[j*4+0] + q4.y*pm[j*4+1] + q4.z*pm[j*4+2] + q4.w*pm[j*4+3];
      }
      xp[n*113 + m] = s * DN;
    }
  }
  __syncthreads();
  // per-token diag + row max
  if (tid < nt){
    int n = tid;
    float sq = 0.f;
    #pragma unroll
    for (int j = 0; j < 8; j++){
      float4 q4 = *(const float4*)(qs + n*36 + j*4);
      sq += q4.x*q4.x + q4.y*q4.y + q4.z*q4.z + q4.w*q4.w;
    }
    dg[n] = 0.5f * DN2 * sq;
    float mx = -INFINITY;
    for (int mm = 0; mm < M_; mm++) mx = fmaxf(mx, xp[n*113 + mm]);
    rmx[n] = mx;
  }
  __syncthreads();
  // qp in place
  for (int i = tid; i < NTOK*M_; i += 256){
    int n = i & 63, mm = i >> 6;
    if (n < nt)
      xp[n*113 + mm] = RATIO * (expf(xp[n*113 + mm] - dg[n] - rmx[n]) + 1e-3f);
  }
  __syncthreads();
  // stage 2: o[n][d] = (qp @ cs) * dinv
  int n2 = tid >> 2, dq = tid & 3, db = dq*8;
  if (n2 < nt){
    float o[8];
    #pragma unroll
    for (int j = 0; j < 8; j++) o[j] = 0.f;
    float den = 0.f;
    for (int mm = 0; mm < M_; mm++){
      float qp = xp[n2*113 + mm];
      den += qp * cs[mm*36 + 32];
      float4 c0 = *(const float4*)(cs + mm*36 + db);
      float4 c1 = *(const float4*)(cs + mm*36 + db + 4);
      o[0] += qp*c0.x; o[1] += qp*c0.y; o[2] += qp*c0.z; o[3] += qp*c0.w;
      o[4] += qp*c1.x; o[5] += qp*c1.y; o[6] += qp*c1.z; o[7] += qp*c1.w;
    }
    float dinv = 1.0f / den;
    long obase = ((long)(b*N_ + n0 + n2))*D_ + h*DH + db;
    float4 w0 = make_float4(o[0]*dinv, o[1]*dinv, o[2]*dinv, o[3]*dinv);
    float4 w1 = make_float4(o[4]*dinv, o[5]*dinv, o[6]*dinv, o[7]*dinv);
    *(float4*)(ob + obase)     = w0;
    *(float4*)(ob + obase + 4) = w1;
  }
}

// ---------------- host ----------------
extern "C" void kernel_launch(void* const* d_in, const int* in_sizes, int n_in,
                              void* d_out, int out_size, void* d_ws, size_t ws_size,
                              hipStream_t stream)
{
  const float* expr = (const float*)d_in[0];
  const float* temb = (const float*)d_in[1];
  const float* cls  = (const float*)d_in[2];
  const float* ln1g = (const float*)d_in[3];
  const float* ln1b = (const float*)d_in[4];
  const float* Wq   = (const float*)d_in[5];
  const float* bq   = (const float*)d_in[6];
  const float* Wk   = (const float*)d_in[7];
  const float* bk   = (const float*)d_in[8];
  const float* Wv   = (const float*)d_in[9];
  const float* bv   = (const float*)d_in[10];
  const float* Wo   = (const float*)d_in[11];
  const float* bo   = (const float*)d_in[12];
  const float* ln2g = (const float*)d_in[13];
  const float* ln2b = (const float*)d_in[14];
  const float* W1   = (const float*)d_in[15];
  const float* b1   = (const float*)d_in[16];
  const float* W2   = (const float*)d_in[17];
  const float* b2   = (const float*)d_in[18];
  const float* proj = (const float*)d_in[19];
  const float* Wp   = (const float*)d_in[20];
  const float* bp   = (const float*)d_in[21];
  (void)in_sizes; (void)n_in; (void)out_size; (void)ws_size;

  char* w = (char*)d_ws;
  size_t off = 0;
  auto alloc = [&](size_t bytes) -> char* {
    char* p = w + off;
    off = (off + bytes + 255) & ~(size_t)255;
    return p;
  };
  float*    selected = (float*)alloc((size_t)B_*KSEL*4);
  float*    bsum     = (float*)alloc(B_*4);
  float*    bv0      = (float*)alloc(B_*4);
  float*    emaxp    = (float*)alloc(4);
  unsigned* kmaxb    = (unsigned*)alloc(4);
  float*    zbias    = (float*)alloc(256*4);
  float*    ctxf     = (float*)alloc((size_t)CTXN2*4);
  float*    x        = (float*)alloc((size_t)BN_*D_*4);
  float*    h        = (float*)alloc((size_t)BN_*D_*4);
  float*    q        = (float*)alloc((size_t)BN_*D_*4);
  float*    k        = (float*)alloc((size_t)BN_*D_*4);
  float*    v        = (float*)alloc((size_t)BN_*D_*4);
  float*    ffi      = k;   // FFN intermediate aliases k (dead during FFN)
  float*    partials = h;   // ctx partials alias h (dead between QKV gemms and ln2)
                            // NC*CTXN2*4 = 14.9 MB <= 16.0 MB ✓

  zerob_k<<<1, 256, 0, stream>>>(zbias);
  topk_k<<<B_, 256, 0, stream>>>(expr, selected);
  nsum_k<<<B_, 256, 0, stream>>>(selected, bsum, bv0);
  emax_k<<<1, 64, 0, stream>>>(bsum, bv0, emaxp);
  embed_k<<<BN_, 64, 0, stream>>>(selected, bsum, emaxp, temb, cls, x);

  for (int L = 0; L < DEPTH_; L++){
    const float* pj = proj + (size_t)L*M_*DH;
    ln_k<<<BN_/4, 256, 0, stream>>>(x, h, ln1g + L*D_, ln1b + L*D_);
    gemm_k<0,0><<<dim3(257,4), 256, 0, stream>>>(h, D_, Wq + (size_t)L*D_*D_, D_, bq + L*D_, nullptr, q, BN_, D_, D_);
    gemm_k<0,0><<<dim3(257,4), 256, 0, stream>>>(h, D_, Wk + (size_t)L*D_*D_, D_, bk + L*D_, nullptr, k, BN_, D_, D_);
    gemm_k<0,0><<<dim3(257,4), 256, 0, stream>>>(h, D_, Wv + (size_t)L*D_*D_, D_, bv + L*D_, nullptr, v, BN_, D_, D_);
    initkm_k<<<1, 1, 0, stream>>>(kmaxb);
    kmax_k<<<dim3(9, H_, B_), 256, 0, stream>>>(k, pj, kmaxb);
    ctx2_k<<<dim3(NC, H_, B_), 256, 0, stream>>>(k, v, pj, kmaxb, partials);
    ctxred2_k<<<(CTXN2 + 255)/256, 256, 0, stream>>>(partials, ctxf);
    attn2_k<<<dim3(33, H_, B_), 256, 0, stream>>>(q, ctxf, pj, q);   // o -> q in place
    gemm_k<0,1><<<dim3(257,4), 256, 0, stream>>>(q, D_, Wo + (size_t)L*D_*D_, D_, bo + L*D_, x, x, BN_, D_, D_);
    ln_k<<<BN_/4, 256, 0, stream>>>(x, h, ln2g + L*D_, ln2b + L*D_);
    for (int c4 = 0; c4 < 4; c4++){
      gemm_k<1,0><<<dim3(257,4), 256, 0, stream>>>(h, D_,
          W1 + (size_t)L*D_*DFF_ + (size_t)c4*256, DFF_,
          b1 + (size_t)L*DFF_ + (size_t)c4*256, nullptr, ffi, BN_, 256, D_);
      gemm_k<0,1><<<dim3(257,4), 256, 0, stream>>>(ffi, 256,
          W2 + (size_t)L*DFF_*D_ + (size_t)c4*256*D_, D_,
          (c4 == 0) ? (b2 + L*D_) : zbias, x, x, BN_, D_, 256);
    }
  }
  gemm_k<0,0><<<dim3(1,4), 256, 0, stream>>>(x, (long)N_*D_, Wp, D_, bp, nullptr,
                                             (float*)d_out, B_, D_, D_);
}

// Round 9
// 3053.734 us; speedup vs baseline: 2.5765x; 1.5449x over previous
//
#include <hip/hip_runtime.h>
#include <hip/hip_bf16.h>

#define B_    8
#define NG    16906
#define KSEL  2048
#define D_    256
#define H_    8
#define DH    32
#define M_    110
#define DEPTH_ 6
#define DFF_  1024
#define N_    2049
#define BN_   (B_*N_)
#define NTOK  64
#define NC    8           // ctx chunks
#define CHUNK 257         // ceil(2049/8)
#define CTXE  (M_*33)     // 3630 per (b,h)
#define CTXN2 (64*CTXE)   // 232320

static constexpr float DN    = 0.42044820762685725f;  // 32^-0.25
static constexpr float DN2   = 0.17677669529663687f;  // 32^-0.5
static constexpr float RATIO = 0.09534625892455922f;  // 110^-0.5

typedef __attribute__((ext_vector_type(8))) short s8v;
typedef __attribute__((ext_vector_type(4))) float f4v;

__device__ __forceinline__ unsigned floatToOrdered(float f){
  unsigned b = __float_as_uint(f);
  return (b & 0x80000000u) ? ~b : (b | 0x80000000u);
}
__device__ __forceinline__ float orderedToFloat(unsigned u){
  unsigned b = (u & 0x80000000u) ? (u & 0x7FFFFFFFu) : ~u;
  return __uint_as_float(b);
}
__device__ __forceinline__ unsigned short f2us(float f){
  __hip_bfloat16 b = __float2bfloat16(f);
  return *reinterpret_cast<unsigned short*>(&b);
}

// ---------------- top-k (radix select on float bits; all inputs >= 0) ----------------
__global__ __launch_bounds__(256) void topk_k(const float* __restrict__ expr,
                                              float* __restrict__ selected)
{
  __shared__ unsigned hist[256];
  __shared__ unsigned sPrefix;
  __shared__ int sKK;
  __shared__ unsigned cGT, cEQ;
  int b = blockIdx.x, tid = threadIdx.x;
  const float* row = expr + (long)b*NG;
  if (tid == 0){ sPrefix = 0u; sKK = KSEL; }
  __syncthreads();
  for (int pass = 0; pass < 4; ++pass){
    int shift = 24 - pass*8;
    hist[tid] = 0u;
    __syncthreads();
    unsigned pref = sPrefix;
    for (int i = tid; i < NG; i += 256){
      unsigned bits = __float_as_uint(row[i]);
      bool ok = (pass == 0) || ((bits >> (shift + 8)) == pref);
      if (ok) atomicAdd(&hist[(bits >> shift) & 255u], 1u);
    }
    __syncthreads();
    if (tid == 0){
      int kk = sKK; unsigned cum = 0; int sel = 0;
      for (int j = 255; j >= 0; --j){
        unsigned c = hist[j];
        if (cum + c >= (unsigned)kk){ sel = j; break; }
        cum += c;
      }
      sPrefix = (pref << 8) | (unsigned)sel;
      sKK = kk - (int)cum;
    }
    __syncthreads();
  }
  unsigned T = sPrefix; int needEQ = sKK; int base = KSEL - needEQ;
  if (tid == 0){ cGT = 0u; cEQ = 0u; }
  __syncthreads();
  for (int i = tid; i < NG; i += 256){
    float v = row[i];
    unsigned bits = __float_as_uint(v);
    if (bits > T){
      unsigned p = atomicAdd(&cGT, 1u);
      selected[(long)b*KSEL + p] = v;
    } else if (bits == T){
      unsigned p = atomicAdd(&cEQ, 1u);
      if ((int)p < needEQ) selected[(long)b*KSEL + base + p] = v;
    }
  }
}

// ---------------- per-batch sum + max of selected ----------------
__global__ __launch_bounds__(256) void nsum_k(const float* __restrict__ selected,
                                              float* __restrict__ bsum, float* __restrict__ bv0)
{
  __shared__ float rs[256], rm[256];
  int b = blockIdx.x, tid = threadIdx.x;
  float s = 0.f, m = -INFINITY;
  for (int i = tid; i < KSEL; i += 256){ float v = selected[(long)b*KSEL + i]; s += v; m = fmaxf(m, v); }
  rs[tid] = s; rm[tid] = m; __syncthreads();
  for (int k = 128; k > 0; k >>= 1){
    if (tid < k){ rs[tid] += rs[tid + k]; rm[tid] = fmaxf(rm[tid], rm[tid + k]); }
    __syncthreads();
  }
  if (tid == 0){ bsum[b] = rs[0]; bv0[b] = rm[0]; }
}

// ---------------- global max of e = log1p(v0/sum*1e4) ----------------
__global__ __launch_bounds__(64) void emax_k(const float* __restrict__ bsum,
                                             const float* __restrict__ bv0,
                                             float* __restrict__ emaxp)
{
  int tid = threadIdx.x;
  float e = -INFINITY;
  if (tid < B_) e = log1pf(bv0[tid] / fmaxf(bsum[tid], 1e-12f) * 10000.0f);
  #pragma unroll
  for (int m = 1; m < 64; m <<= 1) e = fmaxf(e, __shfl_xor(e, m));
  if (tid == 0) emaxp[0] = e;
}

// ---------------- tokenize + embed ----------------
__global__ __launch_bounds__(64) void embed_k(const float* __restrict__ selected,
    const float* __restrict__ bsum, const float* __restrict__ emaxp,
    const float* __restrict__ temb, const float* __restrict__ cls,
    float* __restrict__ x)
{
  int rowi = blockIdx.x;
  int b = rowi / N_, n = rowi % N_;
  int tid = threadIdx.x;
  const float* src;
  if (n == 0){
    src = cls;
  } else {
    float val = selected[(long)b*KSEL + (n - 1)];
    float e = log1pf(val / fmaxf(bsum[b], 1e-12f) * 10000.0f);
    float step = emaxp[0] / 7.0f;              // matches jnp.linspace step
    int cnt = 0;
    #pragma unroll
    for (int i = 0; i < 7; i++) cnt += (((float)i * step) < e) ? 1 : 0;  // searchsorted 'left'
    int tok = cnt > 6 ? 6 : cnt;
    src = temb + (long)tok * D_;
  }
  float4 o = *(const float4*)(src + tid*4);
  *(float4*)(x + (long)rowi*D_ + tid*4) = o;
}

// ---------------- LayerNorm: one wave per row, bf16 output ----------------
__global__ __launch_bounds__(256) void ln_k(const float* __restrict__ x,
    unsigned short* __restrict__ out,
    const float* __restrict__ g, const float* __restrict__ bb)
{
  int row = blockIdx.x*4 + (threadIdx.x >> 6);
  int lane = threadIdx.x & 63;
  float4 v = *(const float4*)(x + (long)row*D_ + lane*4);
  float s = v.x + v.y + v.z + v.w;
  float q = v.x*v.x + v.y*v.y + v.z*v.z + v.w*v.w;
  #pragma unroll
  for (int m = 1; m < 64; m <<= 1){ s += __shfl_xor(s, m); q += __shfl_xor(q, m); }
  float mu  = s * (1.0f/D_);
  float var = q * (1.0f/D_) - mu*mu;
  float inv = 1.0f / sqrtf(fmaxf(var, 0.f) + 1e-5f);
  float4 gu = *(const float4*)(g + lane*4);
  float4 bu = *(const float4*)(bb + lane*4);
  ushort4 o;
  o.x = f2us((v.x - mu)*inv*gu.x + bu.x);
  o.y = f2us((v.y - mu)*inv*gu.y + bu.y);
  o.z = f2us((v.z - mu)*inv*gu.z + bu.z);
  o.w = f2us((v.w - mu)*inv*gu.w + bu.w);
  *(ushort4*)(out + (long)row*D_ + lane*4) = o;
}

// ---------------- weight convert + transpose: dst[n][k] = bf16(src[k][n]) ----------------
__global__ __launch_bounds__(256) void wcvt_k(const float* __restrict__ src, long srcL,
    unsigned short* __restrict__ dst, long dstL, int K, int N)
{
  __shared__ float t[32][33];
  int n0 = blockIdx.x*32, k0 = blockIdx.y*32, L = blockIdx.z;
  int tx = threadIdx.x & 31, ty = threadIdx.x >> 5;
  const float* s = src + (long)L*srcL;
  for (int i = ty; i < 32; i += 8)
    t[i][tx] = s[(long)(k0+i)*N + n0 + tx];
  __syncthreads();
  unsigned short* d = dst + (long)L*dstL;
  for (int i = ty; i < 32; i += 8)
    d[(long)(n0 + i)*K + k0 + tx] = f2us(t[tx][i]);
}

// ---------------- bf16 MFMA GEMM: C = act(A@B + bias) [+res] ----------------
// A bf16 [M][lda]; Bt bf16 [Nn][K] (transposed weights); 128x128 tile, 4 waves.
template<int ACT, int RES, int OUTBF>
__global__ __launch_bounds__(256) void bgemm_k(
    const unsigned short* __restrict__ A, long lda,
    const unsigned short* __restrict__ Bt,
    const float* __restrict__ bias,
    const float* __restrict__ res,
    float* __restrict__ Cf, unsigned short* __restrict__ Cb,
    int M, int Nn, int K)
{
  __shared__ __attribute__((aligned(16))) unsigned short As[128*40];
  __shared__ __attribute__((aligned(16))) unsigned short Bs[128*40];
  int tid = threadIdx.x;
  int rowBlk = blockIdx.x*128, colBlk = blockIdx.y*128;
  int w = tid >> 6, lane = tid & 63;
  int wrow = (w >> 1)*64, wcol = (w & 1)*64;
  int fr = lane & 15, fk = (lane >> 4)*8, fq = lane >> 4;
  int srh = tid >> 2, sk8 = (tid & 3)*8;   // 4 threads/row x 8 shorts, 2 half-tiles

  f4v acc[4][4];
  #pragma unroll
  for (int r = 0; r < 4; r++)
    #pragma unroll
    for (int c = 0; c < 4; c++) acc[r][c] = (f4v){0.f, 0.f, 0.f, 0.f};

  for (int kt = 0; kt < K; kt += 32){
    __syncthreads();                     // previous iteration's readers done
    #pragma unroll
    for (int half = 0; half < 2; half++){
      int r = half*64 + srh;             // full 128x32 coverage (FIX: was half-staged)
      s8v av = (s8v){0,0,0,0,0,0,0,0};
      int ar = rowBlk + r;
      if (ar < M) av = *(const s8v*)(A + (long)ar*lda + kt + sk8);
      *(s8v*)&As[r*40 + sk8] = av;
      s8v bv = *(const s8v*)(Bt + (long)(colBlk + r)*K + kt + sk8);
      *(s8v*)&Bs[r*40 + sk8] = bv;
    }
    __syncthreads();
    s8v a[4], b[4];
    #pragma unroll
    for (int r = 0; r < 4; r++) a[r] = *(s8v*)&As[(wrow + r*16 + fr)*40 + fk];
    #pragma unroll
    for (int c = 0; c < 4; c++) b[c] = *(s8v*)&Bs[(wcol + c*16 + fr)*40 + fk];
    #pragma unroll
    for (int r = 0; r < 4; r++)
      #pragma unroll
      for (int c = 0; c < 4; c++)
        acc[r][c] = __builtin_amdgcn_mfma_f32_16x16x32_bf16(a[r], b[c], acc[r][c], 0, 0, 0);
  }

  #pragma unroll
  for (int c = 0; c < 4; c++){
    int col = colBlk + wcol + c*16 + fr;
    float bz = bias[col];
    #pragma unroll
    for (int r = 0; r < 4; r++){
      #pragma unroll
      for (int j = 0; j < 4; j++){
        int row = rowBlk + wrow + r*16 + fq*4 + j;
        if (row < M){
          float val = acc[r][c][j] + bz;
          if (ACT == 1) val = 0.5f * val * (1.0f + erff(val * 0.70710678118654752f));
          if (RES) val += res[(long)row*Nn + col];
          if (OUTBF) Cb[(long)row*Nn + col] = f2us(val);
          else       Cf[(long)row*Nn + col] = val;
        }
      }
    }
  }
}

// ---------------- fp32 GEMM (head only: 8 rows) ----------------
__global__ __launch_bounds__(256) void gemm_k(
    const float* __restrict__ A, long lda,
    const float* __restrict__ Bw, long ldb,
    const float* __restrict__ bias,
    float* __restrict__ Cf,
    int M, int Nn, int K)
{
  __shared__ float As[16][64];
  __shared__ float Bs[16][64];
  int tid = threadIdx.x;
  int tx = tid & 15, ty = tid >> 4;
  int rowBlk = blockIdx.x * 64, colBlk = blockIdx.y * 64;
  int am = tid >> 2, ak = (tid & 3) * 4;
  int bk = tid >> 4, bc = (tid & 15) * 4;
  float acc[4][4];
  #pragma unroll
  for (int i = 0; i < 4; i++)
    #pragma unroll
    for (int j = 0; j < 4; j++) acc[i][j] = 0.f;

  for (int kt = 0; kt < K; kt += 16){
    float4 av = make_float4(0.f, 0.f, 0.f, 0.f);
    int ar = rowBlk + am;
    if (ar < M) av = *(const float4*)(A + (long)ar*lda + kt + ak);
    As[ak+0][am] = av.x; As[ak+1][am] = av.y; As[ak+2][am] = av.z; As[ak+3][am] = av.w;
    float4 bv4 = *(const float4*)(Bw + (long)(kt + bk)*ldb + colBlk + bc);
    Bs[bk][bc+0] = bv4.x; Bs[bk][bc+1] = bv4.y;
    Bs[bk][bc+2] = bv4.z; Bs[bk][bc+3] = bv4.w;
    __syncthreads();
    #pragma unroll
    for (int kk = 0; kk < 16; kk++){
      float4 a4 = *(const float4*)&As[kk][ty*4];
      float4 b4 = *(const float4*)&Bs[kk][tx*4];
      acc[0][0] += a4.x*b4.x; acc[0][1] += a4.x*b4.y; acc[0][2] += a4.x*b4.z; acc[0][3] += a4.x*b4.w;
      acc[1][0] += a4.y*b4.x; acc[1][1] += a4.y*b4.y; acc[1][2] += a4.y*b4.z; acc[1][3] += a4.y*b4.w;
      acc[2][0] += a4.z*b4.x; acc[2][1] += a4.z*b4.y; acc[2][2] += a4.z*b4.z; acc[2][3] += a4.z*b4.w;
      acc[3][0] += a4.w*b4.x; acc[3][1] += a4.w*b4.y; acc[3][2] += a4.w*b4.z; acc[3][3] += a4.w*b4.w;
    }
    __syncthreads();
  }
  int r0 = rowBlk + ty*4, c0 = colBlk + tx*4;
  float bz[4];
  #pragma unroll
  for (int j = 0; j < 4; j++) bz[j] = bias[c0 + j];
  #pragma unroll
  for (int i = 0; i < 4; i++){
    int r = r0 + i;
    if (r < M){
      #pragma unroll
      for (int j = 0; j < 4; j++)
        Cf[(long)r*Nn + c0 + j] = acc[i][j] + bz[j];
    }
  }
}

// ---------------- small helpers ----------------
__global__ void initkm_k(unsigned* kmaxb){ kmaxb[0] = 0u; }

// ---------------- attention: global key-stab max ----------------
__global__ __launch_bounds__(256) void kmax_k(const float* __restrict__ kb,
    const float* __restrict__ proj, unsigned* __restrict__ kmaxb)
{
  __shared__ float projs[M_*33];
  __shared__ float red[256];
  int c = blockIdx.x, h = blockIdx.y, b = blockIdx.z;
  int tid = threadIdx.x;
  for (int i = tid; i < M_*33; i += 256){
    int m = i / 33, d = i - m*33;
    projs[i] = (d < 32) ? proj[m*32 + d] : 0.f;
  }
  __syncthreads();
  float mx = -INFINITY;
  int n0 = c * 228;
  for (int it = tid; it < 228*M_; it += 256){
    int dn_ = it / M_; int m = it - dn_*M_;
    int n = n0 + dn_;
    if (n < N_){
      const float* kr = kb + ((long)(b*N_ + n))*D_ + h*DH;
      float s = 0.f;
      #pragma unroll
      for (int d = 0; d < 32; d++) s += kr[d] * projs[m*33 + d];
      mx = fmaxf(mx, s * DN);
    }
  }
  red[tid] = mx; __syncthreads();
  for (int m2 = 128; m2 > 0; m2 >>= 1){
    if (tid < m2) red[tid] = fmaxf(red[tid], red[tid + m2]);
    __syncthreads();
  }
  if (tid == 0) atomicMax(kmaxb, floatToOrdered(red[0]));
}

// ---------------- ctx v2: token-parallel, proj in VGPRs, partials out ----------------
__global__ __launch_bounds__(256) void ctx2_k(const float* __restrict__ kb,
    const float* __restrict__ vb, const float* __restrict__ proj,
    const unsigned* __restrict__ kmaxb, float* __restrict__ partials)
{
  __shared__ float ks[NTOK*36];
  __shared__ float vs[NTOK*36];
  int c = blockIdx.x, h = blockIdx.y, b = blockIdx.z;
  int tid = threadIdx.x;
  int mslot = tid >> 1, dh = tid & 1, d0 = dh*16;
  bool act = (mslot < M_);
  int m = act ? mslot : 0;
  float kmax = orderedToFloat(kmaxb[0]);
  float pm[32];
  #pragma unroll
  for (int j = 0; j < 8; j++){
    float4 p4 = *(const float4*)(proj + m*DH + j*4);
    pm[j*4+0]=p4.x; pm[j*4+1]=p4.y; pm[j*4+2]=p4.z; pm[j*4+3]=p4.w;
  }
  float acc[16];
  #pragma unroll
  for (int j = 0; j < 16; j++) acc[j] = 0.f;
  float ksacc = 0.f;

  int n0 = c*CHUNK, n1 = min(N_, n0 + CHUNK);
  for (int t0 = n0; t0 < n1; t0 += NTOK){
    int nt = min(NTOK, n1 - t0);
    __syncthreads();
    #pragma unroll
    for (int it = 0; it < 2; it++){
      int tok = it*32 + (tid >> 3);
      int d4  = tid & 7;
      int ncl = t0 + min(tok, nt - 1);
      long gb = ((long)(b*N_ + ncl))*D_ + h*DH + d4*4;
      float4 kv = *(const float4*)(kb + gb);
      float4 vv = *(const float4*)(vb + gb);
      *(float4*)(ks + tok*36 + d4*4) = kv;
      *(float4*)(vs + tok*36 + d4*4) = vv;
    }
    __syncthreads();
    for (int n = 0; n < nt; n++){
      float s = 0.f, sq = 0.f;
      #pragma unroll
      for (int j = 0; j < 8; j++){
        float4 k4 = *(const float4*)(ks + n*36 + j*4);
        s  += k4.x*pm[j*4+0] + k4.y*pm[j*4+1] + k4.z*pm[j*4+2] + k4.w*pm[j*4+3];
        sq += k4.x*k4.x + k4.y*k4.y + k4.z*k4.z + k4.w*k4.w;
      }
      float kp = RATIO * (expf(s*DN - 0.5f*DN2*sq - kmax) + 1e-3f);
      ksacc += kp;
      #pragma unroll
      for (int j = 0; j < 4; j++){
        float4 v4 = *(const float4*)(vs + n*36 + d0 + j*4);
        acc[j*4+0] += kp*v4.x; acc[j*4+1] += kp*v4.y;
        acc[j*4+2] += kp*v4.z; acc[j*4+3] += kp*v4.w;
      }
    }
  }
  if (act){
    long pb = ((long)c*64 + (b*H_ + h))*CTXE;
    #pragma unroll
    for (int j = 0; j < 16; j++) partials[pb + m*33 + d0 + j] = acc[j];
    if (dh == 0) partials[pb + m*33 + 32] = ksacc;
  }
}

// ---------------- ctx partial reduce ----------------
__global__ __launch_bounds__(256) void ctxred2_k(const float* __restrict__ partials,
                                                 float* __restrict__ ctxf)
{
  int i = blockIdx.x*256 + threadIdx.x;
  if (i >= CTXN2) return;
  float s = 0.f;
  #pragma unroll
  for (int c = 0; c < NC; c++) s += partials[(long)c*CTXN2 + i];
  ctxf[i] = s;
}

// ---------------- attn v2: 64-token blocks, bf16 output ----------------
__global__ __launch_bounds__(256) void attn2_k(const float* __restrict__ qb,
    const float* __restrict__ ctxf, const float* __restrict__ proj,
    unsigned short* __restrict__ ob)
{
  __shared__ float qs[NTOK*36];
  __shared__ float xp[NTOK*113];
  __shared__ float cs[M_*36];
  __shared__ float rmx[NTOK], dg[NTOK];
  int t = blockIdx.x, h = blockIdx.y, b = blockIdx.z;
  int tid = threadIdx.x;
  long cbase = ((long)(b*H_ + h))*CTXE;
  for (int i = tid; i < CTXE; i += 256){
    int mm = i / 33, dd = i - mm*33;
    cs[mm*36 + dd] = ctxf[cbase + i];
  }
  int n0 = t*NTOK;
  int nt = min(NTOK, N_ - n0);
  #pragma unroll
  for (int it = 0; it < 2; it++){
    int tok = it*32 + (tid >> 3);
    int d4  = tid & 7;
    int ncl = n0 + min(tok, nt - 1);
    float4 qv = *(const float4*)(qb + ((long)(b*N_ + ncl))*D_ + h*DH + d4*4);
    *(float4*)(qs + tok*36 + d4*4) = qv;
  }
  int mslot = tid >> 1, dh = tid & 1;
  bool act = (mslot < M_);
  int m = act ? mslot : 0;
  float pm[32];
  #pragma unroll
  for (int j = 0; j < 8; j++){
    float4 p4 = *(const float4*)(proj + m*DH + j*4);
    pm[j*4+0]=p4.x; pm[j*4+1]=p4.y; pm[j*4+2]=p4.z; pm[j*4+3]=p4.w;
  }
  __syncthreads();
  if (act){
    for (int n = dh; n < nt; n += 2){
      float s = 0.f;
      #pragma unroll
      for (int j = 0; j < 8; j++){
        float4 q4 = *(const float4*)(qs + n*36 + j*4);
        s += q4.x*pm[j*4+0] + q4.y*pm[j*4+1] + q4.z*pm[j*4+2] + q4.w*pm[j*4+3];
      }
      xp[n*113 + m] = s * DN;
    }
  }
  __syncthreads();
  if (tid < nt){
    int n = tid;
    float sq = 0.f;
    #pragma unroll
    for (int j = 0; j < 8; j++){
      float4 q4 = *(const float4*)(qs + n*36 + j*4);
      sq += q4.x*q4.x + q4.y*q4.y + q4.z*q4.z + q4.w*q4.w;
    }
    dg[n] = 0.5f * DN2 * sq;
    float mx = -INFINITY;
    for (int mm = 0; mm < M_; mm++) mx = fmaxf(mx, xp[n*113 + mm]);
    rmx[n] = mx;
  }
  __syncthreads();
  for (int i = tid; i < NTOK*M_; i += 256){
    int n = i & 63, mm = i >> 6;
    if (n < nt)
      xp[n*113 + mm] = RATIO * (expf(xp[n*113 + mm] - dg[n] - rmx[n]) + 1e-3f);
  }
  __syncthreads();
  int n2 = tid >> 2, dq = tid & 3, db = dq*8;
  if (n2 < nt){
    float o[8];
    #pragma unroll
    for (int j = 0; j < 8; j++) o[j] = 0.f;
    float den = 0.f;
    for (int mm = 0; mm < M_; mm++){
      float qp = xp[n2*113 + mm];
      den += qp * cs[mm*36 + 32];
      float4 c0 = *(const float4*)(cs + mm*36 + db);
      float4 c1 = *(const float4*)(cs + mm*36 + db + 4);
      o[0] += qp*c0.x; o[1] += qp*c0.y; o[2] += qp*c0.z; o[3] += qp*c0.w;
      o[4] += qp*c1.x; o[5] += qp*c1.y; o[6] += qp*c1.z; o[7] += qp*c1.w;
    }
    float dinv = 1.0f / den;
    long obase = ((long)(b*N_ + n0 + n2))*D_ + h*DH + db;
    ushort4 w0, w1;
    w0.x = f2us(o[0]*dinv); w0.y = f2us(o[1]*dinv); w0.z = f2us(o[2]*dinv); w0.w = f2us(o[3]*dinv);
    w1.x = f2us(o[4]*dinv); w1.y = f2us(o[5]*dinv); w1.z = f2us(o[6]*dinv); w1.w = f2us(o[7]*dinv);
    *(ushort4*)(ob + obase)     = w0;
    *(ushort4*)(ob + obase + 4) = w1;
  }
}

// ---------------- host ----------------
extern "C" void kernel_launch(void* const* d_in, const int* in_sizes, int n_in,
                              void* d_out, int out_size, void* d_ws, size_t ws_size,
                              hipStream_t stream)
{
  const float* expr = (const float*)d_in[0];
  const float* temb = (const float*)d_in[1];
  const float* cls  = (const float*)d_in[2];
  const float* ln1g = (const float*)d_in[3];
  const float* ln1b = (const float*)d_in[4];
  const float* Wq   = (const float*)d_in[5];
  const float* bq   = (const float*)d_in[6];
  const float* Wk   = (const float*)d_in[7];
  const float* bk   = (const float*)d_in[8];
  const float* Wv   = (const float*)d_in[9];
  const float* bv   = (const float*)d_in[10];
  const float* Wo   = (const float*)d_in[11];
  const float* bo   = (const float*)d_in[12];
  const float* ln2g = (const float*)d_in[13];
  const float* ln2b = (const float*)d_in[14];
  const float* W1   = (const float*)d_in[15];
  const float* b1   = (const float*)d_in[16];
  const float* W2   = (const float*)d_in[17];
  const float* b2   = (const float*)d_in[18];
  const float* proj = (const float*)d_in[19];
  const float* Wp   = (const float*)d_in[20];
  const float* bp   = (const float*)d_in[21];
  (void)in_sizes; (void)n_in; (void)out_size; (void)ws_size;

  char* w = (char*)d_ws;
  size_t off = 0;
  auto alloc = [&](size_t bytes) -> char* {
    char* p = w + off;
    off = (off + bytes + 255) & ~(size_t)255;
    return p;
  };
  float*    selected = (float*)alloc((size_t)B_*KSEL*4);
  float*    bsum     = (float*)alloc(B_*4);
  float*    bv0      = (float*)alloc(B_*4);
  float*    emaxp    = (float*)alloc(4);
  unsigned* kmaxb    = (unsigned*)alloc(4);
  float*    ctxf     = (float*)alloc((size_t)CTXN2*4);
  float*          x  = (float*)alloc((size_t)BN_*D_*4);
  unsigned short* h  = (unsigned short*)alloc((size_t)BN_*D_*2);
  float*          q  = (float*)alloc((size_t)BN_*D_*4);
  float*          k  = (float*)alloc((size_t)BN_*D_*4);
  float*          v  = (float*)alloc((size_t)BN_*D_*4);
  unsigned short* Wqt = (unsigned short*)alloc((size_t)DEPTH_*D_*D_*2);
  unsigned short* Wkt = (unsigned short*)alloc((size_t)DEPTH_*D_*D_*2);
  unsigned short* Wvt = (unsigned short*)alloc((size_t)DEPTH_*D_*D_*2);
  unsigned short* Wot = (unsigned short*)alloc((size_t)DEPTH_*D_*D_*2);
  unsigned short* W1t = (unsigned short*)alloc((size_t)DEPTH_*D_*DFF_*2);
  unsigned short* W2t = (unsigned short*)alloc((size_t)DEPTH_*DFF_*D_*2);
  unsigned short* ffi = (unsigned short*)k;  // bf16 [BN][1024] aliases k+v (dead during FFN)
  float*     partials = (float*)h;           // NC*CTXN2*4 = 7.44 MB <= h (8.39 MB); h dead then

  // one-time weight convert+transpose (bf16)
  wcvt_k<<<dim3(8, 8, DEPTH_),  256, 0, stream>>>(Wq, (long)D_*D_,   Wqt, (long)D_*D_,   D_, D_);
  wcvt_k<<<dim3(8, 8, DEPTH_),  256, 0, stream>>>(Wk, (long)D_*D_,   Wkt, (long)D_*D_,   D_, D_);
  wcvt_k<<<dim3(8, 8, DEPTH_),  256, 0, stream>>>(Wv, (long)D_*D_,   Wvt, (long)D_*D_,   D_, D_);
  wcvt_k<<<dim3(8, 8, DEPTH_),  256, 0, stream>>>(Wo, (long)D_*D_,   Wot, (long)D_*D_,   D_, D_);
  wcvt_k<<<dim3(32, 8, DEPTH_), 256, 0, stream>>>(W1, (long)D_*DFF_, W1t, (long)D_*DFF_, D_, DFF_);
  wcvt_k<<<dim3(8, 32, DEPTH_), 256, 0, stream>>>(W2, (long)DFF_*D_, W2t, (long)DFF_*D_, DFF_, D_);

  topk_k<<<B_, 256, 0, stream>>>(expr, selected);
  nsum_k<<<B_, 256, 0, stream>>>(selected, bsum, bv0);
  emax_k<<<1, 64, 0, stream>>>(bsum, bv0, emaxp);
  embed_k<<<BN_, 64, 0, stream>>>(selected, bsum, emaxp, temb, cls, x);

  for (int L = 0; L < DEPTH_; L++){
    const float* pj = proj + (size_t)L*M_*DH;
    ln_k<<<BN_/4, 256, 0, stream>>>(x, h, ln1g + L*D_, ln1b + L*D_);
    bgemm_k<0,0,0><<<dim3(129,2), 256, 0, stream>>>(h, D_, Wqt + (size_t)L*D_*D_, bq + L*D_, nullptr, q, nullptr, BN_, D_, D_);
    bgemm_k<0,0,0><<<dim3(129,2), 256, 0, stream>>>(h, D_, Wkt + (size_t)L*D_*D_, bk + L*D_, nullptr, k, nullptr, BN_, D_, D_);
    bgemm_k<0,0,0><<<dim3(129,2), 256, 0, stream>>>(h, D_, Wvt + (size_t)L*D_*D_, bv + L*D_, nullptr, v, nullptr, BN_, D_, D_);
    initkm_k<<<1, 1, 0, stream>>>(kmaxb);
    kmax_k<<<dim3(9, H_, B_), 256, 0, stream>>>(k, pj, kmaxb);
    ctx2_k<<<dim3(NC, H_, B_), 256, 0, stream>>>(k, v, pj, kmaxb, partials);
    ctxred2_k<<<(CTXN2 + 255)/256, 256, 0, stream>>>(partials, ctxf);
    attn2_k<<<dim3(33, H_, B_), 256, 0, stream>>>(q, ctxf, pj, h);   // o -> h (bf16)
    bgemm_k<0,1,0><<<dim3(129,2), 256, 0, stream>>>(h, D_, Wot + (size_t)L*D_*D_, bo + L*D_, x, x, nullptr, BN_, D_, D_);
    ln_k<<<BN_/4, 256, 0, stream>>>(x, h, ln2g + L*D_, ln2b + L*D_);
    bgemm_k<1,0,1><<<dim3(129,8), 256, 0, stream>>>(h, D_, W1t + (size_t)L*D_*DFF_, b1 + L*DFF_, nullptr, nullptr, ffi, BN_, DFF_, D_);
    bgemm_k<0,1,0><<<dim3(129,2), 256, 0, stream>>>(ffi, DFF_, W2t + (size_t)L*DFF_*D_, b2 + L*D_, x, x, nullptr, BN_, D_, DFF_);
  }
  gemm_k<<<dim3(1,4), 256, 0, stream>>>(x, (long)N_*D_, Wp, D_, bp,
                                        (float*)d_out, B_, D_, D_);
}

// Round 10
// 2142.083 us; speedup vs baseline: 3.6730x; 1.4256x over previous
//
#include <hip/hip_runtime.h>
#include <hip/hip_bf16.h>

#define B_    8
#define NG    16906
#define KSEL  2048
#define D_    256
#define H_    8
#define DH    32
#define M_    110
#define DEPTH_ 6
#define DFF_  1024
#define N_    2049
#define BN_   (B_*N_)
#define NTOK  64
#define NC    8            // fctx chunks (blocks per (b,h))
#define NTILES 33          // ceil(2049/64)
#define CTXE  (M_*33)      // 3630 per (b,h)
#define CTXN2 (64*CTXE)    // 232320

static constexpr float DN    = 0.42044820762685725f;  // 32^-0.25
static constexpr float DN2   = 0.17677669529663687f;  // 32^-0.5
static constexpr float RATIO = 0.09534625892455922f;  // 110^-0.5

typedef __attribute__((ext_vector_type(8))) short s8v;
typedef __attribute__((ext_vector_type(4))) float f4v;

__device__ __forceinline__ unsigned floatToOrdered(float f){
  unsigned b = __float_as_uint(f);
  return (b & 0x80000000u) ? ~b : (b | 0x80000000u);
}
__device__ __forceinline__ float orderedToFloat(unsigned u){
  unsigned b = (u & 0x80000000u) ? (u & 0x7FFFFFFFu) : ~u;
  return __uint_as_float(b);
}
__device__ __forceinline__ unsigned short f2us(float f){
  __hip_bfloat16 b = __float2bfloat16(f);
  return *reinterpret_cast<unsigned short*>(&b);
}

// ---------------- top-k (radix select on float bits; all inputs >= 0) ----------------
__global__ __launch_bounds__(256) void topk_k(const float* __restrict__ expr,
                                              float* __restrict__ selected)
{
  __shared__ unsigned hist[256];
  __shared__ unsigned sPrefix;
  __shared__ int sKK;
  __shared__ unsigned cGT, cEQ;
  int b = blockIdx.x, tid = threadIdx.x;
  const float* row = expr + (long)b*NG;
  if (tid == 0){ sPrefix = 0u; sKK = KSEL; }
  __syncthreads();
  for (int pass = 0; pass < 4; ++pass){
    int shift = 24 - pass*8;
    hist[tid] = 0u;
    __syncthreads();
    unsigned pref = sPrefix;
    for (int i = tid; i < NG; i += 256){
      unsigned bits = __float_as_uint(row[i]);
      bool ok = (pass == 0) || ((bits >> (shift + 8)) == pref);
      if (ok) atomicAdd(&hist[(bits >> shift) & 255u], 1u);
    }
    __syncthreads();
    if (tid == 0){
      int kk = sKK; unsigned cum = 0; int sel = 0;
      for (int j = 255; j >= 0; --j){
        unsigned c = hist[j];
        if (cum + c >= (unsigned)kk){ sel = j; break; }
        cum += c;
      }
      sPrefix = (pref << 8) | (unsigned)sel;
      sKK = kk - (int)cum;
    }
    __syncthreads();
  }
  unsigned T = sPrefix; int needEQ = sKK; int base = KSEL - needEQ;
  if (tid == 0){ cGT = 0u; cEQ = 0u; }
  __syncthreads();
  for (int i = tid; i < NG; i += 256){
    float v = row[i];
    unsigned bits = __float_as_uint(v);
    if (bits > T){
      unsigned p = atomicAdd(&cGT, 1u);
      selected[(long)b*KSEL + p] = v;
    } else if (bits == T){
      unsigned p = atomicAdd(&cEQ, 1u);
      if ((int)p < needEQ) selected[(long)b*KSEL + base + p] = v;
    }
  }
}

// ---------------- per-batch sum + max of selected ----------------
__global__ __launch_bounds__(256) void nsum_k(const float* __restrict__ selected,
                                              float* __restrict__ bsum, float* __restrict__ bv0)
{
  __shared__ float rs[256], rm[256];
  int b = blockIdx.x, tid = threadIdx.x;
  float s = 0.f, m = -INFINITY;
  for (int i = tid; i < KSEL; i += 256){ float v = selected[(long)b*KSEL + i]; s += v; m = fmaxf(m, v); }
  rs[tid] = s; rm[tid] = m; __syncthreads();
  for (int k = 128; k > 0; k >>= 1){
    if (tid < k){ rs[tid] += rs[tid + k]; rm[tid] = fmaxf(rm[tid], rm[tid + k]); }
    __syncthreads();
  }
  if (tid == 0){ bsum[b] = rs[0]; bv0[b] = rm[0]; }
}

// ---------------- global max of e = log1p(v0/sum*1e4) ----------------
__global__ __launch_bounds__(64) void emax_k(const float* __restrict__ bsum,
                                             const float* __restrict__ bv0,
                                             float* __restrict__ emaxp)
{
  int tid = threadIdx.x;
  float e = -INFINITY;
  if (tid < B_) e = log1pf(bv0[tid] / fmaxf(bsum[tid], 1e-12f) * 10000.0f);
  #pragma unroll
  for (int m = 1; m < 64; m <<= 1) e = fmaxf(e, __shfl_xor(e, m));
  if (tid == 0) emaxp[0] = e;
}

// ---------------- tokenize + embed ----------------
__global__ __launch_bounds__(64) void embed_k(const float* __restrict__ selected,
    const float* __restrict__ bsum, const float* __restrict__ emaxp,
    const float* __restrict__ temb, const float* __restrict__ cls,
    float* __restrict__ x)
{
  int rowi = blockIdx.x;
  int b = rowi / N_, n = rowi % N_;
  int tid = threadIdx.x;
  const float* src;
  if (n == 0){
    src = cls;
  } else {
    float val = selected[(long)b*KSEL + (n - 1)];
    float e = log1pf(val / fmaxf(bsum[b], 1e-12f) * 10000.0f);
    float step = emaxp[0] / 7.0f;              // matches jnp.linspace step
    int cnt = 0;
    #pragma unroll
    for (int i = 0; i < 7; i++) cnt += (((float)i * step) < e) ? 1 : 0;  // searchsorted 'left'
    int tok = cnt > 6 ? 6 : cnt;
    src = temb + (long)tok * D_;
  }
  float4 o = *(const float4*)(src + tid*4);
  *(float4*)(x + (long)rowi*D_ + tid*4) = o;
}

// ---------------- LayerNorm: one wave per row, bf16 output ----------------
__global__ __launch_bounds__(256) void ln_k(const float* __restrict__ x,
    unsigned short* __restrict__ out,
    const float* __restrict__ g, const float* __restrict__ bb)
{
  int row = blockIdx.x*4 + (threadIdx.x >> 6);
  int lane = threadIdx.x & 63;
  float4 v = *(const float4*)(x + (long)row*D_ + lane*4);
  float s = v.x + v.y + v.z + v.w;
  float q = v.x*v.x + v.y*v.y + v.z*v.z + v.w*v.w;
  #pragma unroll
  for (int m = 1; m < 64; m <<= 1){ s += __shfl_xor(s, m); q += __shfl_xor(q, m); }
  float mu  = s * (1.0f/D_);
  float var = q * (1.0f/D_) - mu*mu;
  float inv = 1.0f / sqrtf(fmaxf(var, 0.f) + 1e-5f);
  float4 gu = *(const float4*)(g + lane*4);
  float4 bu = *(const float4*)(bb + lane*4);
  ushort4 o;
  o.x = f2us((v.x - mu)*inv*gu.x + bu.x);
  o.y = f2us((v.y - mu)*inv*gu.y + bu.y);
  o.z = f2us((v.z - mu)*inv*gu.z + bu.z);
  o.w = f2us((v.w - mu)*inv*gu.w + bu.w);
  *(ushort4*)(out + (long)row*D_ + lane*4) = o;
}

// ---------------- weight convert + transpose: dst[n][k] = bf16(src[k][n]) ----------------
__global__ __launch_bounds__(256) void wcvt_k(const float* __restrict__ src, long srcL,
    unsigned short* __restrict__ dst, long dstL, int K, int N)
{
  __shared__ float t[32][33];
  int n0 = blockIdx.x*32, k0 = blockIdx.y*32, L = blockIdx.z;
  int tx = threadIdx.x & 31, ty = threadIdx.x >> 5;
  const float* s = src + (long)L*srcL;
  for (int i = ty; i < 32; i += 8)
    t[i][tx] = s[(long)(k0+i)*N + n0 + tx];
  __syncthreads();
  unsigned short* d = dst + (long)L*dstL;
  for (int i = ty; i < 32; i += 8)
    d[(long)(n0 + i)*K + k0 + tx] = f2us(t[tx][i]);
}

// ---------------- proj convert: projb[L][112][32] bf16, zero-padded rows ----------------
__global__ __launch_bounds__(256) void pcvt_k(const float* __restrict__ proj,
                                              unsigned short* __restrict__ projb)
{
  int L = blockIdx.x;
  for (int i = threadIdx.x; i < 112*32; i += 256){
    int m = i >> 5, d = i & 31;
    float v = (m < M_) ? proj[(long)L*M_*DH + m*DH + d] : 0.f;
    projb[(long)L*112*32 + i] = f2us(v);
  }
}

// ---------------- bf16 MFMA GEMM (validated round 9) ----------------
template<int ACT, int RES, int OUTBF>
__global__ __launch_bounds__(256) void bgemm_k(
    const unsigned short* __restrict__ A, long lda,
    const unsigned short* __restrict__ Bt,
    const float* __restrict__ bias,
    const float* __restrict__ res,
    float* __restrict__ Cf, unsigned short* __restrict__ Cb,
    int M, int Nn, int K)
{
  __shared__ __attribute__((aligned(16))) unsigned short As[128*40];
  __shared__ __attribute__((aligned(16))) unsigned short Bs[128*40];
  int tid = threadIdx.x;
  int rowBlk = blockIdx.x*128, colBlk = blockIdx.y*128;
  int w = tid >> 6, lane = tid & 63;
  int wrow = (w >> 1)*64, wcol = (w & 1)*64;
  int fr = lane & 15, fk = (lane >> 4)*8, fq = lane >> 4;
  int srh = tid >> 2, sk8 = (tid & 3)*8;

  f4v acc[4][4];
  #pragma unroll
  for (int r = 0; r < 4; r++)
    #pragma unroll
    for (int c = 0; c < 4; c++) acc[r][c] = (f4v){0.f, 0.f, 0.f, 0.f};

  for (int kt = 0; kt < K; kt += 32){
    __syncthreads();
    #pragma unroll
    for (int half = 0; half < 2; half++){
      int r = half*64 + srh;
      s8v av = (s8v){0,0,0,0,0,0,0,0};
      int ar = rowBlk + r;
      if (ar < M) av = *(const s8v*)(A + (long)ar*lda + kt + sk8);
      *(s8v*)&As[r*40 + sk8] = av;
      s8v bv = *(const s8v*)(Bt + (long)(colBlk + r)*K + kt + sk8);
      *(s8v*)&Bs[r*40 + sk8] = bv;
    }
    __syncthreads();
    s8v a[4], b[4];
    #pragma unroll
    for (int r = 0; r < 4; r++) a[r] = *(s8v*)&As[(wrow + r*16 + fr)*40 + fk];
    #pragma unroll
    for (int c = 0; c < 4; c++) b[c] = *(s8v*)&Bs[(wcol + c*16 + fr)*40 + fk];
    #pragma unroll
    for (int r = 0; r < 4; r++)
      #pragma unroll
      for (int c = 0; c < 4; c++)
        acc[r][c] = __builtin_amdgcn_mfma_f32_16x16x32_bf16(a[r], b[c], acc[r][c], 0, 0, 0);
  }

  #pragma unroll
  for (int c = 0; c < 4; c++){
    int col = colBlk + wcol + c*16 + fr;
    float bz = bias[col];
    #pragma unroll
    for (int r = 0; r < 4; r++){
      #pragma unroll
      for (int j = 0; j < 4; j++){
        int row = rowBlk + wrow + r*16 + fq*4 + j;
        if (row < M){
          float val = acc[r][c][j] + bz;
          if (ACT == 1) val = 0.5f * val * (1.0f + erff(val * 0.70710678118654752f));
          if (RES) val += res[(long)row*Nn + col];
          if (OUTBF) Cb[(long)row*Nn + col] = f2us(val);
          else       Cf[(long)row*Nn + col] = val;
        }
      }
    }
  }
}

// ---------------- fp32 GEMM (head only: 8 rows) ----------------
__global__ __launch_bounds__(256) void gemm_k(
    const float* __restrict__ A, long lda,
    const float* __restrict__ Bw, long ldb,
    const float* __restrict__ bias,
    float* __restrict__ Cf,
    int M, int Nn, int K)
{
  __shared__ float As[16][64];
  __shared__ float Bs[16][64];
  int tid = threadIdx.x;
  int tx = tid & 15, ty = tid >> 4;
  int rowBlk = blockIdx.x * 64, colBlk = blockIdx.y * 64;
  int am = tid >> 2, ak = (tid & 3) * 4;
  int bk = tid >> 4, bc = (tid & 15) * 4;
  float acc[4][4];
  #pragma unroll
  for (int i = 0; i < 4; i++)
    #pragma unroll
    for (int j = 0; j < 4; j++) acc[i][j] = 0.f;

  for (int kt = 0; kt < K; kt += 16){
    float4 av = make_float4(0.f, 0.f, 0.f, 0.f);
    int ar = rowBlk + am;
    if (ar < M) av = *(const float4*)(A + (long)ar*lda + kt + ak);
    As[ak+0][am] = av.x; As[ak+1][am] = av.y; As[ak+2][am] = av.z; As[ak+3][am] = av.w;
    float4 bv4 = *(const float4*)(Bw + (long)(kt + bk)*ldb + colBlk + bc);
    Bs[bk][bc+0] = bv4.x; Bs[bk][bc+1] = bv4.y;
    Bs[bk][bc+2] = bv4.z; Bs[bk][bc+3] = bv4.w;
    __syncthreads();
    #pragma unroll
    for (int kk = 0; kk < 16; kk++){
      float4 a4 = *(const float4*)&As[kk][ty*4];
      float4 b4 = *(const float4*)&Bs[kk][tx*4];
      acc[0][0] += a4.x*b4.x; acc[0][1] += a4.x*b4.y; acc[0][2] += a4.x*b4.z; acc[0][3] += a4.x*b4.w;
      acc[1][0] += a4.y*b4.x; acc[1][1] += a4.y*b4.y; acc[1][2] += a4.y*b4.z; acc[1][3] += a4.y*b4.w;
      acc[2][0] += a4.z*b4.x; acc[2][1] += a4.z*b4.y; acc[2][2] += a4.z*b4.z; acc[2][3] += a4.z*b4.w;
      acc[3][0] += a4.w*b4.x; acc[3][1] += a4.w*b4.y; acc[3][2] += a4.w*b4.z; acc[3][3] += a4.w*b4.w;
    }
    __syncthreads();
  }
  int r0 = rowBlk + ty*4, c0 = colBlk + tx*4;
  float bz[4];
  #pragma unroll
  for (int j = 0; j < 4; j++) bz[j] = bias[c0 + j];
  #pragma unroll
  for (int i = 0; i < 4; i++){
    int r = r0 + i;
    if (r < M){
      #pragma unroll
      for (int j = 0; j < 4; j++)
        Cf[(long)r*Nn + c0 + j] = acc[i][j] + bz[j];
    }
  }
}

// ---------------- small helpers ----------------
__global__ void initkm_k(unsigned* kmaxb){ kmaxb[0] = 0u; }

// ---------------- kmax via MFMA: xdT = projb @ K^T, masked max ----------------
__global__ __launch_bounds__(256) void kmax2_k(const float* __restrict__ kb,
    const unsigned short* __restrict__ projb, unsigned* __restrict__ kmaxb)
{
  __shared__ __attribute__((aligned(16))) unsigned short ks[64*40];
  __shared__ float red[4];
  int t = blockIdx.x, h = blockIdx.y, b = blockIdx.z;
  int tid = threadIdx.x, w = tid >> 6, lane = tid & 63;
  int fr = lane & 15, fq = lane >> 4, fk = fq*8;
  int n0 = t*64;
  // stage K tile bf16
  #pragma unroll
  for (int it = 0; it < 2; it++){
    int tok = it*32 + (tid >> 3), d4 = tid & 7;
    int n = n0 + tok;
    bool vld = (n < N_);
    long gb = ((long)(b*N_ + (vld ? n : 0)))*D_ + h*DH + d4*4;
    float4 kv = vld ? *(const float4*)(kb + gb) : make_float4(0,0,0,0);
    ushort4 ku; ku.x=f2us(kv.x); ku.y=f2us(kv.y); ku.z=f2us(kv.z); ku.w=f2us(kv.w);
    *(ushort4*)&ks[tok*40 + d4*4] = ku;
  }
  __syncthreads();
  // xdT for n-tile w
  s8v bk_ = *(s8v*)&ks[(w*16 + fr)*40 + fk];
  float mx = -INFINITY;
  int n_ = w*16 + fr;
  bool nv = (n0 + n_ < N_);
  #pragma unroll
  for (int mt = 0; mt < 7; mt++){
    s8v ap = *(const s8v*)(projb + (mt*16 + fr)*32 + fk);
    f4v z = (f4v){0.f,0.f,0.f,0.f};
    f4v xd = __builtin_amdgcn_mfma_f32_16x16x32_bf16(ap, bk_, z, 0, 0, 0);
    #pragma unroll
    for (int j = 0; j < 4; j++){
      int m = mt*16 + fq*4 + j;
      float v = (nv && m < M_) ? xd[j]*DN : -INFINITY;
      mx = fmaxf(mx, v);
    }
  }
  #pragma unroll
  for (int mk = 1; mk < 64; mk <<= 1) mx = fmaxf(mx, __shfl_xor(mx, mk));
  if (lane == 0) red[w] = mx;
  __syncthreads();
  if (tid == 0){
    float g = fmaxf(fmaxf(red[0], red[1]), fmaxf(red[2], red[3]));
    atomicMax(kmaxb, floatToOrdered(g));
  }
}

// ---------------- fused ctx via double MFMA ----------------
// phase1: xdT[m][n] = projb @ K^T ; exp -> kpT bf16 LDS
// phase2: ctx[m][d(+ksum)] += kpT @ V   (V staged transposed, row32 = ones)
__global__ __launch_bounds__(256) void fctx_k(const float* __restrict__ kb,
    const float* __restrict__ vb, const unsigned short* __restrict__ projb,
    const unsigned* __restrict__ kmaxb, float* __restrict__ partials)
{
  __shared__ __attribute__((aligned(16))) unsigned short ks[64*40];
  __shared__ __attribute__((aligned(16))) unsigned short vt[48*72];
  __shared__ __attribute__((aligned(16))) unsigned short kps[112*72];
  __shared__ float diags[64];
  int c = blockIdx.x, h = blockIdx.y, b = blockIdx.z;
  int tid = threadIdx.x, w = tid >> 6, lane = tid & 63;
  int fr = lane & 15, fq = lane >> 4, fk = fq*8;
  float kmax = orderedToFloat(kmaxb[0]);

  // one-time LDS init: vt rows 33..47 zero, row 32 ones
  for (int i = tid; i < 15*72; i += 256) vt[33*72 + i] = 0;
  if (tid < 64) vt[32*72 + tid] = f2us(1.0f);

  // persistent proj A-fragments
  s8v ap[7];
  #pragma unroll
  for (int mt = 0; mt < 7; mt++)
    ap[mt] = *(const s8v*)(projb + (mt*16 + fr)*32 + fk);

  int mt0 = w, mt1 = w + 4;         // wave w owns m-tiles {w, w+4} (mt1<7 only w<3)
  f4v acc0[3], acc1[3];
  #pragma unroll
  for (int dt = 0; dt < 3; dt++){ acc0[dt] = (f4v){0.f,0.f,0.f,0.f}; acc1[dt] = (f4v){0.f,0.f,0.f,0.f}; }

  for (int t = c; t < NTILES; t += NC){
    int n0 = t*64;
    __syncthreads();                 // prior phase-2 readers of vt/kps done
    // ---- stage: ks bf16, vt transposed bf16, diag fp32 ----
    #pragma unroll
    for (int it = 0; it < 2; it++){
      int tok = it*32 + (tid >> 3), d4 = tid & 7;
      int n = n0 + tok;
      bool vld = (n < N_);
      long gb = ((long)(b*N_ + (vld ? n : 0)))*D_ + h*DH + d4*4;
      float4 kv = vld ? *(const float4*)(kb + gb) : make_float4(0,0,0,0);
      float4 vv = vld ? *(const float4*)(vb + gb) : make_float4(0,0,0,0);
      ushort4 ku; ku.x=f2us(kv.x); ku.y=f2us(kv.y); ku.z=f2us(kv.z); ku.w=f2us(kv.w);
      *(ushort4*)&ks[tok*40 + d4*4] = ku;
      vt[(d4*4+0)*72 + tok] = f2us(vv.x);
      vt[(d4*4+1)*72 + tok] = f2us(vv.y);
      vt[(d4*4+2)*72 + tok] = f2us(vv.z);
      vt[(d4*4+3)*72 + tok] = f2us(vv.w);
      float sq = kv.x*kv.x + kv.y*kv.y + kv.z*kv.z + kv.w*kv.w;
      sq += __shfl_xor(sq, 1); sq += __shfl_xor(sq, 2); sq += __shfl_xor(sq, 4);
      if (d4 == 0) diags[tok] = 0.5f * DN2 * sq;
    }
    __syncthreads();
    // ---- phase 1: xdT for n-tile w; exp; write kpT ----
    s8v bk_ = *(s8v*)&ks[(w*16 + fr)*40 + fk];
    int n_ = w*16 + fr;
    bool nv = (n0 + n_ < N_);
    float dgn = diags[n_];
    #pragma unroll
    for (int mt = 0; mt < 7; mt++){
      f4v z = (f4v){0.f,0.f,0.f,0.f};
      f4v xd = __builtin_amdgcn_mfma_f32_16x16x32_bf16(ap[mt], bk_, z, 0, 0, 0);
      #pragma unroll
      for (int j = 0; j < 4; j++){
        float kp = nv ? RATIO*(expf(xd[j]*DN - dgn - kmax) + 1e-3f) : 0.f;
        kps[(mt*16 + fq*4 + j)*72 + n_] = f2us(kp);
      }
    }
    __syncthreads();
    // ---- phase 2: ctx += kpT @ V (K=64 over tokens) ----
    #pragma unroll
    for (int kst = 0; kst < 2; kst++){
      int ko = kst*32 + fk;
      s8v b0 = *(s8v*)&vt[( 0 + fr)*72 + ko];
      s8v b1 = *(s8v*)&vt[(16 + fr)*72 + ko];
      s8v b2 = *(s8v*)&vt[(32 + fr)*72 + ko];
      s8v a0 = *(s8v*)&kps[(mt0*16 + fr)*72 + ko];
      acc0[0] = __builtin_amdgcn_mfma_f32_16x16x32_bf16(a0, b0, acc0[0], 0, 0, 0);
      acc0[1] = __builtin_amdgcn_mfma_f32_16x16x32_bf16(a0, b1, acc0[1], 0, 0, 0);
      acc0[2] = __builtin_amdgcn_mfma_f32_16x16x32_bf16(a0, b2, acc0[2], 0, 0, 0);
      if (mt1 < 7){
        s8v a1 = *(s8v*)&kps[(mt1*16 + fr)*72 + ko];
        acc1[0] = __builtin_amdgcn_mfma_f32_16x16x32_bf16(a1, b0, acc1[0], 0, 0, 0);
        acc1[1] = __builtin_amdgcn_mfma_f32_16x16x32_bf16(a1, b1, acc1[1], 0, 0, 0);
        acc1[2] = __builtin_amdgcn_mfma_f32_16x16x32_bf16(a1, b2, acc1[2], 0, 0, 0);
      }
    }
  }
  // ---- writeout partials: rows m<110, cols d<33 (d=32 is ksum) ----
  long pb = ((long)c*64 + (b*H_ + h))*CTXE;
  #pragma unroll
  for (int dt = 0; dt < 3; dt++){
    int d = dt*16 + fr;
    if (d < 33){
      #pragma unroll
      for (int j = 0; j < 4; j++){
        int m0 = mt0*16 + fq*4 + j;
        if (m0 < M_) partials[pb + m0*33 + d] = acc0[dt][j];
        if (mt1 < 7){
          int m1 = mt1*16 + fq*4 + j;
          if (m1 < M_) partials[pb + m1*33 + d] = acc1[dt][j];
        }
      }
    }
  }
}

// ---------------- ctx partial reduce ----------------
__global__ __launch_bounds__(256) void ctxred2_k(const float* __restrict__ partials,
                                                 float* __restrict__ ctxf)
{
  int i = blockIdx.x*256 + threadIdx.x;
  if (i >= CTXN2) return;
  float s = 0.f;
  #pragma unroll
  for (int c = 0; c < NC; c++) s += partials[(long)c*CTXN2 + i];
  ctxf[i] = s;
}

// ---------------- attn v2: 64-token blocks, bf16 output (unchanged) ----------------
__global__ __launch_bounds__(256) void attn2_k(const float* __restrict__ qb,
    const float* __restrict__ ctxf, const float* __restrict__ proj,
    unsigned short* __restrict__ ob)
{
  __shared__ float qs[NTOK*36];
  __shared__ float xp[NTOK*113];
  __shared__ float cs[M_*36];
  __shared__ float rmx[NTOK], dg[NTOK];
  int t = blockIdx.x, h = blockIdx.y, b = blockIdx.z;
  int tid = threadIdx.x;
  long cbase = ((long)(b*H_ + h))*CTXE;
  for (int i = tid; i < CTXE; i += 256){
    int mm = i / 33, dd = i - mm*33;
    cs[mm*36 + dd] = ctxf[cbase + i];
  }
  int n0 = t*NTOK;
  int nt = min(NTOK, N_ - n0);
  #pragma unroll
  for (int it = 0; it < 2; it++){
    int tok = it*32 + (tid >> 3);
    int d4  = tid & 7;
    int ncl = n0 + min(tok, nt - 1);
    float4 qv = *(const float4*)(qb + ((long)(b*N_ + ncl))*D_ + h*DH + d4*4);
    *(float4*)(qs + tok*36 + d4*4) = qv;
  }
  int mslot = tid >> 1, dh = tid & 1;
  bool act = (mslot < M_);
  int m = act ? mslot : 0;
  float pm[32];
  #pragma unroll
  for (int j = 0; j < 8; j++){
    float4 p4 = *(const float4*)(proj + m*DH + j*4);
    pm[j*4+0]=p4.x; pm[j*4+1]=p4.y; pm[j*4+2]=p4.z; pm[j*4+3]=p4.w;
  }
  __syncthreads();
  if (act){
    for (int n = dh; n < nt; n += 2){
      float s = 0.f;
      #pragma unroll
      for (int j = 0; j < 8; j++){
        float4 q4 = *(const float4*)(qs + n*36 + j*4);
        s += q4.x*pm[j*4+0] + q4.y*pm[j*4+1] + q4.z*pm[j*4+2] + q4.w*pm[j*4+3];
      }
      xp[n*113 + m] = s * DN;
    }
  }
  __syncthreads();
  if (tid < nt){
    int n = tid;
    float sq = 0.f;
    #pragma unroll
    for (int j = 0; j < 8; j++){
      float4 q4 = *(const float4*)(qs + n*36 + j*4);
      sq += q4.x*q4.x + q4.y*q4.y + q4.z*q4.z + q4.w*q4.w;
    }
    dg[n] = 0.5f * DN2 * sq;
    float mx = -INFINITY;
    for (int mm = 0; mm < M_; mm++) mx = fmaxf(mx, xp[n*113 + mm]);
    rmx[n] = mx;
  }
  __syncthreads();
  for (int i = tid; i < NTOK*M_; i += 256){
    int n = i & 63, mm = i >> 6;
    if (n < nt)
      xp[n*113 + mm] = RATIO * (expf(xp[n*113 + mm] - dg[n] - rmx[n]) + 1e-3f);
  }
  __syncthreads();
  int n2 = tid >> 2, dq = tid & 3, db = dq*8;
  if (n2 < nt){
    float o[8];
    #pragma unroll
    for (int j = 0; j < 8; j++) o[j] = 0.f;
    float den = 0.f;
    for (int mm = 0; mm < M_; mm++){
      float qp = xp[n2*113 + mm];
      den += qp * cs[mm*36 + 32];
      float4 c0 = *(const float4*)(cs + mm*36 + db);
      float4 c1 = *(const float4*)(cs + mm*36 + db + 4);
      o[0] += qp*c0.x; o[1] += qp*c0.y; o[2] += qp*c0.z; o[3] += qp*c0.w;
      o[4] += qp*c1.x; o[5] += qp*c1.y; o[6] += qp*c1.z; o[7] += qp*c1.w;
    }
    float dinv = 1.0f / den;
    long obase = ((long)(b*N_ + n0 + n2))*D_ + h*DH + db;
    ushort4 w0, w1;
    w0.x = f2us(o[0]*dinv); w0.y = f2us(o[1]*dinv); w0.z = f2us(o[2]*dinv); w0.w = f2us(o[3]*dinv);
    w1.x = f2us(o[4]*dinv); w1.y = f2us(o[5]*dinv); w1.z = f2us(o[6]*dinv); w1.w = f2us(o[7]*dinv);
    *(ushort4*)(ob + obase)     = w0;
    *(ushort4*)(ob + obase + 4) = w1;
  }
}

// ---------------- host ----------------
extern "C" void kernel_launch(void* const* d_in, const int* in_sizes, int n_in,
                              void* d_out, int out_size, void* d_ws, size_t ws_size,
                              hipStream_t stream)
{
  const float* expr = (const float*)d_in[0];
  const float* temb = (const float*)d_in[1];
  const float* cls  = (const float*)d_in[2];
  const float* ln1g = (const float*)d_in[3];
  const float* ln1b = (const float*)d_in[4];
  const float* Wq   = (const float*)d_in[5];
  const float* bq   = (const float*)d_in[6];
  const float* Wk   = (const float*)d_in[7];
  const float* bk   = (const float*)d_in[8];
  const float* Wv   = (const float*)d_in[9];
  const float* bv   = (const float*)d_in[10];
  const float* Wo   = (const float*)d_in[11];
  const float* bo   = (const float*)d_in[12];
  const float* ln2g = (const float*)d_in[13];
  const float* ln2b = (const float*)d_in[14];
  const float* W1   = (const float*)d_in[15];
  const float* b1   = (const float*)d_in[16];
  const float* W2   = (const float*)d_in[17];
  const float* b2   = (const float*)d_in[18];
  const float* proj = (const float*)d_in[19];
  const float* Wp   = (const float*)d_in[20];
  const float* bp   = (const float*)d_in[21];
  (void)in_sizes; (void)n_in; (void)out_size; (void)ws_size;

  char* w = (char*)d_ws;
  size_t off = 0;
  auto alloc = [&](size_t bytes) -> char* {
    char* p = w + off;
    off = (off + bytes + 255) & ~(size_t)255;
    return p;
  };
  float*    selected = (float*)alloc((size_t)B_*KSEL*4);
  float*    bsum     = (float*)alloc(B_*4);
  float*    bv0      = (float*)alloc(B_*4);
  float*    emaxp    = (float*)alloc(4);
  unsigned* kmaxb    = (unsigned*)alloc(4);
  float*    ctxf     = (float*)alloc((size_t)CTXN2*4);
  float*          x  = (float*)alloc((size_t)BN_*D_*4);
  unsigned short* h  = (unsigned short*)alloc((size_t)BN_*D_*2);
  float*          q  = (float*)alloc((size_t)BN_*D_*4);
  float*          k  = (float*)alloc((size_t)BN_*D_*4);
  float*          v  = (float*)alloc((size_t)BN_*D_*4);
  unsigned short* Wqt = (unsigned short*)alloc((size_t)DEPTH_*D_*D_*2);
  unsigned short* Wkt = (unsigned short*)alloc((size_t)DEPTH_*D_*D_*2);
  unsigned short* Wvt = (unsigned short*)alloc((size_t)DEPTH_*D_*D_*2);
  unsigned short* Wot = (unsigned short*)alloc((size_t)DEPTH_*D_*D_*2);
  unsigned short* W1t = (unsigned short*)alloc((size_t)DEPTH_*D_*DFF_*2);
  unsigned short* W2t = (unsigned short*)alloc((size_t)DEPTH_*DFF_*D_*2);
  unsigned short* projb = (unsigned short*)alloc((size_t)DEPTH_*112*32*2);
  unsigned short* ffi = (unsigned short*)k;  // bf16 [BN][1024] aliases k+v (dead during FFN)
  float*     partials = (float*)h;           // NC*CTXN2*4 = 7.44 MB <= h (8.39 MB)

  // one-time weight/proj conversions
  wcvt_k<<<dim3(8, 8, DEPTH_),  256, 0, stream>>>(Wq, (long)D_*D_,   Wqt, (long)D_*D_,   D_, D_);
  wcvt_k<<<dim3(8, 8, DEPTH_),  256, 0, stream>>>(Wk, (long)D_*D_,   Wkt, (long)D_*D_,   D_, D_);
  wcvt_k<<<dim3(8, 8, DEPTH_),  256, 0, stream>>>(Wv, (long)D_*D_,   Wvt, (long)D_*D_,   D_, D_);
  wcvt_k<<<dim3(8, 8, DEPTH_),  256, 0, stream>>>(Wo, (long)D_*D_,   Wot, (long)D_*D_,   D_, D_);
  wcvt_k<<<dim3(32, 8, DEPTH_), 256, 0, stream>>>(W1, (long)D_*DFF_, W1t, (long)D_*DFF_, D_, DFF_);
  wcvt_k<<<dim3(8, 32, DEPTH_), 256, 0, stream>>>(W2, (long)DFF_*D_, W2t, (long)DFF_*D_, DFF_, D_);
  pcvt_k<<<DEPTH_, 256, 0, stream>>>(proj, projb);

  topk_k<<<B_, 256, 0, stream>>>(expr, selected);
  nsum_k<<<B_, 256, 0, stream>>>(selected, bsum, bv0);
  emax_k<<<1, 64, 0, stream>>>(bsum, bv0, emaxp);
  embed_k<<<BN_, 64, 0, stream>>>(selected, bsum, emaxp, temb, cls, x);

  for (int L = 0; L < DEPTH_; L++){
    const float* pj = proj + (size_t)L*M_*DH;
    const unsigned short* pjb = projb + (size_t)L*112*32;
    ln_k<<<BN_/4, 256, 0, stream>>>(x, h, ln1g + L*D_, ln1b + L*D_);
    bgemm_k<0,0,0><<<dim3(129,2), 256, 0, stream>>>(h, D_, Wqt + (size_t)L*D_*D_, bq + L*D_, nullptr, q, nullptr, BN_, D_, D_);
    bgemm_k<0,0,0><<<dim3(129,2), 256, 0, stream>>>(h, D_, Wkt + (size_t)L*D_*D_, bk + L*D_, nullptr, k, nullptr, BN_, D_, D_);
    bgemm_k<0,0,0><<<dim3(129,2), 256, 0, stream>>>(h, D_, Wvt + (size_t)L*D_*D_, bv + L*D_, nullptr, v, nullptr, BN_, D_, D_);
    initkm_k<<<1, 1, 0, stream>>>(kmaxb);
    kmax2_k<<<dim3(NTILES, H_, B_), 256, 0, stream>>>(k, pjb, kmaxb);
    fctx_k<<<dim3(NC, H_, B_), 256, 0, stream>>>(k, v, pjb, kmaxb, partials);
    ctxred2_k<<<(CTXN2 + 255)/256, 256, 0, stream>>>(partials, ctxf);
    attn2_k<<<dim3(33, H_, B_), 256, 0, stream>>>(q, ctxf, pj, h);   // o -> h (bf16)
    bgemm_k<0,1,0><<<dim3(129,2), 256, 0, stream>>>(h, D_, Wot + (size_t)L*D_*D_, bo + L*D_, x, x, nullptr, BN_, D_, D_);
    ln_k<<<BN_/4, 256, 0, stream>>>(x, h, ln2g + L*D_, ln2b + L*D_);
    bgemm_k<1,0,1><<<dim3(129,8), 256, 0, stream>>>(h, D_, W1t + (size_t)L*D_*DFF_, b1 + L*DFF_, nullptr, nullptr, ffi, BN_, DFF_, D_);
    bgemm_k<0,1,0><<<dim3(129,2), 256, 0, stream>>>(ffi, DFF_, W2t + (size_t)L*DFF_*D_, b2 + L*D_, x, x, nullptr, BN_, D_, DFF_);
  }
  gemm_k<<<dim3(1,4), 256, 0, stream>>>(x, (long)N_*D_, Wp, D_, bp,
                                        (float*)d_out, B_, D_, D_);
}

// Round 11
// 1753.523 us; speedup vs baseline: 4.4869x; 1.2216x over previous
//
#include <hip/hip_runtime.h>
#include <hip/hip_bf16.h>

#define B_    8
#define NG    16906
#define KSEL  2048
#define D_    256
#define H_    8
#define DH    32
#define M_    110
#define DEPTH_ 6
#define DFF_  1024
#define N_    2049
#define BN_   (B_*N_)
#define NTOK  64
#define NC    8            // fctx chunks (blocks per (b,h))
#define NTILES 33          // ceil(2049/64)
#define CTXE  (M_*33)      // 3630 per (b,h)
#define CTXN2 (64*CTXE)    // 232320
#define NIT_TK 67          // ceil(16906/256)

static constexpr float DN    = 0.42044820762685725f;  // 32^-0.25
static constexpr float DN2   = 0.17677669529663687f;  // 32^-0.5
static constexpr float RATIO = 0.09534625892455922f;  // 110^-0.5

typedef __attribute__((ext_vector_type(8))) short s8v;
typedef __attribute__((ext_vector_type(4))) float f4v;

__device__ __forceinline__ unsigned floatToOrdered(float f){
  unsigned b = __float_as_uint(f);
  return (b & 0x80000000u) ? ~b : (b | 0x80000000u);
}
__device__ __forceinline__ float orderedToFloat(unsigned u){
  unsigned b = (u & 0x80000000u) ? (u & 0x7FFFFFFFu) : ~u;
  return __uint_as_float(b);
}
__device__ __forceinline__ unsigned short f2us(float f){
  __hip_bfloat16 b = __float2bfloat16(f);
  return *reinterpret_cast<unsigned short*>(&b);
}

// ---------------- top-k: radix select, row cached in registers ----------------
__global__ __launch_bounds__(256) void topk_k(const float* __restrict__ expr,
                                              float* __restrict__ selected)
{
  __shared__ unsigned hist[256];
  __shared__ unsigned sPrefix;
  __shared__ int sKK;
  __shared__ unsigned cGT, cEQ;
  int b = blockIdx.x, tid = threadIdx.x;
  const float* row = expr + (long)b*NG;
  unsigned rb[NIT_TK];
  #pragma unroll
  for (int i = 0; i < NIT_TK; i++){
    int idx = tid + i*256;
    rb[i] = (idx < NG) ? __float_as_uint(row[idx]) : 0u;
  }
  if (tid == 0){ sPrefix = 0u; sKK = KSEL; }
  __syncthreads();
  for (int pass = 0; pass < 4; ++pass){
    int shift = 24 - pass*8;
    hist[tid] = 0u;
    __syncthreads();
    unsigned pref = sPrefix;
    #pragma unroll
    for (int i = 0; i < NIT_TK; i++){
      int idx = tid + i*256;
      unsigned bits = rb[i];
      bool ok = (idx < NG) && ((pass == 0) || ((bits >> (shift + 8)) == pref));
      if (ok) atomicAdd(&hist[(bits >> shift) & 255u], 1u);
    }
    __syncthreads();
    if (tid == 0){
      int kk = sKK; unsigned cum = 0; int sel = 0;
      for (int j = 255; j >= 0; --j){
        unsigned c = hist[j];
        if (cum + c >= (unsigned)kk){ sel = j; break; }
        cum += c;
      }
      sPrefix = (pref << 8) | (unsigned)sel;
      sKK = kk - (int)cum;
    }
    __syncthreads();
  }
  unsigned T = sPrefix; int needEQ = sKK; int base = KSEL - needEQ;
  if (tid == 0){ cGT = 0u; cEQ = 0u; }
  __syncthreads();
  #pragma unroll
  for (int i = 0; i < NIT_TK; i++){
    int idx = tid + i*256;
    if (idx < NG){
      unsigned bits = rb[i];
      if (bits > T){
        unsigned p = atomicAdd(&cGT, 1u);
        selected[(long)b*KSEL + p] = __uint_as_float(bits);
      } else if (bits == T){
        unsigned p = atomicAdd(&cEQ, 1u);
        if ((int)p < needEQ) selected[(long)b*KSEL + base + p] = __uint_as_float(bits);
      }
    }
  }
}

// ---------------- per-batch sum + max of selected ----------------
__global__ __launch_bounds__(256) void nsum_k(const float* __restrict__ selected,
                                              float* __restrict__ bsum, float* __restrict__ bv0)
{
  __shared__ float rs[256], rm[256];
  int b = blockIdx.x, tid = threadIdx.x;
  float s = 0.f, m = -INFINITY;
  for (int i = tid; i < KSEL; i += 256){ float v = selected[(long)b*KSEL + i]; s += v; m = fmaxf(m, v); }
  rs[tid] = s; rm[tid] = m; __syncthreads();
  for (int k = 128; k > 0; k >>= 1){
    if (tid < k){ rs[tid] += rs[tid + k]; rm[tid] = fmaxf(rm[tid], rm[tid + k]); }
    __syncthreads();
  }
  if (tid == 0){ bsum[b] = rs[0]; bv0[b] = rm[0]; }
}

// ---------------- global max of e = log1p(v0/sum*1e4) ----------------
__global__ __launch_bounds__(64) void emax_k(const float* __restrict__ bsum,
                                             const float* __restrict__ bv0,
                                             float* __restrict__ emaxp)
{
  int tid = threadIdx.x;
  float e = -INFINITY;
  if (tid < B_) e = log1pf(bv0[tid] / fmaxf(bsum[tid], 1e-12f) * 10000.0f);
  #pragma unroll
  for (int m = 1; m < 64; m <<= 1) e = fmaxf(e, __shfl_xor(e, m));
  if (tid == 0) emaxp[0] = e;
}

// ---------------- tokenize + embed ----------------
__global__ __launch_bounds__(64) void embed_k(const float* __restrict__ selected,
    const float* __restrict__ bsum, const float* __restrict__ emaxp,
    const float* __restrict__ temb, const float* __restrict__ cls,
    float* __restrict__ x)
{
  int rowi = blockIdx.x;
  int b = rowi / N_, n = rowi % N_;
  int tid = threadIdx.x;
  const float* src;
  if (n == 0){
    src = cls;
  } else {
    float val = selected[(long)b*KSEL + (n - 1)];
    float e = log1pf(val / fmaxf(bsum[b], 1e-12f) * 10000.0f);
    float step = emaxp[0] / 7.0f;              // matches jnp.linspace step
    int cnt = 0;
    #pragma unroll
    for (int i = 0; i < 7; i++) cnt += (((float)i * step) < e) ? 1 : 0;  // searchsorted 'left'
    int tok = cnt > 6 ? 6 : cnt;
    src = temb + (long)tok * D_;
  }
  float4 o = *(const float4*)(src + tid*4);
  *(float4*)(x + (long)rowi*D_ + tid*4) = o;
}

// ---------------- LayerNorm: one wave per row, bf16 output ----------------
__global__ __launch_bounds__(256) void ln_k(const float* __restrict__ x,
    unsigned short* __restrict__ out,
    const float* __restrict__ g, const float* __restrict__ bb)
{
  int row = blockIdx.x*4 + (threadIdx.x >> 6);
  int lane = threadIdx.x & 63;
  float4 v = *(const float4*)(x + (long)row*D_ + lane*4);
  float s = v.x + v.y + v.z + v.w;
  float q = v.x*v.x + v.y*v.y + v.z*v.z + v.w*v.w;
  #pragma unroll
  for (int m = 1; m < 64; m <<= 1){ s += __shfl_xor(s, m); q += __shfl_xor(q, m); }
  float mu  = s * (1.0f/D_);
  float var = q * (1.0f/D_) - mu*mu;
  float inv = 1.0f / sqrtf(fmaxf(var, 0.f) + 1e-5f);
  float4 gu = *(const float4*)(g + lane*4);
  float4 bu = *(const float4*)(bb + lane*4);
  ushort4 o;
  o.x = f2us((v.x - mu)*inv*gu.x + bu.x);
  o.y = f2us((v.y - mu)*inv*gu.y + bu.y);
  o.z = f2us((v.z - mu)*inv*gu.z + bu.z);
  o.w = f2us((v.w - mu)*inv*gu.w + bu.w);
  *(ushort4*)(out + (long)row*D_ + lane*4) = o;
}

// ---------------- weight convert + transpose: dst[n][k] = bf16(src[k][n]) ----------------
__global__ __launch_bounds__(256) void wcvt_k(const float* __restrict__ src, long srcL,
    unsigned short* __restrict__ dst, long dstL, int K, int N)
{
  __shared__ float t[32][33];
  int n0 = blockIdx.x*32, k0 = blockIdx.y*32, L = blockIdx.z;
  int tx = threadIdx.x & 31, ty = threadIdx.x >> 5;
  const float* s = src + (long)L*srcL;
  for (int i = ty; i < 32; i += 8)
    t[i][tx] = s[(long)(k0+i)*N + n0 + tx];
  __syncthreads();
  unsigned short* d = dst + (long)L*dstL;
  for (int i = ty; i < 32; i += 8)
    d[(long)(n0 + i)*K + k0 + tx] = f2us(t[tx][i]);
}

// ---------------- proj convert: projb[L][112][32] bf16, zero-padded rows ----------------
__global__ __launch_bounds__(256) void pcvt_k(const float* __restrict__ proj,
                                              unsigned short* __restrict__ projb)
{
  int L = blockIdx.x;
  for (int i = threadIdx.x; i < 112*32; i += 256){
    int m = i >> 5, d = i & 31;
    float v = (m < M_) ? proj[(long)L*M_*DH + m*DH + d] : 0.f;
    projb[(long)L*112*32 + i] = f2us(v);
  }
}

// ---------------- bf16 MFMA GEMM (validated round 9) ----------------
template<int ACT, int RES, int OUTBF>
__global__ __launch_bounds__(256) void bgemm_k(
    const unsigned short* __restrict__ A, long lda,
    const unsigned short* __restrict__ Bt,
    const float* __restrict__ bias,
    const float* __restrict__ res,
    float* __restrict__ Cf, unsigned short* __restrict__ Cb,
    int M, int Nn, int K)
{
  __shared__ __attribute__((aligned(16))) unsigned short As[128*40];
  __shared__ __attribute__((aligned(16))) unsigned short Bs[128*40];
  int tid = threadIdx.x;
  int rowBlk = blockIdx.x*128, colBlk = blockIdx.y*128;
  int w = tid >> 6, lane = tid & 63;
  int wrow = (w >> 1)*64, wcol = (w & 1)*64;
  int fr = lane & 15, fk = (lane >> 4)*8, fq = lane >> 4;
  int srh = tid >> 2, sk8 = (tid & 3)*8;

  f4v acc[4][4];
  #pragma unroll
  for (int r = 0; r < 4; r++)
    #pragma unroll
    for (int c = 0; c < 4; c++) acc[r][c] = (f4v){0.f, 0.f, 0.f, 0.f};

  for (int kt = 0; kt < K; kt += 32){
    __syncthreads();
    #pragma unroll
    for (int half = 0; half < 2; half++){
      int r = half*64 + srh;
      s8v av = (s8v){0,0,0,0,0,0,0,0};
      int ar = rowBlk + r;
      if (ar < M) av = *(const s8v*)(A + (long)ar*lda + kt + sk8);
      *(s8v*)&As[r*40 + sk8] = av;
      s8v bv = *(const s8v*)(Bt + (long)(colBlk + r)*K + kt + sk8);
      *(s8v*)&Bs[r*40 + sk8] = bv;
    }
    __syncthreads();
    s8v a[4], b[4];
    #pragma unroll
    for (int r = 0; r < 4; r++) a[r] = *(s8v*)&As[(wrow + r*16 + fr)*40 + fk];
    #pragma unroll
    for (int c = 0; c < 4; c++) b[c] = *(s8v*)&Bs[(wcol + c*16 + fr)*40 + fk];
    #pragma unroll
    for (int r = 0; r < 4; r++)
      #pragma unroll
      for (int c = 0; c < 4; c++)
        acc[r][c] = __builtin_amdgcn_mfma_f32_16x16x32_bf16(a[r], b[c], acc[r][c], 0, 0, 0);
  }

  #pragma unroll
  for (int c = 0; c < 4; c++){
    int col = colBlk + wcol + c*16 + fr;
    float bz = bias[col];
    #pragma unroll
    for (int r = 0; r < 4; r++){
      #pragma unroll
      for (int j = 0; j < 4; j++){
        int row = rowBlk + wrow + r*16 + fq*4 + j;
        if (row < M){
          float val = acc[r][c][j] + bz;
          if (ACT == 1) val = 0.5f * val * (1.0f + erff(val * 0.70710678118654752f));
          if (RES) val += res[(long)row*Nn + col];
          if (OUTBF) Cb[(long)row*Nn + col] = f2us(val);
          else       Cf[(long)row*Nn + col] = val;
        }
      }
    }
  }
}

// ---------------- fp32 GEMM (head only: 8 rows) ----------------
__global__ __launch_bounds__(256) void gemm_k(
    const float* __restrict__ A, long lda,
    const float* __restrict__ Bw, long ldb,
    const float* __restrict__ bias,
    float* __restrict__ Cf,
    int M, int Nn, int K)
{
  __shared__ float As[16][64];
  __shared__ float Bs[16][64];
  int tid = threadIdx.x;
  int tx = tid & 15, ty = tid >> 4;
  int rowBlk = blockIdx.x * 64, colBlk = blockIdx.y * 64;
  int am = tid >> 2, ak = (tid & 3) * 4;
  int bk = tid >> 4, bc = (tid & 15) * 4;
  float acc[4][4];
  #pragma unroll
  for (int i = 0; i < 4; i++)
    #pragma unroll
    for (int j = 0; j < 4; j++) acc[i][j] = 0.f;

  for (int kt = 0; kt < K; kt += 16){
    float4 av = make_float4(0.f, 0.f, 0.f, 0.f);
    int ar = rowBlk + am;
    if (ar < M) av = *(const float4*)(A + (long)ar*lda + kt + ak);
    As[ak+0][am] = av.x; As[ak+1][am] = av.y; As[ak+2][am] = av.z; As[ak+3][am] = av.w;
    float4 bv4 = *(const float4*)(Bw + (long)(kt + bk)*ldb + colBlk + bc);
    Bs[bk][bc+0] = bv4.x; Bs[bk][bc+1] = bv4.y;
    Bs[bk][bc+2] = bv4.z; Bs[bk][bc+3] = bv4.w;
    __syncthreads();
    #pragma unroll
    for (int kk = 0; kk < 16; kk++){
      float4 a4 = *(const float4*)&As[kk][ty*4];
      float4 b4 = *(const float4*)&Bs[kk][tx*4];
      acc[0][0] += a4.x*b4.x; acc[0][1] += a4.x*b4.y; acc[0][2] += a4.x*b4.z; acc[0][3] += a4.x*b4.w;
      acc[1][0] += a4.y*b4.x; acc[1][1] += a4.y*b4.y; acc[1][2] += a4.y*b4.z; acc[1][3] += a4.y*b4.w;
      acc[2][0] += a4.z*b4.x; acc[2][1] += a4.z*b4.y; acc[2][2] += a4.z*b4.z; acc[2][3] += a4.z*b4.w;
      acc[3][0] += a4.w*b4.x; acc[3][1] += a4.w*b4.y; acc[3][2] += a4.w*b4.z; acc[3][3] += a4.w*b4.w;
    }
    __syncthreads();
  }
  int r0 = rowBlk + ty*4, c0 = colBlk + tx*4;
  float bz[4];
  #pragma unroll
  for (int j = 0; j < 4; j++) bz[j] = bias[c0 + j];
  #pragma unroll
  for (int i = 0; i < 4; i++){
    int r = r0 + i;
    if (r < M){
      #pragma unroll
      for (int j = 0; j < 4; j++)
        Cf[(long)r*Nn + c0 + j] = acc[i][j] + bz[j];
    }
  }
}

// ---------------- small helpers ----------------
__global__ void initkm_k(unsigned* kmaxb){ kmaxb[0] = 0u; }

// ---------------- kmax via MFMA ----------------
__global__ __launch_bounds__(256) void kmax2_k(const float* __restrict__ kb,
    const unsigned short* __restrict__ projb, unsigned* __restrict__ kmaxb)
{
  __shared__ __attribute__((aligned(16))) unsigned short ks[64*40];
  __shared__ float red[4];
  int t = blockIdx.x, h = blockIdx.y, b = blockIdx.z;
  int tid = threadIdx.x, w = tid >> 6, lane = tid & 63;
  int fr = lane & 15, fq = lane >> 4, fk = fq*8;
  int n0 = t*64;
  #pragma unroll
  for (int it = 0; it < 2; it++){
    int tok = it*32 + (tid >> 3), d4 = tid & 7;
    int n = n0 + tok;
    bool vld = (n < N_);
    long gb = ((long)(b*N_ + (vld ? n : 0)))*D_ + h*DH + d4*4;
    float4 kv = vld ? *(const float4*)(kb + gb) : make_float4(0,0,0,0);
    ushort4 ku; ku.x=f2us(kv.x); ku.y=f2us(kv.y); ku.z=f2us(kv.z); ku.w=f2us(kv.w);
    *(ushort4*)&ks[tok*40 + d4*4] = ku;
  }
  __syncthreads();
  s8v bk_ = *(s8v*)&ks[(w*16 + fr)*40 + fk];
  float mx = -INFINITY;
  int n_ = w*16 + fr;
  bool nv = (n0 + n_ < N_);
  #pragma unroll
  for (int mt = 0; mt < 7; mt++){
    s8v ap = *(const s8v*)(projb + (mt*16 + fr)*32 + fk);
    f4v z = (f4v){0.f,0.f,0.f,0.f};
    f4v xd = __builtin_amdgcn_mfma_f32_16x16x32_bf16(ap, bk_, z, 0, 0, 0);
    #pragma unroll
    for (int j = 0; j < 4; j++){
      int m = mt*16 + fq*4 + j;
      float v = (nv && m < M_) ? xd[j]*DN : -INFINITY;
      mx = fmaxf(mx, v);
    }
  }
  #pragma unroll
  for (int mk = 1; mk < 64; mk <<= 1) mx = fmaxf(mx, __shfl_xor(mx, mk));
  if (lane == 0) red[w] = mx;
  __syncthreads();
  if (tid == 0){
    float g = fmaxf(fmaxf(red[0], red[1]), fmaxf(red[2], red[3]));
    atomicMax(kmaxb, floatToOrdered(g));
  }
}

// ---------------- fused ctx via double MFMA (validated round 10) ----------------
__global__ __launch_bounds__(256) void fctx_k(const float* __restrict__ kb,
    const float* __restrict__ vb, const unsigned short* __restrict__ projb,
    const unsigned* __restrict__ kmaxb, float* __restrict__ partials)
{
  __shared__ __attribute__((aligned(16))) unsigned short ks[64*40];
  __shared__ __attribute__((aligned(16))) unsigned short vt[48*72];
  __shared__ __attribute__((aligned(16))) unsigned short kps[112*72];
  __shared__ float diags[64];
  int c = blockIdx.x, h = blockIdx.y, b = blockIdx.z;
  int tid = threadIdx.x, w = tid >> 6, lane = tid & 63;
  int fr = lane & 15, fq = lane >> 4, fk = fq*8;
  float kmax = orderedToFloat(kmaxb[0]);

  for (int i = tid; i < 15*72; i += 256) vt[33*72 + i] = 0;
  if (tid < 64) vt[32*72 + tid] = f2us(1.0f);

  s8v ap[7];
  #pragma unroll
  for (int mt = 0; mt < 7; mt++)
    ap[mt] = *(const s8v*)(projb + (mt*16 + fr)*32 + fk);

  int mt0 = w, mt1 = w + 4;
  f4v acc0[3], acc1[3];
  #pragma unroll
  for (int dt = 0; dt < 3; dt++){ acc0[dt] = (f4v){0.f,0.f,0.f,0.f}; acc1[dt] = (f4v){0.f,0.f,0.f,0.f}; }

  for (int t = c; t < NTILES; t += NC){
    int n0 = t*64;
    __syncthreads();
    #pragma unroll
    for (int it = 0; it < 2; it++){
      int tok = it*32 + (tid >> 3), d4 = tid & 7;
      int n = n0 + tok;
      bool vld = (n < N_);
      long gb = ((long)(b*N_ + (vld ? n : 0)))*D_ + h*DH + d4*4;
      float4 kv = vld ? *(const float4*)(kb + gb) : make_float4(0,0,0,0);
      float4 vv = vld ? *(const float4*)(vb + gb) : make_float4(0,0,0,0);
      ushort4 ku; ku.x=f2us(kv.x); ku.y=f2us(kv.y); ku.z=f2us(kv.z); ku.w=f2us(kv.w);
      *(ushort4*)&ks[tok*40 + d4*4] = ku;
      vt[(d4*4+0)*72 + tok] = f2us(vv.x);
      vt[(d4*4+1)*72 + tok] = f2us(vv.y);
      vt[(d4*4+2)*72 + tok] = f2us(vv.z);
      vt[(d4*4+3)*72 + tok] = f2us(vv.w);
      float sq = kv.x*kv.x + kv.y*kv.y + kv.z*kv.z + kv.w*kv.w;
      sq += __shfl_xor(sq, 1); sq += __shfl_xor(sq, 2); sq += __shfl_xor(sq, 4);
      if (d4 == 0) diags[tok] = 0.5f * DN2 * sq;
    }
    __syncthreads();
    s8v bk_ = *(s8v*)&ks[(w*16 + fr)*40 + fk];
    int n_ = w*16 + fr;
    bool nv = (n0 + n_ < N_);
    float dgn = diags[n_];
    #pragma unroll
    for (int mt = 0; mt < 7; mt++){
      f4v z = (f4v){0.f,0.f,0.f,0.f};
      f4v xd = __builtin_amdgcn_mfma_f32_16x16x32_bf16(ap[mt], bk_, z, 0, 0, 0);
      #pragma unroll
      for (int j = 0; j < 4; j++){
        float kp = nv ? RATIO*(expf(xd[j]*DN - dgn - kmax) + 1e-3f) : 0.f;
        kps[(mt*16 + fq*4 + j)*72 + n_] = f2us(kp);
      }
    }
    __syncthreads();
    #pragma unroll
    for (int kst = 0; kst < 2; kst++){
      int ko = kst*32 + fk;
      s8v b0 = *(s8v*)&vt[( 0 + fr)*72 + ko];
      s8v b1 = *(s8v*)&vt[(16 + fr)*72 + ko];
      s8v b2 = *(s8v*)&vt[(32 + fr)*72 + ko];
      s8v a0 = *(s8v*)&kps[(mt0*16 + fr)*72 + ko];
      acc0[0] = __builtin_amdgcn_mfma_f32_16x16x32_bf16(a0, b0, acc0[0], 0, 0, 0);
      acc0[1] = __builtin_amdgcn_mfma_f32_16x16x32_bf16(a0, b1, acc0[1], 0, 0, 0);
      acc0[2] = __builtin_amdgcn_mfma_f32_16x16x32_bf16(a0, b2, acc0[2], 0, 0, 0);
      if (mt1 < 7){
        s8v a1 = *(s8v*)&kps[(mt1*16 + fr)*72 + ko];
        acc1[0] = __builtin_amdgcn_mfma_f32_16x16x32_bf16(a1, b0, acc1[0], 0, 0, 0);
        acc1[1] = __builtin_amdgcn_mfma_f32_16x16x32_bf16(a1, b1, acc1[1], 0, 0, 0);
        acc1[2] = __builtin_amdgcn_mfma_f32_16x16x32_bf16(a1, b2, acc1[2], 0, 0, 0);
      }
    }
  }
  long pb = ((long)c*64 + (b*H_ + h))*CTXE;
  #pragma unroll
  for (int dt = 0; dt < 3; dt++){
    int d = dt*16 + fr;
    if (d < 33){
      #pragma unroll
      for (int j = 0; j < 4; j++){
        int m0 = mt0*16 + fq*4 + j;
        if (m0 < M_) partials[pb + m0*33 + d] = acc0[dt][j];
        if (mt1 < 7){
          int m1 = mt1*16 + fq*4 + j;
          if (m1 < M_) partials[pb + m1*33 + d] = acc1[dt][j];
        }
      }
    }
  }
}

// ---------------- ctx partial reduce ----------------
__global__ __launch_bounds__(256) void ctxred2_k(const float* __restrict__ partials,
                                                 float* __restrict__ ctxf)
{
  int i = blockIdx.x*256 + threadIdx.x;
  if (i >= CTXN2) return;
  float s = 0.f;
  #pragma unroll
  for (int c = 0; c < NC; c++) s += partials[(long)c*CTXN2 + i];
  ctxf[i] = s;
}

// ---------------- attn v3: full-MFMA query side ----------------
// phase1: xdT[m][n] = projb @ Q^T (MFMA); row-max; qp -> bf16 LDS [64][136]
// phase2: o^T[d][n] = cstT @ qp^T (MFMA); row 32 of cstT = ksum -> den for free
__global__ __launch_bounds__(256) void attn3_k(const float* __restrict__ qb,
    const float* __restrict__ ctxf, const unsigned short* __restrict__ projb,
    unsigned short* __restrict__ ob)
{
  __shared__ __attribute__((aligned(16))) unsigned short qs[64*40];
  __shared__ __attribute__((aligned(16))) unsigned short qps[64*136];
  __shared__ __attribute__((aligned(16))) unsigned short cst[48*136];
  __shared__ float diags[64];
  __shared__ float dens[64];
  int t = blockIdx.x, h = blockIdx.y, b = blockIdx.z;
  int tid = threadIdx.x, w = tid >> 6, lane = tid & 63;
  int fr = lane & 15, fq = lane >> 4, fk = fq*8;
  int n0 = t*64;
  long cbase = ((long)(b*H_ + h))*CTXE;

  // zero qps padded cols 112..127 (avoid NaN garbage * 0 in MFMA K-dim)
  for (int i = tid; i < 64*16; i += 256)
    qps[(i >> 4)*136 + 112 + (i & 15)] = 0;

  // stage Q bf16 + diag fp32
  #pragma unroll
  for (int it = 0; it < 2; it++){
    int tok = it*32 + (tid >> 3), d4 = tid & 7;
    int n = n0 + tok;
    bool vld = (n < N_);
    long gb = ((long)(b*N_ + (vld ? n : 0)))*D_ + h*DH + d4*4;
    float4 qv = vld ? *(const float4*)(qb + gb) : make_float4(0,0,0,0);
    ushort4 qu; qu.x=f2us(qv.x); qu.y=f2us(qv.y); qu.z=f2us(qv.z); qu.w=f2us(qv.w);
    *(ushort4*)&qs[tok*40 + d4*4] = qu;
    float sq = qv.x*qv.x + qv.y*qv.y + qv.z*qv.z + qv.w*qv.w;
    sq += __shfl_xor(sq, 1); sq += __shfl_xor(sq, 2); sq += __shfl_xor(sq, 4);
    if (d4 == 0) diags[tok] = 0.5f * DN2 * sq;
  }
  // stage ctx^T bf16: cst[d][m], row 32 = ksum; zero outside (incl. m>=110)
  for (int i = tid; i < 48*128; i += 256){
    int d = i >> 7, m = i & 127;
    float v = (d < 33 && m < M_) ? ctxf[cbase + (long)m*33 + d] : 0.f;
    cst[d*136 + m] = f2us(v);
  }
  __syncthreads();

  // ---- phase 1 ----
  s8v bq_ = *(s8v*)&qs[(w*16 + fr)*40 + fk];
  int n_ = w*16 + fr;
  bool nv = (n0 + n_ < N_);
  float dgn = diags[n_];
  f4v xdv[7];
  #pragma unroll
  for (int mt = 0; mt < 7; mt++){
    s8v ap = *(const s8v*)(projb + (mt*16 + fr)*32 + fk);
    f4v z = (f4v){0.f,0.f,0.f,0.f};
    xdv[mt] = __builtin_amdgcn_mfma_f32_16x16x32_bf16(ap, bq_, z, 0, 0, 0);
  }
  float mx = -INFINITY;
  #pragma unroll
  for (int mt = 0; mt < 7; mt++)
    #pragma unroll
    for (int j = 0; j < 4; j++){
      int m = mt*16 + fq*4 + j;
      if (m < M_) mx = fmaxf(mx, xdv[mt][j]*DN);
    }
  mx = fmaxf(mx, __shfl_xor(mx, 16));
  mx = fmaxf(mx, __shfl_xor(mx, 32));
  #pragma unroll
  for (int mt = 0; mt < 7; mt++)
    #pragma unroll
    for (int j = 0; j < 4; j++){
      int m = mt*16 + fq*4 + j;
      float qp = (nv && m < M_) ? RATIO*(expf(xdv[mt][j]*DN - dgn - mx) + 1e-3f) : 0.f;
      qps[n_*136 + m] = f2us(qp);
    }
  __syncthreads();

  // ---- phase 2 ----
  f4v acc[3];
  acc[0] = (f4v){0,0,0,0}; acc[1] = (f4v){0,0,0,0}; acc[2] = (f4v){0,0,0,0};
  #pragma unroll
  for (int ks = 0; ks < 4; ks++){
    int ko = ks*32 + fk;
    s8v bqp = *(s8v*)&qps[(w*16 + fr)*136 + ko];
    #pragma unroll
    for (int dt = 0; dt < 3; dt++){
      s8v ac = *(s8v*)&cst[(dt*16 + fr)*136 + ko];
      acc[dt] = __builtin_amdgcn_mfma_f32_16x16x32_bf16(ac, bqp, acc[dt], 0, 0, 0);
    }
  }
  if (fq == 0) dens[n_] = acc[2][0];   // d = 32 row = denominator
  __syncthreads();
  float dinv = 1.0f / dens[n_];
  if (nv){
    long obase = ((long)(b*N_ + n0 + n_))*D_ + h*DH;
    #pragma unroll
    for (int dt = 0; dt < 2; dt++){
      ushort4 wv;
      wv.x = f2us(acc[dt][0]*dinv);
      wv.y = f2us(acc[dt][1]*dinv);
      wv.z = f2us(acc[dt][2]*dinv);
      wv.w = f2us(acc[dt][3]*dinv);
      *(ushort4*)(ob + obase + dt*16 + fq*4) = wv;
    }
  }
}

// ---------------- host ----------------
extern "C" void kernel_launch(void* const* d_in, const int* in_sizes, int n_in,
                              void* d_out, int out_size, void* d_ws, size_t ws_size,
                              hipStream_t stream)
{
  const float* expr = (const float*)d_in[0];
  const float* temb = (const float*)d_in[1];
  const float* cls  = (const float*)d_in[2];
  const float* ln1g = (const float*)d_in[3];
  const float* ln1b = (const float*)d_in[4];
  const float* Wq   = (const float*)d_in[5];
  const float* bq   = (const float*)d_in[6];
  const float* Wk   = (const float*)d_in[7];
  const float* bk   = (const float*)d_in[8];
  const float* Wv   = (const float*)d_in[9];
  const float* bv   = (const float*)d_in[10];
  const float* Wo   = (const float*)d_in[11];
  const float* bo   = (const float*)d_in[12];
  const float* ln2g = (const float*)d_in[13];
  const float* ln2b = (const float*)d_in[14];
  const float* W1   = (const float*)d_in[15];
  const float* b1   = (const float*)d_in[16];
  const float* W2   = (const float*)d_in[17];
  const float* b2   = (const float*)d_in[18];
  const float* proj = (const float*)d_in[19];
  const float* Wp   = (const float*)d_in[20];
  const float* bp   = (const float*)d_in[21];
  (void)in_sizes; (void)n_in; (void)out_size; (void)ws_size;

  char* w = (char*)d_ws;
  size_t off = 0;
  auto alloc = [&](size_t bytes) -> char* {
    char* p = w + off;
    off = (off + bytes + 255) & ~(size_t)255;
    return p;
  };
  float*    selected = (float*)alloc((size_t)B_*KSEL*4);
  float*    bsum     = (float*)alloc(B_*4);
  float*    bv0      = (float*)alloc(B_*4);
  float*    emaxp    = (float*)alloc(4);
  unsigned* kmaxb    = (unsigned*)alloc(4);
  float*    ctxf     = (float*)alloc((size_t)CTXN2*4);
  float*          x  = (float*)alloc((size_t)BN_*D_*4);
  unsigned short* h  = (unsigned short*)alloc((size_t)BN_*D_*2);
  float*          q  = (float*)alloc((size_t)BN_*D_*4);
  float*          k  = (float*)alloc((size_t)BN_*D_*4);
  float*          v  = (float*)alloc((size_t)BN_*D_*4);
  unsigned short* Wqt = (unsigned short*)alloc((size_t)DEPTH_*D_*D_*2);
  unsigned short* Wkt = (unsigned short*)alloc((size_t)DEPTH_*D_*D_*2);
  unsigned short* Wvt = (unsigned short*)alloc((size_t)DEPTH_*D_*D_*2);
  unsigned short* Wot = (unsigned short*)alloc((size_t)DEPTH_*D_*D_*2);
  unsigned short* W1t = (unsigned short*)alloc((size_t)DEPTH_*D_*DFF_*2);
  unsigned short* W2t = (unsigned short*)alloc((size_t)DEPTH_*DFF_*D_*2);
  unsigned short* projb = (unsigned short*)alloc((size_t)DEPTH_*112*32*2);
  unsigned short* ffi = (unsigned short*)k;  // bf16 [BN][1024] aliases k+v (dead during FFN)
  float*     partials = (float*)h;           // NC*CTXN2*4 = 7.44 MB <= h (8.39 MB)

  // one-time weight/proj conversions
  wcvt_k<<<dim3(8, 8, DEPTH_),  256, 0, stream>>>(Wq, (long)D_*D_,   Wqt, (long)D_*D_,   D_, D_);
  wcvt_k<<<dim3(8, 8, DEPTH_),  256, 0, stream>>>(Wk, (long)D_*D_,   Wkt, (long)D_*D_,   D_, D_);
  wcvt_k<<<dim3(8, 8, DEPTH_),  256, 0, stream>>>(Wv, (long)D_*D_,   Wvt, (long)D_*D_,   D_, D_);
  wcvt_k<<<dim3(8, 8, DEPTH_),  256, 0, stream>>>(Wo, (long)D_*D_,   Wot, (long)D_*D_,   D_, D_);
  wcvt_k<<<dim3(32, 8, DEPTH_), 256, 0, stream>>>(W1, (long)D_*DFF_, W1t, (long)D_*DFF_, D_, DFF_);
  wcvt_k<<<dim3(8, 32, DEPTH_), 256, 0, stream>>>(W2, (long)DFF_*D_, W2t, (long)DFF_*D_, DFF_, D_);
  pcvt_k<<<DEPTH_, 256, 0, stream>>>(proj, projb);

  topk_k<<<B_, 256, 0, stream>>>(expr, selected);
  nsum_k<<<B_, 256, 0, stream>>>(selected, bsum, bv0);
  emax_k<<<1, 64, 0, stream>>>(bsum, bv0, emaxp);
  embed_k<<<BN_, 64, 0, stream>>>(selected, bsum, emaxp, temb, cls, x);

  for (int L = 0; L < DEPTH_; L++){
    const unsigned short* pjb = projb + (size_t)L*112*32;
    ln_k<<<BN_/4, 256, 0, stream>>>(x, h, ln1g + L*D_, ln1b + L*D_);
    bgemm_k<0,0,0><<<dim3(129,2), 256, 0, stream>>>(h, D_, Wqt + (size_t)L*D_*D_, bq + L*D_, nullptr, q, nullptr, BN_, D_, D_);
    bgemm_k<0,0,0><<<dim3(129,2), 256, 0, stream>>>(h, D_, Wkt + (size_t)L*D_*D_, bk + L*D_, nullptr, k, nullptr, BN_, D_, D_);
    bgemm_k<0,0,0><<<dim3(129,2), 256, 0, stream>>>(h, D_, Wvt + (size_t)L*D_*D_, bv + L*D_, nullptr, v, nullptr, BN_, D_, D_);
    initkm_k<<<1, 1, 0, stream>>>(kmaxb);
    kmax2_k<<<dim3(NTILES, H_, B_), 256, 0, stream>>>(k, pjb, kmaxb);
    fctx_k<<<dim3(NC, H_, B_), 256, 0, stream>>>(k, v, pjb, kmaxb, partials);
    ctxred2_k<<<(CTXN2 + 255)/256, 256, 0, stream>>>(partials, ctxf);
    attn3_k<<<dim3(NTILES, H_, B_), 256, 0, stream>>>(q, ctxf, pjb, h);   // o -> h (bf16)
    bgemm_k<0,1,0><<<dim3(129,2), 256, 0, stream>>>(h, D_, Wot + (size_t)L*D_*D_, bo + L*D_, x, x, nullptr, BN_, D_, D_);
    ln_k<<<BN_/4, 256, 0, stream>>>(x, h, ln2g + L*D_, ln2b + L*D_);
    bgemm_k<1,0,1><<<dim3(129,8), 256, 0, stream>>>(h, D_, W1t + (size_t)L*D_*DFF_, b1 + L*DFF_, nullptr, nullptr, ffi, BN_, DFF_, D_);
    bgemm_k<0,1,0><<<dim3(129,2), 256, 0, stream>>>(ffi, DFF_, W2t + (size_t)L*DFF_*D_, b2 + L*D_, x, x, nullptr, BN_, D_, DFF_);
  }
  gemm_k<<<dim3(1,4), 256, 0, stream>>>(x, (long)N_*D_, Wp, D_, bp,
                                        (float*)d_out, B_, D_, D_);
}

// Round 12
// 1539.400 us; speedup vs baseline: 5.1110x; 1.1391x over previous
//
#include <hip/hip_runtime.h>
#include <hip/hip_bf16.h>

#define B_    8
#define NG    16906
#define KSEL  2048
#define D_    256
#define H_    8
#define DH    32
#define M_    110
#define DEPTH_ 6
#define DFF_  1024
#define N_    2049
#define BN_   (B_*N_)
#define QS    768          // fused qkv row stride
#define NC    8            // fctx chunks (blocks per (b,h))
#define NTILES 33          // ceil(2049/64)
#define CTXE  (M_*33)      // 3630 per (b,h)
#define CTXN2 (64*CTXE)    // 232320
#define NIT_TK 17          // ceil(16906/1024)

static constexpr float DN    = 0.42044820762685725f;  // 32^-0.25
static constexpr float DN2   = 0.17677669529663687f;  // 32^-0.5
static constexpr float RATIO = 0.09534625892455922f;  // 110^-0.5

typedef __attribute__((ext_vector_type(8))) short s8v;
typedef __attribute__((ext_vector_type(4))) float f4v;

__device__ __forceinline__ unsigned floatToOrdered(float f){
  unsigned b = __float_as_uint(f);
  return (b & 0x80000000u) ? ~b : (b | 0x80000000u);
}
__device__ __forceinline__ float orderedToFloat(unsigned u){
  unsigned b = (u & 0x80000000u) ? (u & 0x7FFFFFFFu) : ~u;
  return __uint_as_float(b);
}
__device__ __forceinline__ unsigned short f2us(float f){
  __hip_bfloat16 b = __float2bfloat16(f);
  return *reinterpret_cast<unsigned short*>(&b);
}

// ---------------- top-k: radix select, 1024 threads, row cached in registers ----------------
__global__ __launch_bounds__(1024) void topk_k(const float* __restrict__ expr,
                                               float* __restrict__ selected)
{
  __shared__ unsigned hist[256];
  __shared__ unsigned sPrefix;
  __shared__ int sKK;
  __shared__ unsigned cGT, cEQ;
  int b = blockIdx.x, tid = threadIdx.x;
  const float* row = expr + (long)b*NG;
  unsigned rb[NIT_TK];
  #pragma unroll
  for (int i = 0; i < NIT_TK; i++){
    int idx = tid + i*1024;
    rb[i] = (idx < NG) ? __float_as_uint(row[idx]) : 0u;
  }
  if (tid == 0){ sPrefix = 0u; sKK = KSEL; }
  __syncthreads();
  for (int pass = 0; pass < 4; ++pass){
    int shift = 24 - pass*8;
    if (tid < 256) hist[tid] = 0u;
    __syncthreads();
    unsigned pref = sPrefix;
    #pragma unroll
    for (int i = 0; i < NIT_TK; i++){
      int idx = tid + i*1024;
      unsigned bits = rb[i];
      bool ok = (idx < NG) && ((pass == 0) || ((bits >> (shift + 8)) == pref));
      if (ok) atomicAdd(&hist[(bits >> shift) & 255u], 1u);
    }
    __syncthreads();
    if (tid == 0){
      int kk = sKK; unsigned cum = 0; int sel = 0;
      for (int j = 255; j >= 0; --j){
        unsigned c = hist[j];
        if (cum + c >= (unsigned)kk){ sel = j; break; }
        cum += c;
      }
      sPrefix = (pref << 8) | (unsigned)sel;
      sKK = kk - (int)cum;
    }
    __syncthreads();
  }
  unsigned T = sPrefix; int needEQ = sKK; int base = KSEL - needEQ;
  if (tid == 0){ cGT = 0u; cEQ = 0u; }
  __syncthreads();
  #pragma unroll
  for (int i = 0; i < NIT_TK; i++){
    int idx = tid + i*1024;
    if (idx < NG){
      unsigned bits = rb[i];
      if (bits > T){
        unsigned p = atomicAdd(&cGT, 1u);
        selected[(long)b*KSEL + p] = __uint_as_float(bits);
      } else if (bits == T){
        unsigned p = atomicAdd(&cEQ, 1u);
        if ((int)p < needEQ) selected[(long)b*KSEL + base + p] = __uint_as_float(bits);
      }
    }
  }
}

// ---------------- per-batch sum + max of selected ----------------
__global__ __launch_bounds__(256) void nsum_k(const float* __restrict__ selected,
                                              float* __restrict__ bsum, float* __restrict__ bv0)
{
  __shared__ float rs[256], rm[256];
  int b = blockIdx.x, tid = threadIdx.x;
  float s = 0.f, m = -INFINITY;
  for (int i = tid; i < KSEL; i += 256){ float v = selected[(long)b*KSEL + i]; s += v; m = fmaxf(m, v); }
  rs[tid] = s; rm[tid] = m; __syncthreads();
  for (int k = 128; k > 0; k >>= 1){
    if (tid < k){ rs[tid] += rs[tid + k]; rm[tid] = fmaxf(rm[tid], rm[tid + k]); }
    __syncthreads();
  }
  if (tid == 0){ bsum[b] = rs[0]; bv0[b] = rm[0]; }
}

// ---------------- global max of e = log1p(v0/sum*1e4) ----------------
__global__ __launch_bounds__(64) void emax_k(const float* __restrict__ bsum,
                                             const float* __restrict__ bv0,
                                             float* __restrict__ emaxp)
{
  int tid = threadIdx.x;
  float e = -INFINITY;
  if (tid < B_) e = log1pf(bv0[tid] / fmaxf(bsum[tid], 1e-12f) * 10000.0f);
  #pragma unroll
  for (int m = 1; m < 64; m <<= 1) e = fmaxf(e, __shfl_xor(e, m));
  if (tid == 0) emaxp[0] = e;
}

// ---------------- tokenize + embed ----------------
__global__ __launch_bounds__(64) void embed_k(const float* __restrict__ selected,
    const float* __restrict__ bsum, const float* __restrict__ emaxp,
    const float* __restrict__ temb, const float* __restrict__ cls,
    float* __restrict__ x)
{
  int rowi = blockIdx.x;
  int b = rowi / N_, n = rowi % N_;
  int tid = threadIdx.x;
  const float* src;
  if (n == 0){
    src = cls;
  } else {
    float val = selected[(long)b*KSEL + (n - 1)];
    float e = log1pf(val / fmaxf(bsum[b], 1e-12f) * 10000.0f);
    float step = emaxp[0] / 7.0f;              // matches jnp.linspace step
    int cnt = 0;
    #pragma unroll
    for (int i = 0; i < 7; i++) cnt += (((float)i * step) < e) ? 1 : 0;  // searchsorted 'left'
    int tok = cnt > 6 ? 6 : cnt;
    src = temb + (long)tok * D_;
  }
  float4 o = *(const float4*)(src + tid*4);
  *(float4*)(x + (long)rowi*D_ + tid*4) = o;
}

// ---------------- LayerNorm: one wave per row, bf16 output ----------------
__global__ __launch_bounds__(256) void ln_k(const float* __restrict__ x,
    unsigned short* __restrict__ out,
    const float* __restrict__ g, const float* __restrict__ bb)
{
  int row = blockIdx.x*4 + (threadIdx.x >> 6);
  int lane = threadIdx.x & 63;
  float4 v = *(const float4*)(x + (long)row*D_ + lane*4);
  float s = v.x + v.y + v.z + v.w;
  float q = v.x*v.x + v.y*v.y + v.z*v.z + v.w*v.w;
  #pragma unroll
  for (int m = 1; m < 64; m <<= 1){ s += __shfl_xor(s, m); q += __shfl_xor(q, m); }
  float mu  = s * (1.0f/D_);
  float var = q * (1.0f/D_) - mu*mu;
  float inv = 1.0f / sqrtf(fmaxf(var, 0.f) + 1e-5f);
  float4 gu = *(const float4*)(g + lane*4);
  float4 bu = *(const float4*)(bb + lane*4);
  ushort4 o;
  o.x = f2us((v.x - mu)*inv*gu.x + bu.x);
  o.y = f2us((v.y - mu)*inv*gu.y + bu.y);
  o.z = f2us((v.z - mu)*inv*gu.z + bu.z);
  o.w = f2us((v.w - mu)*inv*gu.w + bu.w);
  *(ushort4*)(out + (long)row*D_ + lane*4) = o;
}

// ---------------- weight convert + transpose: dst[n][k] = bf16(src[k][n]) ----------------
__global__ __launch_bounds__(256) void wcvt_k(const float* __restrict__ src, long srcL,
    unsigned short* __restrict__ dst, long dstL, int K, int N)
{
  __shared__ float t[32][33];
  int n0 = blockIdx.x*32, k0 = blockIdx.y*32, L = blockIdx.z;
  int tx = threadIdx.x & 31, ty = threadIdx.x >> 5;
  const float* s = src + (long)L*srcL;
  for (int i = ty; i < 32; i += 8)
    t[i][tx] = s[(long)(k0+i)*N + n0 + tx];
  __syncthreads();
  unsigned short* d = dst + (long)L*dstL;
  for (int i = ty; i < 32; i += 8)
    d[(long)(n0 + i)*K + k0 + tx] = f2us(t[tx][i]);
}

// ---------------- proj convert + zero kmax slots ----------------
__global__ __launch_bounds__(256) void pcvt_k(const float* __restrict__ proj,
                                              unsigned short* __restrict__ projb,
                                              unsigned* __restrict__ kmaxb)
{
  int L = blockIdx.x;
  if (blockIdx.x == 0 && threadIdx.x < DEPTH_) kmaxb[threadIdx.x] = 0u;
  for (int i = threadIdx.x; i < 112*32; i += 256){
    int m = i >> 5, d = i & 31;
    float v = (m < M_) ? proj[(long)L*M_*DH + m*DH + d] : 0.f;
    projb[(long)L*112*32 + i] = f2us(v);
  }
}

// ---------------- bias concat: bqkv[L][768] = [bq|bk|bv] ----------------
__global__ __launch_bounds__(256) void bcat_k(const float* __restrict__ bq,
    const float* __restrict__ bk, const float* __restrict__ bv,
    float* __restrict__ bqkv)
{
  int L = blockIdx.x;
  for (int i = threadIdx.x; i < QS; i += 256){
    float v = (i < 256) ? bq[L*256 + i] : (i < 512) ? bk[L*256 + i - 256] : bv[L*256 + i - 512];
    bqkv[(long)L*QS + i] = v;
  }
}

// ---------------- bf16 MFMA GEMM with register-prefetch pipeline ----------------
template<int ACT, int RES, int OUTBF>
__global__ __launch_bounds__(256) void bgemm_k(
    const unsigned short* __restrict__ A, long lda,
    const unsigned short* __restrict__ Bt,
    const float* __restrict__ bias,
    const float* __restrict__ res,
    float* __restrict__ Cf, unsigned short* __restrict__ Cb,
    int M, int Nn, int K)
{
  __shared__ __attribute__((aligned(16))) unsigned short As[128*40];
  __shared__ __attribute__((aligned(16))) unsigned short Bs[128*40];
  int tid = threadIdx.x;
  int rowBlk = blockIdx.x*128, colBlk = blockIdx.y*128;
  int w = tid >> 6, lane = tid & 63;
  int wrow = (w >> 1)*64, wcol = (w & 1)*64;
  int fr = lane & 15, fk = (lane >> 4)*8, fq = lane >> 4;
  int srh = tid >> 2, sk8 = (tid & 3)*8;

  f4v acc[4][4];
  #pragma unroll
  for (int r = 0; r < 4; r++)
    #pragma unroll
    for (int c = 0; c < 4; c++) acc[r][c] = (f4v){0.f, 0.f, 0.f, 0.f};

  s8v pa[2], pb[2];
  // prologue load tile 0
  #pragma unroll
  for (int half = 0; half < 2; half++){
    int r = half*64 + srh;
    int ar = rowBlk + r;
    pa[half] = (ar < M) ? *(const s8v*)(A + (long)ar*lda + sk8) : (s8v){0,0,0,0,0,0,0,0};
    pb[half] = *(const s8v*)(Bt + (long)(colBlk + r)*K + sk8);
  }

  for (int kt = 0; kt < K; kt += 32){
    __syncthreads();                     // previous iteration's fragment readers done
    #pragma unroll
    for (int half = 0; half < 2; half++){
      int r = half*64 + srh;
      *(s8v*)&As[r*40 + sk8] = pa[half];
      *(s8v*)&Bs[r*40 + sk8] = pb[half];
    }
    __syncthreads();
    if (kt + 32 < K){                    // prefetch next tile; latency hides under MFMAs
      int kn = kt + 32;
      #pragma unroll
      for (int half = 0; half < 2; half++){
        int r = half*64 + srh;
        int ar = rowBlk + r;
        pa[half] = (ar < M) ? *(const s8v*)(A + (long)ar*lda + kn + sk8) : (s8v){0,0,0,0,0,0,0,0};
        pb[half] = *(const s8v*)(Bt + (long)(colBlk + r)*K + kn + sk8);
      }
    }
    s8v a[4], b[4];
    #pragma unroll
    for (int r = 0; r < 4; r++) a[r] = *(s8v*)&As[(wrow + r*16 + fr)*40 + fk];
    #pragma unroll
    for (int c = 0; c < 4; c++) b[c] = *(s8v*)&Bs[(wcol + c*16 + fr)*40 + fk];
    #pragma unroll
    for (int r = 0; r < 4; r++)
      #pragma unroll
      for (int c = 0; c < 4; c++)
        acc[r][c] = __builtin_amdgcn_mfma_f32_16x16x32_bf16(a[r], b[c], acc[r][c], 0, 0, 0);
  }

  #pragma unroll
  for (int c = 0; c < 4; c++){
    int col = colBlk + wcol + c*16 + fr;
    float bz = bias[col];
    #pragma unroll
    for (int r = 0; r < 4; r++){
      #pragma unroll
      for (int j = 0; j < 4; j++){
        int row = rowBlk + wrow + r*16 + fq*4 + j;
        if (row < M){
          float val = acc[r][c][j] + bz;
          if (ACT == 1) val = 0.5f * val * (1.0f + erff(val * 0.70710678118654752f));
          if (RES) val += res[(long)row*Nn + col];
          if (OUTBF) Cb[(long)row*Nn + col] = f2us(val);
          else       Cf[(long)row*Nn + col] = val;
        }
      }
    }
  }
}

// ---------------- fp32 GEMM (head only: 8 rows) ----------------
__global__ __launch_bounds__(256) void gemm_k(
    const float* __restrict__ A, long lda,
    const float* __restrict__ Bw, long ldb,
    const float* __restrict__ bias,
    float* __restrict__ Cf,
    int M, int Nn, int K)
{
  __shared__ float As[16][64];
  __shared__ float Bs[16][64];
  int tid = threadIdx.x;
  int tx = tid & 15, ty = tid >> 4;
  int rowBlk = blockIdx.x * 64, colBlk = blockIdx.y * 64;
  int am = tid >> 2, ak = (tid & 3) * 4;
  int bk = tid >> 4, bc = (tid & 15) * 4;
  float acc[4][4];
  #pragma unroll
  for (int i = 0; i < 4; i++)
    #pragma unroll
    for (int j = 0; j < 4; j++) acc[i][j] = 0.f;

  for (int kt = 0; kt < K; kt += 16){
    float4 av = make_float4(0.f, 0.f, 0.f, 0.f);
    int ar = rowBlk + am;
    if (ar < M) av = *(const float4*)(A + (long)ar*lda + kt + ak);
    As[ak+0][am] = av.x; As[ak+1][am] = av.y; As[ak+2][am] = av.z; As[ak+3][am] = av.w;
    float4 bv4 = *(const float4*)(Bw + (long)(kt + bk)*ldb + colBlk + bc);
    Bs[bk][bc+0] = bv4.x; Bs[bk][bc+1] = bv4.y;
    Bs[bk][bc+2] = bv4.z; Bs[bk][bc+3] = bv4.w;
    __syncthreads();
    #pragma unroll
    for (int kk = 0; kk < 16; kk++){
      float4 a4 = *(const float4*)&As[kk][ty*4];
      float4 b4 = *(const float4*)&Bs[kk][tx*4];
      acc[0][0] += a4.x*b4.x; acc[0][1] += a4.x*b4.y; acc[0][2] += a4.x*b4.z; acc[0][3] += a4.x*b4.w;
      acc[1][0] += a4.y*b4.x; acc[1][1] += a4.y*b4.y; acc[1][2] += a4.y*b4.z; acc[1][3] += a4.y*b4.w;
      acc[2][0] += a4.z*b4.x; acc[2][1] += a4.z*b4.y; acc[2][2] += a4.z*b4.z; acc[2][3] += a4.z*b4.w;
      acc[3][0] += a4.w*b4.x; acc[3][1] += a4.w*b4.y; acc[3][2] += a4.w*b4.z; acc[3][3] += a4.w*b4.w;
    }
    __syncthreads();
  }
  int r0 = rowBlk + ty*4, c0 = colBlk + tx*4;
  float bz[4];
  #pragma unroll
  for (int j = 0; j < 4; j++) bz[j] = bias[c0 + j];
  #pragma unroll
  for (int i = 0; i < 4; i++){
    int r = r0 + i;
    if (r < M){
      #pragma unroll
      for (int j = 0; j < 4; j++)
        Cf[(long)r*Nn + c0 + j] = acc[i][j] + bz[j];
    }
  }
}

// ---------------- kmax via MFMA (reads k slice of fused qkv) ----------------
__global__ __launch_bounds__(256) void kmax2_k(const float* __restrict__ qkv,
    const unsigned short* __restrict__ projb, unsigned* __restrict__ kmaxb)
{
  __shared__ __attribute__((aligned(16))) unsigned short ks[64*40];
  __shared__ float red[4];
  int t = blockIdx.x, h = blockIdx.y, b = blockIdx.z;
  int tid = threadIdx.x, w = tid >> 6, lane = tid & 63;
  int fr = lane & 15, fq = lane >> 4, fk = fq*8;
  int n0 = t*64;
  #pragma unroll
  for (int it = 0; it < 2; it++){
    int tok = it*32 + (tid >> 3), d4 = tid & 7;
    int n = n0 + tok;
    bool vld = (n < N_);
    long gb = ((long)(b*N_ + (vld ? n : 0)))*QS + 256 + h*DH + d4*4;
    float4 kv = vld ? *(const float4*)(qkv + gb) : make_float4(0,0,0,0);
    ushort4 ku; ku.x=f2us(kv.x); ku.y=f2us(kv.y); ku.z=f2us(kv.z); ku.w=f2us(kv.w);
    *(ushort4*)&ks[tok*40 + d4*4] = ku;
  }
  __syncthreads();
  s8v bk_ = *(s8v*)&ks[(w*16 + fr)*40 + fk];
  float mx = -INFINITY;
  int n_ = w*16 + fr;
  bool nv = (n0 + n_ < N_);
  #pragma unroll
  for (int mt = 0; mt < 7; mt++){
    s8v ap = *(const s8v*)(projb + (mt*16 + fr)*32 + fk);
    f4v z = (f4v){0.f,0.f,0.f,0.f};
    f4v xd = __builtin_amdgcn_mfma_f32_16x16x32_bf16(ap, bk_, z, 0, 0, 0);
    #pragma unroll
    for (int j = 0; j < 4; j++){
      int m = mt*16 + fq*4 + j;
      float v = (nv && m < M_) ? xd[j]*DN : -INFINITY;
      mx = fmaxf(mx, v);
    }
  }
  #pragma unroll
  for (int mk = 1; mk < 64; mk <<= 1) mx = fmaxf(mx, __shfl_xor(mx, mk));
  if (lane == 0) red[w] = mx;
  __syncthreads();
  if (tid == 0){
    float g = fmaxf(fmaxf(red[0], red[1]), fmaxf(red[2], red[3]));
    atomicMax(kmaxb, floatToOrdered(g));
  }
}

// ---------------- fused ctx via double MFMA (k/v from fused qkv) ----------------
__global__ __launch_bounds__(256) void fctx_k(const float* __restrict__ qkv,
    const unsigned short* __restrict__ projb,
    const unsigned* __restrict__ kmaxb, float* __restrict__ partials)
{
  __shared__ __attribute__((aligned(16))) unsigned short ks[64*40];
  __shared__ __attribute__((aligned(16))) unsigned short vt[48*72];
  __shared__ __attribute__((aligned(16))) unsigned short kps[112*72];
  __shared__ float diags[64];
  int c = blockIdx.x, h = blockIdx.y, b = blockIdx.z;
  int tid = threadIdx.x, w = tid >> 6, lane = tid & 63;
  int fr = lane & 15, fq = lane >> 4, fk = fq*8;
  float kmax = orderedToFloat(kmaxb[0]);

  for (int i = tid; i < 15*72; i += 256) vt[33*72 + i] = 0;
  if (tid < 64) vt[32*72 + tid] = f2us(1.0f);

  s8v ap[7];
  #pragma unroll
  for (int mt = 0; mt < 7; mt++)
    ap[mt] = *(const s8v*)(projb + (mt*16 + fr)*32 + fk);

  int mt0 = w, mt1 = w + 4;
  f4v acc0[3], acc1[3];
  #pragma unroll
  for (int dt = 0; dt < 3; dt++){ acc0[dt] = (f4v){0.f,0.f,0.f,0.f}; acc1[dt] = (f4v){0.f,0.f,0.f,0.f}; }

  for (int t = c; t < NTILES; t += NC){
    int n0 = t*64;
    __syncthreads();
    #pragma unroll
    for (int it = 0; it < 2; it++){
      int tok = it*32 + (tid >> 3), d4 = tid & 7;
      int n = n0 + tok;
      bool vld = (n < N_);
      long gb = ((long)(b*N_ + (vld ? n : 0)))*QS + 256 + h*DH + d4*4;
      float4 kv = vld ? *(const float4*)(qkv + gb) : make_float4(0,0,0,0);
      float4 vv = vld ? *(const float4*)(qkv + gb + 256) : make_float4(0,0,0,0);
      ushort4 ku; ku.x=f2us(kv.x); ku.y=f2us(kv.y); ku.z=f2us(kv.z); ku.w=f2us(kv.w);
      *(ushort4*)&ks[tok*40 + d4*4] = ku;
      vt[(d4*4+0)*72 + tok] = f2us(vv.x);
      vt[(d4*4+1)*72 + tok] = f2us(vv.y);
      vt[(d4*4+2)*72 + tok] = f2us(vv.z);
      vt[(d4*4+3)*72 + tok] = f2us(vv.w);
      float sq = kv.x*kv.x + kv.y*kv.y + kv.z*kv.z + kv.w*kv.w;
      sq += __shfl_xor(sq, 1); sq += __shfl_xor(sq, 2); sq += __shfl_xor(sq, 4);
      if (d4 == 0) diags[tok] = 0.5f * DN2 * sq;
    }
    __syncthreads();
    s8v bk_ = *(s8v*)&ks[(w*16 + fr)*40 + fk];
    int n_ = w*16 + fr;
    bool nv = (n0 + n_ < N_);
    float dgn = diags[n_];
    #pragma unroll
    for (int mt = 0; mt < 7; mt++){
      f4v z = (f4v){0.f,0.f,0.f,0.f};
      f4v xd = __builtin_amdgcn_mfma_f32_16x16x32_bf16(ap[mt], bk_, z, 0, 0, 0);
      #pragma unroll
      for (int j = 0; j < 4; j++){
        float kp = nv ? RATIO*(expf(xd[j]*DN - dgn - kmax) + 1e-3f) : 0.f;
        kps[(mt*16 + fq*4 + j)*72 + n_] = f2us(kp);
      }
    }
    __syncthreads();
    #pragma unroll
    for (int kst = 0; kst < 2; kst++){
      int ko = kst*32 + fk;
      s8v b0 = *(s8v*)&vt[( 0 + fr)*72 + ko];
      s8v b1 = *(s8v*)&vt[(16 + fr)*72 + ko];
      s8v b2 = *(s8v*)&vt[(32 + fr)*72 + ko];
      s8v a0 = *(s8v*)&kps[(mt0*16 + fr)*72 + ko];
      acc0[0] = __builtin_amdgcn_mfma_f32_16x16x32_bf16(a0, b0, acc0[0], 0, 0, 0);
      acc0[1] = __builtin_amdgcn_mfma_f32_16x16x32_bf16(a0, b1, acc0[1], 0, 0, 0);
      acc0[2] = __builtin_amdgcn_mfma_f32_16x16x32_bf16(a0, b2, acc0[2], 0, 0, 0);
      if (mt1 < 7){
        s8v a1 = *(s8v*)&kps[(mt1*16 + fr)*72 + ko];
        acc1[0] = __builtin_amdgcn_mfma_f32_16x16x32_bf16(a1, b0, acc1[0], 0, 0, 0);
        acc1[1] = __builtin_amdgcn_mfma_f32_16x16x32_bf16(a1, b1, acc1[1], 0, 0, 0);
        acc1[2] = __builtin_amdgcn_mfma_f32_16x16x32_bf16(a1, b2, acc1[2], 0, 0, 0);
      }
    }
  }
  long pb = ((long)c*64 + (b*H_ + h))*CTXE;
  #pragma unroll
  for (int dt = 0; dt < 3; dt++){
    int d = dt*16 + fr;
    if (d < 33){
      #pragma unroll
      for (int j = 0; j < 4; j++){
        int m0 = mt0*16 + fq*4 + j;
        if (m0 < M_) partials[pb + m0*33 + d] = acc0[dt][j];
        if (mt1 < 7){
          int m1 = mt1*16 + fq*4 + j;
          if (m1 < M_) partials[pb + m1*33 + d] = acc1[dt][j];
        }
      }
    }
  }
}

// ---------------- ctx partial reduce ----------------
__global__ __launch_bounds__(256) void ctxred2_k(const float* __restrict__ partials,
                                                 float* __restrict__ ctxf)
{
  int i = blockIdx.x*256 + threadIdx.x;
  if (i >= CTXN2) return;
  float s = 0.f;
  #pragma unroll
  for (int c = 0; c < NC; c++) s += partials[(long)c*CTXN2 + i];
  ctxf[i] = s;
}

// ---------------- attn v3: full-MFMA query side (q from fused qkv) ----------------
__global__ __launch_bounds__(256) void attn3_k(const float* __restrict__ qkv,
    const float* __restrict__ ctxf, const unsigned short* __restrict__ projb,
    unsigned short* __restrict__ ob)
{
  __shared__ __attribute__((aligned(16))) unsigned short qs[64*40];
  __shared__ __attribute__((aligned(16))) unsigned short qps[64*136];
  __shared__ __attribute__((aligned(16))) unsigned short cst[48*136];
  __shared__ float diags[64];
  __shared__ float dens[64];
  int t = blockIdx.x, h = blockIdx.y, b = blockIdx.z;
  int tid = threadIdx.x, w = tid >> 6, lane = tid & 63;
  int fr = lane & 15, fq = lane >> 4, fk = fq*8;
  int n0 = t*64;
  long cbase = ((long)(b*H_ + h))*CTXE;

  for (int i = tid; i < 64*16; i += 256)
    qps[(i >> 4)*136 + 112 + (i & 15)] = 0;

  #pragma unroll
  for (int it = 0; it < 2; it++){
    int tok = it*32 + (tid >> 3), d4 = tid & 7;
    int n = n0 + tok;
    bool vld = (n < N_);
    long gb = ((long)(b*N_ + (vld ? n : 0)))*QS + h*DH + d4*4;
    float4 qv = vld ? *(const float4*)(qkv + gb) : make_float4(0,0,0,0);
    ushort4 qu; qu.x=f2us(qv.x); qu.y=f2us(qv.y); qu.z=f2us(qv.z); qu.w=f2us(qv.w);
    *(ushort4*)&qs[tok*40 + d4*4] = qu;
    float sq = qv.x*qv.x + qv.y*qv.y + qv.z*qv.z + qv.w*qv.w;
    sq += __shfl_xor(sq, 1); sq += __shfl_xor(sq, 2); sq += __shfl_xor(sq, 4);
    if (d4 == 0) diags[tok] = 0.5f * DN2 * sq;
  }
  for (int i = tid; i < 48*128; i += 256){
    int d = i >> 7, m = i & 127;
    float v = (d < 33 && m < M_) ? ctxf[cbase + (long)m*33 + d] : 0.f;
    cst[d*136 + m] = f2us(v);
  }
  __syncthreads();

  s8v bq_ = *(s8v*)&qs[(w*16 + fr)*40 + fk];
  int n_ = w*16 + fr;
  bool nv = (n0 + n_ < N_);
  float dgn = diags[n_];
  f4v xdv[7];
  #pragma unroll
  for (int mt = 0; mt < 7; mt++){
    s8v ap = *(const s8v*)(projb + (mt*16 + fr)*32 + fk);
    f4v z = (f4v){0.f,0.f,0.f,0.f};
    xdv[mt] = __builtin_amdgcn_mfma_f32_16x16x32_bf16(ap, bq_, z, 0, 0, 0);
  }
  float mx = -INFINITY;
  #pragma unroll
  for (int mt = 0; mt < 7; mt++)
    #pragma unroll
    for (int j = 0; j < 4; j++){
      int m = mt*16 + fq*4 + j;
      if (m < M_) mx = fmaxf(mx, xdv[mt][j]*DN);
    }
  mx = fmaxf(mx, __shfl_xor(mx, 16));
  mx = fmaxf(mx, __shfl_xor(mx, 32));
  #pragma unroll
  for (int mt = 0; mt < 7; mt++)
    #pragma unroll
    for (int j = 0; j < 4; j++){
      int m = mt*16 + fq*4 + j;
      float qp = (nv && m < M_) ? RATIO*(expf(xdv[mt][j]*DN - dgn - mx) + 1e-3f) : 0.f;
      qps[n_*136 + m] = f2us(qp);
    }
  __syncthreads();

  f4v acc[3];
  acc[0] = (f4v){0,0,0,0}; acc[1] = (f4v){0,0,0,0}; acc[2] = (f4v){0,0,0,0};
  #pragma unroll
  for (int ks = 0; ks < 4; ks++){
    int ko = ks*32 + fk;
    s8v bqp = *(s8v*)&qps[(w*16 + fr)*136 + ko];
    #pragma unroll
    for (int dt = 0; dt < 3; dt++){
      s8v ac = *(s8v*)&cst[(dt*16 + fr)*136 + ko];
      acc[dt] = __builtin_amdgcn_mfma_f32_16x16x32_bf16(ac, bqp, acc[dt], 0, 0, 0);
    }
  }
  if (fq == 0) dens[n_] = acc[2][0];
  __syncthreads();
  float dinv = 1.0f / dens[n_];
  if (nv){
    long obase = ((long)(b*N_ + n0 + n_))*D_ + h*DH;
    #pragma unroll
    for (int dt = 0; dt < 2; dt++){
      ushort4 wv;
      wv.x = f2us(acc[dt][0]*dinv);
      wv.y = f2us(acc[dt][1]*dinv);
      wv.z = f2us(acc[dt][2]*dinv);
      wv.w = f2us(acc[dt][3]*dinv);
      *(ushort4*)(ob + obase + dt*16 + fq*4) = wv;
    }
  }
}

// ---------------- host ----------------
extern "C" void kernel_launch(void* const* d_in, const int* in_sizes, int n_in,
                              void* d_out, int out_size, void* d_ws, size_t ws_size,
                              hipStream_t stream)
{
  const float* expr = (const float*)d_in[0];
  const float* temb = (const float*)d_in[1];
  const float* cls  = (const float*)d_in[2];
  const float* ln1g = (const float*)d_in[3];
  const float* ln1b = (const float*)d_in[4];
  const float* Wq   = (const float*)d_in[5];
  const float* bq   = (const float*)d_in[6];
  const float* Wk   = (const float*)d_in[7];
  const float* bk   = (const float*)d_in[8];
  const float* Wv   = (const float*)d_in[9];
  const float* bv   = (const float*)d_in[10];
  const float* Wo   = (const float*)d_in[11];
  const float* bo   = (const float*)d_in[12];
  const float* ln2g = (const float*)d_in[13];
  const float* ln2b = (const float*)d_in[14];
  const float* W1   = (const float*)d_in[15];
  const float* b1   = (const float*)d_in[16];
  const float* W2   = (const float*)d_in[17];
  const float* b2   = (const float*)d_in[18];
  const float* proj = (const float*)d_in[19];
  const float* Wp   = (const float*)d_in[20];
  const float* bp   = (const float*)d_in[21];
  (void)in_sizes; (void)n_in; (void)out_size; (void)ws_size;

  char* w = (char*)d_ws;
  size_t off = 0;
  auto alloc = [&](size_t bytes) -> char* {
    char* p = w + off;
    off = (off + bytes + 255) & ~(size_t)255;
    return p;
  };
  float*    selected = (float*)alloc((size_t)B_*KSEL*4);
  float*    bsum     = (float*)alloc(B_*4);
  float*    bv0      = (float*)alloc(B_*4);
  float*    emaxp    = (float*)alloc(4);
  unsigned* kmaxb    = (unsigned*)alloc(DEPTH_*4);
  float*    ctxf     = (float*)alloc((size_t)CTXN2*4);
  float*          x  = (float*)alloc((size_t)BN_*D_*4);
  unsigned short* h  = (unsigned short*)alloc((size_t)BN_*D_*2);
  float*        qkv  = (float*)alloc((size_t)BN_*QS*4);
  unsigned short* Wqkvt = (unsigned short*)alloc((size_t)DEPTH_*QS*D_*2);
  unsigned short* Wot = (unsigned short*)alloc((size_t)DEPTH_*D_*D_*2);
  unsigned short* W1t = (unsigned short*)alloc((size_t)DEPTH_*D_*DFF_*2);
  unsigned short* W2t = (unsigned short*)alloc((size_t)DEPTH_*DFF_*D_*2);
  unsigned short* projb = (unsigned short*)alloc((size_t)DEPTH_*112*32*2);
  float*    bqkv     = (float*)alloc((size_t)DEPTH_*QS*4);
  unsigned short* ffi = (unsigned short*)qkv;  // bf16 [BN][1024] aliases qkv (dead during FFN)
  float*     partials = (float*)h;             // NC*CTXN2*4 = 7.44 MB <= h (8.39 MB)

  // one-time weight/proj conversions (Wq/Wk/Wv into one concatenated [768][256] bf16)
  wcvt_k<<<dim3(8, 8, DEPTH_),  256, 0, stream>>>(Wq, (long)D_*D_, Wqkvt + 0,      (long)QS*D_, D_, D_);
  wcvt_k<<<dim3(8, 8, DEPTH_),  256, 0, stream>>>(Wk, (long)D_*D_, Wqkvt + 256*D_, (long)QS*D_, D_, D_);
  wcvt_k<<<dim3(8, 8, DEPTH_),  256, 0, stream>>>(Wv, (long)D_*D_, Wqkvt + 512*D_, (long)QS*D_, D_, D_);
  wcvt_k<<<dim3(8, 8, DEPTH_),  256, 0, stream>>>(Wo, (long)D_*D_,   Wot, (long)D_*D_,   D_, D_);
  wcvt_k<<<dim3(32, 8, DEPTH_), 256, 0, stream>>>(W1, (long)D_*DFF_, W1t, (long)D_*DFF_, D_, DFF_);
  wcvt_k<<<dim3(8, 32, DEPTH_), 256, 0, stream>>>(W2, (long)DFF_*D_, W2t, (long)DFF_*D_, DFF_, D_);
  pcvt_k<<<DEPTH_, 256, 0, stream>>>(proj, projb, kmaxb);
  bcat_k<<<DEPTH_, 256, 0, stream>>>(bq, bk, bv, bqkv);

  topk_k<<<B_, 1024, 0, stream>>>(expr, selected);
  nsum_k<<<B_, 256, 0, stream>>>(selected, bsum, bv0);
  emax_k<<<1, 64, 0, stream>>>(bsum, bv0, emaxp);
  embed_k<<<BN_, 64, 0, stream>>>(selected, bsum, emaxp, temb, cls, x);

  for (int L = 0; L < DEPTH_; L++){
    const unsigned short* pjb = projb + (size_t)L*112*32;
    ln_k<<<BN_/4, 256, 0, stream>>>(x, h, ln1g + L*D_, ln1b + L*D_);
    bgemm_k<0,0,0><<<dim3(129,6), 256, 0, stream>>>(h, D_, Wqkvt + (size_t)L*QS*D_, bqkv + (size_t)L*QS, nullptr, qkv, nullptr, BN_, QS, D_);
    kmax2_k<<<dim3(NTILES, H_, B_), 256, 0, stream>>>(qkv, pjb, kmaxb + L);
    fctx_k<<<dim3(NC, H_, B_), 256, 0, stream>>>(qkv, pjb, kmaxb + L, partials);
    ctxred2_k<<<(CTXN2 + 255)/256, 256, 0, stream>>>(partials, ctxf);
    attn3_k<<<dim3(NTILES, H_, B_), 256, 0, stream>>>(qkv, ctxf, pjb, h);   // o -> h (bf16)
    bgemm_k<0,1,0><<<dim3(129,2), 256, 0, stream>>>(h, D_, Wot + (size_t)L*D_*D_, bo + L*D_, x, x, nullptr, BN_, D_, D_);
    ln_k<<<BN_/4, 256, 0, stream>>>(x, h, ln2g + L*D_, ln2b + L*D_);
    bgemm_k<1,0,1><<<dim3(129,8), 256, 0, stream>>>(h, D_, W1t + (size_t)L*D_*DFF_, b1 + L*DFF_, nullptr, nullptr, ffi, BN_, DFF_, D_);
    bgemm_k<0,1,0><<<dim3(129,2), 256, 0, stream>>>(ffi, DFF_, W2t + (size_t)L*DFF_*D_, b2 + L*D_, x, x, nullptr, BN_, D_, DFF_);
  }
  gemm_k<<<dim3(1,4), 256, 0, stream>>>(x, (long)N_*D_, Wp, D_, bp,
                                        (float*)d_out, B_, D_, D_);
}

// Round 13
// 1425.558 us; speedup vs baseline: 5.5191x; 1.0799x over previous
//
#include <hip/hip_runtime.h>
#include <hip/hip_bf16.h>

#define B_    8
#define NG    16906
#define KSEL  2048
#define D_    256
#define H_    8
#define DH    32
#define M_    110
#define DEPTH_ 6
#define DFF_  1024
#define N_    2049
#define BN_   (B_*N_)
#define QS    768          // fused qkv row stride
#define NC    8            // fctx chunks (blocks per (b,h))
#define NTILES 33          // ceil(2049/64)
#define CTXE  (M_*33)      // 3630 per (b,h)
#define CTXN2 (64*CTXE)    // 232320
#define NIT_TK 17          // ceil(16906/1024)

static constexpr float DN    = 0.42044820762685725f;  // 32^-0.25
static constexpr float DN2   = 0.17677669529663687f;  // 32^-0.5
static constexpr float RATIO = 0.09534625892455922f;  // 110^-0.5

typedef __attribute__((ext_vector_type(8))) short s8v;
typedef __attribute__((ext_vector_type(4))) float f4v;

__device__ __forceinline__ unsigned floatToOrdered(float f){
  unsigned b = __float_as_uint(f);
  return (b & 0x80000000u) ? ~b : (b | 0x80000000u);
}
__device__ __forceinline__ float orderedToFloat(unsigned u){
  unsigned b = (u & 0x80000000u) ? (u & 0x7FFFFFFFu) : ~u;
  return __uint_as_float(b);
}
__device__ __forceinline__ unsigned short f2us(float f){
  __hip_bfloat16 b = __float2bfloat16(f);
  return *reinterpret_cast<unsigned short*>(&b);
}

// ---------------- top-k: radix select, per-wave hists + aggregated scatter ----------------
__global__ __launch_bounds__(1024) void topk_k(const float* __restrict__ expr,
                                               float* __restrict__ selected)
{
  __shared__ unsigned histw[16*256];
  __shared__ unsigned sPrefix;
  __shared__ int sKK;
  __shared__ unsigned cGT, cEQ;
  int b = blockIdx.x, tid = threadIdx.x;
  int wv = tid >> 6, lane = tid & 63;
  const float* row = expr + (long)b*NG;
  unsigned rb[NIT_TK];
  #pragma unroll
  for (int i = 0; i < NIT_TK; i++){
    int idx = tid + i*1024;
    rb[i] = (idx < NG) ? __float_as_uint(row[idx]) : 0u;
  }
  if (tid == 0){ sPrefix = 0u; sKK = KSEL; }
  for (int pass = 0; pass < 4; ++pass){
    int shift = 24 - pass*8;
    for (int i = tid; i < 16*256; i += 1024) histw[i] = 0u;
    __syncthreads();
    unsigned pref = sPrefix;
    #pragma unroll
    for (int i = 0; i < NIT_TK; i++){
      int idx = tid + i*1024;
      unsigned bits = rb[i];
      bool ok = (idx < NG) && ((pass == 0) || ((bits >> (shift + 8)) == pref));
      if (ok) atomicAdd(&histw[wv*256 + ((bits >> shift) & 255u)], 1u);
    }
    __syncthreads();
    if (tid < 256){
      unsigned s = 0;
      #pragma unroll
      for (int w = 0; w < 16; w++) s += histw[w*256 + tid];
      histw[tid] = s;
    }
    __syncthreads();
    if (tid == 0){
      int kk = sKK; unsigned cum = 0; int sel = 0;
      for (int j = 255; j >= 0; --j){
        unsigned c = histw[j];
        if (cum + c >= (unsigned)kk){ sel = j; break; }
        cum += c;
      }
      sPrefix = (pref << 8) | (unsigned)sel;
      sKK = kk - (int)cum;
    }
    __syncthreads();
  }
  unsigned T = sPrefix; int needEQ = sKK; int base = KSEL - needEQ;
  if (tid == 0){ cGT = 0u; cEQ = 0u; }
  __syncthreads();
  #pragma unroll
  for (int i = 0; i < NIT_TK; i++){
    int idx = tid + i*1024;
    bool v = (idx < NG);
    unsigned bits = rb[i];
    // GT path: wave-aggregated atomic
    bool gt = v && (bits > T);
    unsigned long long mgt = __ballot(gt);
    if (mgt){
      int leader = __ffsll((long long)mgt) - 1;
      unsigned wbase = 0;
      if (lane == leader) wbase = atomicAdd(&cGT, (unsigned)__popcll(mgt));
      wbase = __shfl(wbase, leader);
      if (gt){
        int pre = __popcll(mgt & ((1ULL << lane) - 1ULL));
        selected[(long)b*KSEL + wbase + pre] = __uint_as_float(bits);
      }
    }
    // EQ path
    bool eq = v && (bits == T);
    unsigned long long meq = __ballot(eq);
    if (meq){
      int leader = __ffsll((long long)meq) - 1;
      unsigned wbase = 0;
      if (lane == leader) wbase = atomicAdd(&cEQ, (unsigned)__popcll(meq));
      wbase = __shfl(wbase, leader);
      if (eq){
        int pos = (int)wbase + __popcll(meq & ((1ULL << lane) - 1ULL));
        if (pos < needEQ) selected[(long)b*KSEL + base + pos] = __uint_as_float(bits);
      }
    }
  }
}

// ---------------- per-batch sum + max of selected ----------------
__global__ __launch_bounds__(256) void nsum_k(const float* __restrict__ selected,
                                              float* __restrict__ bsum, float* __restrict__ bv0)
{
  __shared__ float rs[256], rm[256];
  int b = blockIdx.x, tid = threadIdx.x;
  float s = 0.f, m = -INFINITY;
  for (int i = tid; i < KSEL; i += 256){ float v = selected[(long)b*KSEL + i]; s += v; m = fmaxf(m, v); }
  rs[tid] = s; rm[tid] = m; __syncthreads();
  for (int k = 128; k > 0; k >>= 1){
    if (tid < k){ rs[tid] += rs[tid + k]; rm[tid] = fmaxf(rm[tid], rm[tid + k]); }
    __syncthreads();
  }
  if (tid == 0){ bsum[b] = rs[0]; bv0[b] = rm[0]; }
}

// ---------------- global max of e = log1p(v0/sum*1e4) ----------------
__global__ __launch_bounds__(64) void emax_k(const float* __restrict__ bsum,
                                             const float* __restrict__ bv0,
                                             float* __restrict__ emaxp)
{
  int tid = threadIdx.x;
  float e = -INFINITY;
  if (tid < B_) e = log1pf(bv0[tid] / fmaxf(bsum[tid], 1e-12f) * 10000.0f);
  #pragma unroll
  for (int m = 1; m < 64; m <<= 1) e = fmaxf(e, __shfl_xor(e, m));
  if (tid == 0) emaxp[0] = e;
}

// ---------------- tokenize + embed ----------------
__global__ __launch_bounds__(64) void embed_k(const float* __restrict__ selected,
    const float* __restrict__ bsum, const float* __restrict__ emaxp,
    const float* __restrict__ temb, const float* __restrict__ cls,
    float* __restrict__ x)
{
  int rowi = blockIdx.x;
  int b = rowi / N_, n = rowi % N_;
  int tid = threadIdx.x;
  const float* src;
  if (n == 0){
    src = cls;
  } else {
    float val = selected[(long)b*KSEL + (n - 1)];
    float e = log1pf(val / fmaxf(bsum[b], 1e-12f) * 10000.0f);
    float step = emaxp[0] / 7.0f;              // matches jnp.linspace step
    int cnt = 0;
    #pragma unroll
    for (int i = 0; i < 7; i++) cnt += (((float)i * step) < e) ? 1 : 0;  // searchsorted 'left'
    int tok = cnt > 6 ? 6 : cnt;
    src = temb + (long)tok * D_;
  }
  float4 o = *(const float4*)(src + tid*4);
  *(float4*)(x + (long)rowi*D_ + tid*4) = o;
}

// ---------------- LayerNorm: one wave per row, bf16 output ----------------
__global__ __launch_bounds__(256) void ln_k(const float* __restrict__ x,
    unsigned short* __restrict__ out,
    const float* __restrict__ g, const float* __restrict__ bb)
{
  int row = blockIdx.x*4 + (threadIdx.x >> 6);
  int lane = threadIdx.x & 63;
  float4 v = *(const float4*)(x + (long)row*D_ + lane*4);
  float s = v.x + v.y + v.z + v.w;
  float q = v.x*v.x + v.y*v.y + v.z*v.z + v.w*v.w;
  #pragma unroll
  for (int m = 1; m < 64; m <<= 1){ s += __shfl_xor(s, m); q += __shfl_xor(q, m); }
  float mu  = s * (1.0f/D_);
  float var = q * (1.0f/D_) - mu*mu;
  float inv = 1.0f / sqrtf(fmaxf(var, 0.f) + 1e-5f);
  float4 gu = *(const float4*)(g + lane*4);
  float4 bu = *(const float4*)(bb + lane*4);
  ushort4 o;
  o.x = f2us((v.x - mu)*inv*gu.x + bu.x);
  o.y = f2us((v.y - mu)*inv*gu.y + bu.y);
  o.z = f2us((v.z - mu)*inv*gu.z + bu.z);
  o.w = f2us((v.w - mu)*inv*gu.w + bu.w);
  *(ushort4*)(out + (long)row*D_ + lane*4) = o;
}

// ---------------- weight convert + transpose: dst[n][k] = bf16(src[k][n]) ----------------
__global__ __launch_bounds__(256) void wcvt_k(const float* __restrict__ src, long srcL,
    unsigned short* __restrict__ dst, long dstL, int K, int N)
{
  __shared__ float t[32][33];
  int n0 = blockIdx.x*32, k0 = blockIdx.y*32, L = blockIdx.z;
  int tx = threadIdx.x & 31, ty = threadIdx.x >> 5;
  const float* s = src + (long)L*srcL;
  for (int i = ty; i < 32; i += 8)
    t[i][tx] = s[(long)(k0+i)*N + n0 + tx];
  __syncthreads();
  unsigned short* d = dst + (long)L*dstL;
  for (int i = ty; i < 32; i += 8)
    d[(long)(n0 + i)*K + k0 + tx] = f2us(t[tx][i]);
}

// ---------------- proj convert + zero kmax slots ----------------
__global__ __launch_bounds__(256) void pcvt_k(const float* __restrict__ proj,
                                              unsigned short* __restrict__ projb,
                                              unsigned* __restrict__ kmaxb)
{
  int L = blockIdx.x;
  if (blockIdx.x == 0 && threadIdx.x < DEPTH_) kmaxb[threadIdx.x] = 0u;
  for (int i = threadIdx.x; i < 112*32; i += 256){
    int m = i >> 5, d = i & 31;
    float v = (m < M_) ? proj[(long)L*M_*DH + m*DH + d] : 0.f;
    projb[(long)L*112*32 + i] = f2us(v);
  }
}

// ---------------- bias concat: bqkv[L][768] = [bq|bk|bv] ----------------
__global__ __launch_bounds__(256) void bcat_k(const float* __restrict__ bq,
    const float* __restrict__ bk, const float* __restrict__ bv,
    float* __restrict__ bqkv)
{
  int L = blockIdx.x;
  for (int i = threadIdx.x; i < QS; i += 256){
    float v = (i < 256) ? bq[L*256 + i] : (i < 512) ? bk[L*256 + i - 256] : bv[L*256 + i - 512];
    bqkv[(long)L*QS + i] = v;
  }
}

// ---------------- bf16 MFMA GEMM, prefetch pipeline, coalesced bf16 epilogue ----------------
// grid: (colBlocks, rowBlocks) — consecutive blocks share the A row-tile (L2 locality)
template<int ACT, int RES, int OUTBF>
__global__ __launch_bounds__(256) void bgemm_k(
    const unsigned short* __restrict__ A, long lda,
    const unsigned short* __restrict__ Bt,
    const float* __restrict__ bias,
    const float* __restrict__ res,
    float* __restrict__ Cf, unsigned short* __restrict__ Cb,
    int M, int Nn, int K)
{
  // OUTBF=1 overlays a 128x132 bf16 C-tile on the staging buffers after the K loop
  __shared__ __attribute__((aligned(16))) unsigned short smem[OUTBF ? 128*132 : 2*128*40];
  unsigned short* As = smem;
  unsigned short* Bs = smem + 128*40;
  int tid = threadIdx.x;
  int colBlk = blockIdx.x*128, rowBlk = blockIdx.y*128;
  int w = tid >> 6, lane = tid & 63;
  int wrow = (w >> 1)*64, wcol = (w & 1)*64;
  int fr = lane & 15, fk = (lane >> 4)*8, fq = lane >> 4;
  int srh = tid >> 2, sk8 = (tid & 3)*8;

  f4v acc[4][4];
  #pragma unroll
  for (int r = 0; r < 4; r++)
    #pragma unroll
    for (int c = 0; c < 4; c++) acc[r][c] = (f4v){0.f, 0.f, 0.f, 0.f};

  s8v pa[2], pb[2];
  #pragma unroll
  for (int half = 0; half < 2; half++){
    int r = half*64 + srh;
    int ar = rowBlk + r;
    pa[half] = (ar < M) ? *(const s8v*)(A + (long)ar*lda + sk8) : (s8v){0,0,0,0,0,0,0,0};
    pb[half] = *(const s8v*)(Bt + (long)(colBlk + r)*K + sk8);
  }

  for (int kt = 0; kt < K; kt += 32){
    __syncthreads();
    #pragma unroll
    for (int half = 0; half < 2; half++){
      int r = half*64 + srh;
      *(s8v*)&As[r*40 + sk8] = pa[half];
      *(s8v*)&Bs[r*40 + sk8] = pb[half];
    }
    __syncthreads();
    if (kt + 32 < K){
      int kn = kt + 32;
      #pragma unroll
      for (int half = 0; half < 2; half++){
        int r = half*64 + srh;
        int ar = rowBlk + r;
        pa[half] = (ar < M) ? *(const s8v*)(A + (long)ar*lda + kn + sk8) : (s8v){0,0,0,0,0,0,0,0};
        pb[half] = *(const s8v*)(Bt + (long)(colBlk + r)*K + kn + sk8);
      }
    }
    s8v a[4], b[4];
    #pragma unroll
    for (int r = 0; r < 4; r++) a[r] = *(s8v*)&As[(wrow + r*16 + fr)*40 + fk];
    #pragma unroll
    for (int c = 0; c < 4; c++) b[c] = *(s8v*)&Bs[(wcol + c*16 + fr)*40 + fk];
    #pragma unroll
    for (int r = 0; r < 4; r++)
      #pragma unroll
      for (int c = 0; c < 4; c++)
        acc[r][c] = __builtin_amdgcn_mfma_f32_16x16x32_bf16(a[r], b[c], acc[r][c], 0, 0, 0);
  }

  if (OUTBF){
    __syncthreads();                       // fragment reads done; reuse smem as C tile
    unsigned short* Cs = smem;             // [128][132]
    #pragma unroll
    for (int c = 0; c < 4; c++){
      int col = wcol + c*16 + fr;
      float bz = bias[colBlk + col];
      #pragma unroll
      for (int r = 0; r < 4; r++){
        #pragma unroll
        for (int j = 0; j < 4; j++){
          int rrow = wrow + r*16 + fq*4 + j;
          float val = acc[r][c][j] + bz;
          if (ACT == 1) val = 0.5f * val * (1.0f + erff(val * 0.70710678118654752f));
          Cs[rrow*132 + col] = f2us(val);
        }
      }
    }
    __syncthreads();
    for (int ci = tid; ci < 128*16; ci += 256){
      int rrow = ci >> 4, ch = ci & 15;
      int grow = rowBlk + rrow;
      if (grow < M)
        *(s8v*)(Cb + (long)grow*Nn + colBlk + ch*8) = *(s8v*)&Cs[rrow*132 + ch*8];
    }
  } else {
    #pragma unroll
    for (int c = 0; c < 4; c++){
      int col = colBlk + wcol + c*16 + fr;
      float bz = bias[col];
      #pragma unroll
      for (int r = 0; r < 4; r++){
        #pragma unroll
        for (int j = 0; j < 4; j++){
          int row = rowBlk + wrow + r*16 + fq*4 + j;
          if (row < M){
            float val = acc[r][c][j] + bz;
            if (ACT == 1) val = 0.5f * val * (1.0f + erff(val * 0.70710678118654752f));
            if (RES) val += res[(long)row*Nn + col];
            Cf[(long)row*Nn + col] = val;
          }
        }
      }
    }
  }
}

// ---------------- fp32 GEMM (head only: 8 rows) ----------------
__global__ __launch_bounds__(256) void gemm_k(
    const float* __restrict__ A, long lda,
    const float* __restrict__ Bw, long ldb,
    const float* __restrict__ bias,
    float* __restrict__ Cf,
    int M, int Nn, int K)
{
  __shared__ float As[16][64];
  __shared__ float Bs[16][64];
  int tid = threadIdx.x;
  int tx = tid & 15, ty = tid >> 4;
  int rowBlk = blockIdx.x * 64, colBlk = blockIdx.y * 64;
  int am = tid >> 2, ak = (tid & 3) * 4;
  int bk = tid >> 4, bc = (tid & 15) * 4;
  float acc[4][4];
  #pragma unroll
  for (int i = 0; i < 4; i++)
    #pragma unroll
    for (int j = 0; j < 4; j++) acc[i][j] = 0.f;

  for (int kt = 0; kt < K; kt += 16){
    float4 av = make_float4(0.f, 0.f, 0.f, 0.f);
    int ar = rowBlk + am;
    if (ar < M) av = *(const float4*)(A + (long)ar*lda + kt + ak);
    As[ak+0][am] = av.x; As[ak+1][am] = av.y; As[ak+2][am] = av.z; As[ak+3][am] = av.w;
    float4 bv4 = *(const float4*)(Bw + (long)(kt + bk)*ldb + colBlk + bc);
    Bs[bk][bc+0] = bv4.x; Bs[bk][bc+1] = bv4.y;
    Bs[bk][bc+2] = bv4.z; Bs[bk][bc+3] = bv4.w;
    __syncthreads();
    #pragma unroll
    for (int kk = 0; kk < 16; kk++){
      float4 a4 = *(const float4*)&As[kk][ty*4];
      float4 b4 = *(const float4*)&Bs[kk][tx*4];
      acc[0][0] += a4.x*b4.x; acc[0][1] += a4.x*b4.y; acc[0][2] += a4.x*b4.z; acc[0][3] += a4.x*b4.w;
      acc[1][0] += a4.y*b4.x; acc[1][1] += a4.y*b4.y; acc[1][2] += a4.y*b4.z; acc[1][3] += a4.y*b4.w;
      acc[2][0] += a4.z*b4.x; acc[2][1] += a4.z*b4.y; acc[2][2] += a4.z*b4.z; acc[2][3] += a4.z*b4.w;
      acc[3][0] += a4.w*b4.x; acc[3][1] += a4.w*b4.y; acc[3][2] += a4.w*b4.z; acc[3][3] += a4.w*b4.w;
    }
    __syncthreads();
  }
  int r0 = rowBlk + ty*4, c0 = colBlk + tx*4;
  float bz[4];
  #pragma unroll
  for (int j = 0; j < 4; j++) bz[j] = bias[c0 + j];
  #pragma unroll
  for (int i = 0; i < 4; i++){
    int r = r0 + i;
    if (r < M){
      #pragma unroll
      for (int j = 0; j < 4; j++)
        Cf[(long)r*Nn + c0 + j] = acc[i][j] + bz[j];
    }
  }
}

// ---------------- kmax via MFMA (reads k slice of fused qkv) ----------------
__global__ __launch_bounds__(256) void kmax2_k(const float* __restrict__ qkv,
    const unsigned short* __restrict__ projb, unsigned* __restrict__ kmaxb)
{
  __shared__ __attribute__((aligned(16))) unsigned short ks[64*40];
  __shared__ float red[4];
  int t = blockIdx.x, h = blockIdx.y, b = blockIdx.z;
  int tid = threadIdx.x, w = tid >> 6, lane = tid & 63;
  int fr = lane & 15, fq = lane >> 4, fk = fq*8;
  int n0 = t*64;
  #pragma unroll
  for (int it = 0; it < 2; it++){
    int tok = it*32 + (tid >> 3), d4 = tid & 7;
    int n = n0 + tok;
    bool vld = (n < N_);
    long gb = ((long)(b*N_ + (vld ? n : 0)))*QS + 256 + h*DH + d4*4;
    float4 kv = vld ? *(const float4*)(qkv + gb) : make_float4(0,0,0,0);
    ushort4 ku; ku.x=f2us(kv.x); ku.y=f2us(kv.y); ku.z=f2us(kv.z); ku.w=f2us(kv.w);
    *(ushort4*)&ks[tok*40 + d4*4] = ku;
  }
  __syncthreads();
  s8v bk_ = *(s8v*)&ks[(w*16 + fr)*40 + fk];
  float mx = -INFINITY;
  int n_ = w*16 + fr;
  bool nv = (n0 + n_ < N_);
  #pragma unroll
  for (int mt = 0; mt < 7; mt++){
    s8v ap = *(const s8v*)(projb + (mt*16 + fr)*32 + fk);
    f4v z = (f4v){0.f,0.f,0.f,0.f};
    f4v xd = __builtin_amdgcn_mfma_f32_16x16x32_bf16(ap, bk_, z, 0, 0, 0);
    #pragma unroll
    for (int j = 0; j < 4; j++){
      int m = mt*16 + fq*4 + j;
      float v = (nv && m < M_) ? xd[j]*DN : -INFINITY;
      mx = fmaxf(mx, v);
    }
  }
  #pragma unroll
  for (int mk = 1; mk < 64; mk <<= 1) mx = fmaxf(mx, __shfl_xor(mx, mk));
  if (lane == 0) red[w] = mx;
  __syncthreads();
  if (tid == 0){
    float g = fmaxf(fmaxf(red[0], red[1]), fmaxf(red[2], red[3]));
    atomicMax(kmaxb, floatToOrdered(g));
  }
}

// ---------------- fused ctx via double MFMA (k/v from fused qkv) ----------------
__global__ __launch_bounds__(256) void fctx_k(const float* __restrict__ qkv,
    const unsigned short* __restrict__ projb,
    const unsigned* __restrict__ kmaxb, float* __restrict__ partials)
{
  __shared__ __attribute__((aligned(16))) unsigned short ks[64*40];
  __shared__ __attribute__((aligned(16))) unsigned short vt[48*72];
  __shared__ __attribute__((aligned(16))) unsigned short kps[112*72];
  __shared__ float diags[64];
  int c = blockIdx.x, h = blockIdx.y, b = blockIdx.z;
  int tid = threadIdx.x, w = tid >> 6, lane = tid & 63;
  int fr = lane & 15, fq = lane >> 4, fk = fq*8;
  float kmax = orderedToFloat(kmaxb[0]);

  for (int i = tid; i < 15*72; i += 256) vt[33*72 + i] = 0;
  if (tid < 64) vt[32*72 + tid] = f2us(1.0f);

  s8v ap[7];
  #pragma unroll
  for (int mt = 0; mt < 7; mt++)
    ap[mt] = *(const s8v*)(projb + (mt*16 + fr)*32 + fk);

  int mt0 = w, mt1 = w + 4;
  f4v acc0[3], acc1[3];
  #pragma unroll
  for (int dt = 0; dt < 3; dt++){ acc0[dt] = (f4v){0.f,0.f,0.f,0.f}; acc1[dt] = (f4v){0.f,0.f,0.f,0.f}; }

  for (int t = c; t < NTILES; t += NC){
    int n0 = t*64;
    __syncthreads();
    #pragma unroll
    for (int it = 0; it < 2; it++){
      int tok = it*32 + (tid >> 3), d4 = tid & 7;
      int n = n0 + tok;
      bool vld = (n < N_);
      long gb = ((long)(b*N_ + (vld ? n : 0)))*QS + 256 + h*DH + d4*4;
      float4 kv = vld ? *(const float4*)(qkv + gb) : make_float4(0,0,0,0);
      float4 vv = vld ? *(const float4*)(qkv + gb + 256) : make_float4(0,0,0,0);
      ushort4 ku; ku.x=f2us(kv.x); ku.y=f2us(kv.y); ku.z=f2us(kv.z); ku.w=f2us(kv.w);
      *(ushort4*)&ks[tok*40 + d4*4] = ku;
      vt[(d4*4+0)*72 + tok] = f2us(vv.x);
      vt[(d4*4+1)*72 + tok] = f2us(vv.y);
      vt[(d4*4+2)*72 + tok] = f2us(vv.z);
      vt[(d4*4+3)*72 + tok] = f2us(vv.w);
      float sq = kv.x*kv.x + kv.y*kv.y + kv.z*kv.z + kv.w*kv.w;
      sq += __shfl_xor(sq, 1); sq += __shfl_xor(sq, 2); sq += __shfl_xor(sq, 4);
      if (d4 == 0) diags[tok] = 0.5f * DN2 * sq;
    }
    __syncthreads();
    s8v bk_ = *(s8v*)&ks[(w*16 + fr)*40 + fk];
    int n_ = w*16 + fr;
    bool nv = (n0 + n_ < N_);
    float dgn = diags[n_];
    #pragma unroll
    for (int mt = 0; mt < 7; mt++){
      f4v z = (f4v){0.f,0.f,0.f,0.f};
      f4v xd = __builtin_amdgcn_mfma_f32_16x16x32_bf16(ap[mt], bk_, z, 0, 0, 0);
      #pragma unroll
      for (int j = 0; j < 4; j++){
        float kp = nv ? RATIO*(expf(xd[j]*DN - dgn - kmax) + 1e-3f) : 0.f;
        kps[(mt*16 + fq*4 + j)*72 + n_] = f2us(kp);
      }
    }
    __syncthreads();
    #pragma unroll
    for (int kst = 0; kst < 2; kst++){
      int ko = kst*32 + fk;
      s8v b0 = *(s8v*)&vt[( 0 + fr)*72 + ko];
      s8v b1 = *(s8v*)&vt[(16 + fr)*72 + ko];
      s8v b2 = *(s8v*)&vt[(32 + fr)*72 + ko];
      s8v a0 = *(s8v*)&kps[(mt0*16 + fr)*72 + ko];
      acc0[0] = __builtin_amdgcn_mfma_f32_16x16x32_bf16(a0, b0, acc0[0], 0, 0, 0);
      acc0[1] = __builtin_amdgcn_mfma_f32_16x16x32_bf16(a0, b1, acc0[1], 0, 0, 0);
      acc0[2] = __builtin_amdgcn_mfma_f32_16x16x32_bf16(a0, b2, acc0[2], 0, 0, 0);
      if (mt1 < 7){
        s8v a1 = *(s8v*)&kps[(mt1*16 + fr)*72 + ko];
        acc1[0] = __builtin_amdgcn_mfma_f32_16x16x32_bf16(a1, b0, acc1[0], 0, 0, 0);
        acc1[1] = __builtin_amdgcn_mfma_f32_16x16x32_bf16(a1, b1, acc1[1], 0, 0, 0);
        acc1[2] = __builtin_amdgcn_mfma_f32_16x16x32_bf16(a1, b2, acc1[2], 0, 0, 0);
      }
    }
  }
  long pb = ((long)c*64 + (b*H_ + h))*CTXE;
  #pragma unroll
  for (int dt = 0; dt < 3; dt++){
    int d = dt*16 + fr;
    if (d < 33){
      #pragma unroll
      for (int j = 0; j < 4; j++){
        int m0 = mt0*16 + fq*4 + j;
        if (m0 < M_) partials[pb + m0*33 + d] = acc0[dt][j];
        if (mt1 < 7){
          int m1 = mt1*16 + fq*4 + j;
          if (m1 < M_) partials[pb + m1*33 + d] = acc1[dt][j];
        }
      }
    }
  }
}

// ---------------- ctx partial reduce ----------------
__global__ __launch_bounds__(256) void ctxred2_k(const float* __restrict__ partials,
                                                 float* __restrict__ ctxf)
{
  int i = blockIdx.x*256 + threadIdx.x;
  if (i >= CTXN2) return;
  float s = 0.f;
  #pragma unroll
  for (int c = 0; c < NC; c++) s += partials[(long)c*CTXN2 + i];
  ctxf[i] = s;
}

// ---------------- attn v3: full-MFMA query side (q from fused qkv) ----------------
__global__ __launch_bounds__(256) void attn3_k(const float* __restrict__ qkv,
    const float* __restrict__ ctxf, const unsigned short* __restrict__ projb,
    unsigned short* __restrict__ ob)
{
  __shared__ __attribute__((aligned(16))) unsigned short qs[64*40];
  __shared__ __attribute__((aligned(16))) unsigned short qps[64*136];
  __shared__ __attribute__((aligned(16))) unsigned short cst[48*136];
  __shared__ float diags[64];
  __shared__ float dens[64];
  int t = blockIdx.x, h = blockIdx.y, b = blockIdx.z;
  int tid = threadIdx.x, w = tid >> 6, lane = tid & 63;
  int fr = lane & 15, fq = lane >> 4, fk = fq*8;
  int n0 = t*64;
  long cbase = ((long)(b*H_ + h))*CTXE;

  for (int i = tid; i < 64*16; i += 256)
    qps[(i >> 4)*136 + 112 + (i & 15)] = 0;

  #pragma unroll
  for (int it = 0; it < 2; it++){
    int tok = it*32 + (tid >> 3), d4 = tid & 7;
    int n = n0 + tok;
    bool vld = (n < N_);
    long gb = ((long)(b*N_ + (vld ? n : 0)))*QS + h*DH + d4*4;
    float4 qv = vld ? *(const float4*)(qkv + gb) : make_float4(0,0,0,0);
    ushort4 qu; qu.x=f2us(qv.x); qu.y=f2us(qv.y); qu.z=f2us(qv.z); qu.w=f2us(qv.w);
    *(ushort4*)&qs[tok*40 + d4*4] = qu;
    float sq = qv.x*qv.x + qv.y*qv.y + qv.z*qv.z + qv.w*qv.w;
    sq += __shfl_xor(sq, 1); sq += __shfl_xor(sq, 2); sq += __shfl_xor(sq, 4);
    if (d4 == 0) diags[tok] = 0.5f * DN2 * sq;
  }
  for (int i = tid; i < 48*128; i += 256){
    int d = i >> 7, m = i & 127;
    float v = (d < 33 && m < M_) ? ctxf[cbase + (long)m*33 + d] : 0.f;
    cst[d*136 + m] = f2us(v);
  }
  __syncthreads();

  s8v bq_ = *(s8v*)&qs[(w*16 + fr)*40 + fk];
  int n_ = w*16 + fr;
  bool nv = (n0 + n_ < N_);
  float dgn = diags[n_];
  f4v xdv[7];
  #pragma unroll
  for (int mt = 0; mt < 7; mt++){
    s8v ap = *(const s8v*)(projb + (mt*16 + fr)*32 + fk);
    f4v z = (f4v){0.f,0.f,0.f,0.f};
    xdv[mt] = __builtin_amdgcn_mfma_f32_16x16x32_bf16(ap, bq_, z, 0, 0, 0);
  }
  float mx = -INFINITY;
  #pragma unroll
  for (int mt = 0; mt < 7; mt++)
    #pragma unroll
    for (int j = 0; j < 4; j++){
      int m = mt*16 + fq*4 + j;
      if (m < M_) mx = fmaxf(mx, xdv[mt][j]*DN);
    }
  mx = fmaxf(mx, __shfl_xor(mx, 16));
  mx = fmaxf(mx, __shfl_xor(mx, 32));
  #pragma unroll
  for (int mt = 0; mt < 7; mt++)
    #pragma unroll
    for (int j = 0; j < 4; j++){
      int m = mt*16 + fq*4 + j;
      float qp = (nv && m < M_) ? RATIO*(expf(xdv[mt][j]*DN - dgn - mx) + 1e-3f) : 0.f;
      qps[n_*136 + m] = f2us(qp);
    }
  __syncthreads();

  f4v acc[3];
  acc[0] = (f4v){0,0,0,0}; acc[1] = (f4v){0,0,0,0}; acc[2] = (f4v){0,0,0,0};
  #pragma unroll
  for (int ks = 0; ks < 4; ks++){
    int ko = ks*32 + fk;
    s8v bqp = *(s8v*)&qps[(w*16 + fr)*136 + ko];
    #pragma unroll
    for (int dt = 0; dt < 3; dt++){
      s8v ac = *(s8v*)&cst[(dt*16 + fr)*136 + ko];
      acc[dt] = __builtin_amdgcn_mfma_f32_16x16x32_bf16(ac, bqp, acc[dt], 0, 0, 0);
    }
  }
  if (fq == 0) dens[n_] = acc[2][0];
  __syncthreads();
  float dinv = 1.0f / dens[n_];
  if (nv){
    long obase = ((long)(b*N_ + n0 + n_))*D_ + h*DH;
    #pragma unroll
    for (int dt = 0; dt < 2; dt++){
      ushort4 wv;
      wv.x = f2us(acc[dt][0]*dinv);
      wv.y = f2us(acc[dt][1]*dinv);
      wv.z = f2us(acc[dt][2]*dinv);
      wv.w = f2us(acc[dt][3]*dinv);
      *(ushort4*)(ob + obase + dt*16 + fq*4) = wv;
    }
  }
}

// ---------------- host ----------------
extern "C" void kernel_launch(void* const* d_in, const int* in_sizes, int n_in,
                              void* d_out, int out_size, void* d_ws, size_t ws_size,
                              hipStream_t stream)
{
  const float* expr = (const float*)d_in[0];
  const float* temb = (const float*)d_in[1];
  const float* cls  = (const float*)d_in[2];
  const float* ln1g = (const float*)d_in[3];
  const float* ln1b = (const float*)d_in[4];
  const float* Wq   = (const float*)d_in[5];
  const float* bq   = (const float*)d_in[6];
  const float* Wk   = (const float*)d_in[7];
  const float* bk   = (const float*)d_in[8];
  const float* Wv   = (const float*)d_in[9];
  const float* bv   = (const float*)d_in[10];
  const float* Wo   = (const float*)d_in[11];
  const float* bo   = (const float*)d_in[12];
  const float* ln2g = (const float*)d_in[13];
  const float* ln2b = (const float*)d_in[14];
  const float* W1   = (const float*)d_in[15];
  const float* b1   = (const float*)d_in[16];
  const float* W2   = (const float*)d_in[17];
  const float* b2   = (const float*)d_in[18];
  const float* proj = (const float*)d_in[19];
  const float* Wp   = (const float*)d_in[20];
  const float* bp   = (const float*)d_in[21];
  (void)in_sizes; (void)n_in; (void)out_size; (void)ws_size;

  char* w = (char*)d_ws;
  size_t off = 0;
  auto alloc = [&](size_t bytes) -> char* {
    char* p = w + off;
    off = (off + bytes + 255) & ~(size_t)255;
    return p;
  };
  float*    selected = (float*)alloc((size_t)B_*KSEL*4);
  float*    bsum     = (float*)alloc(B_*4);
  float*    bv0      = (float*)alloc(B_*4);
  float*    emaxp    = (float*)alloc(4);
  unsigned* kmaxb    = (unsigned*)alloc(DEPTH_*4);
  float*    ctxf     = (float*)alloc((size_t)CTXN2*4);
  float*          x  = (float*)alloc((size_t)BN_*D_*4);
  unsigned short* h  = (unsigned short*)alloc((size_t)BN_*D_*2);
  float*        qkv  = (float*)alloc((size_t)BN_*QS*4);
  unsigned short* Wqkvt = (unsigned short*)alloc((size_t)DEPTH_*QS*D_*2);
  unsigned short* Wot = (unsigned short*)alloc((size_t)DEPTH_*D_*D_*2);
  unsigned short* W1t = (unsigned short*)alloc((size_t)DEPTH_*D_*DFF_*2);
  unsigned short* W2t = (unsigned short*)alloc((size_t)DEPTH_*DFF_*D_*2);
  unsigned short* projb = (unsigned short*)alloc((size_t)DEPTH_*112*32*2);
  float*    bqkv     = (float*)alloc((size_t)DEPTH_*QS*4);
  unsigned short* ffi = (unsigned short*)qkv;  // bf16 [BN][1024] aliases qkv (dead during FFN)
  float*     partials = (float*)h;             // NC*CTXN2*4 = 7.44 MB <= h (8.39 MB)

  // one-time weight/proj conversions (Wq/Wk/Wv into one concatenated [768][256] bf16)
  wcvt_k<<<dim3(8, 8, DEPTH_),  256, 0, stream>>>(Wq, (long)D_*D_, Wqkvt + 0,      (long)QS*D_, D_, D_);
  wcvt_k<<<dim3(8, 8, DEPTH_),  256, 0, stream>>>(Wk, (long)D_*D_, Wqkvt + 256*D_, (long)QS*D_, D_, D_);
  wcvt_k<<<dim3(8, 8, DEPTH_),  256, 0, stream>>>(Wv, (long)D_*D_, Wqkvt + 512*D_, (long)QS*D_, D_, D_);
  wcvt_k<<<dim3(8, 8, DEPTH_),  256, 0, stream>>>(Wo, (long)D_*D_,   Wot, (long)D_*D_,   D_, D_);
  wcvt_k<<<dim3(32, 8, DEPTH_), 256, 0, stream>>>(W1, (long)D_*DFF_, W1t, (long)D_*DFF_, D_, DFF_);
  wcvt_k<<<dim3(8, 32, DEPTH_), 256, 0, stream>>>(W2, (long)DFF_*D_, W2t, (long)DFF_*D_, DFF_, D_);
  pcvt_k<<<DEPTH_, 256, 0, stream>>>(proj, projb, kmaxb);
  bcat_k<<<DEPTH_, 256, 0, stream>>>(bq, bk, bv, bqkv);

  topk_k<<<B_, 1024, 0, stream>>>(expr, selected);
  nsum_k<<<B_, 256, 0, stream>>>(selected, bsum, bv0);
  emax_k<<<1, 64, 0, stream>>>(bsum, bv0, emaxp);
  embed_k<<<BN_, 64, 0, stream>>>(selected, bsum, emaxp, temb, cls, x);

  for (int L = 0; L < DEPTH_; L++){
    const unsigned short* pjb = projb + (size_t)L*112*32;
    ln_k<<<BN_/4, 256, 0, stream>>>(x, h, ln1g + L*D_, ln1b + L*D_);
    bgemm_k<0,0,0><<<dim3(6,129), 256, 0, stream>>>(h, D_, Wqkvt + (size_t)L*QS*D_, bqkv + (size_t)L*QS, nullptr, qkv, nullptr, BN_, QS, D_);
    kmax2_k<<<dim3(NTILES, H_, B_), 256, 0, stream>>>(qkv, pjb, kmaxb + L);
    fctx_k<<<dim3(NC, H_, B_), 256, 0, stream>>>(qkv, pjb, kmaxb + L, partials);
    ctxred2_k<<<(CTXN2 + 255)/256, 256, 0, stream>>>(partials, ctxf);
    attn3_k<<<dim3(NTILES, H_, B_), 256, 0, stream>>>(qkv, ctxf, pjb, h);   // o -> h (bf16)
    bgemm_k<0,1,0><<<dim3(2,129), 256, 0, stream>>>(h, D_, Wot + (size_t)L*D_*D_, bo + L*D_, x, x, nullptr, BN_, D_, D_);
    ln_k<<<BN_/4, 256, 0, stream>>>(x, h, ln2g + L*D_, ln2b + L*D_);
    bgemm_k<1,0,1><<<dim3(8,129), 256, 0, stream>>>(h, D_, W1t + (size_t)L*D_*DFF_, b1 + L*DFF_, nullptr, nullptr, ffi, BN_, DFF_, D_);
    bgemm_k<0,1,0><<<dim3(2,129), 256, 0, stream>>>(ffi, DFF_, W2t + (size_t)L*DFF_*D_, b2 + L*D_, x, x, nullptr, BN_, D_, DFF_);
  }
  gemm_k<<<dim3(1,4), 256, 0, stream>>>(x, (long)N_*D_, Wp, D_, bp,
                                        (float*)d_out, B_, D_, D_);
}

// Round 14
// 1386.270 us; speedup vs baseline: 5.6755x; 1.0283x over previous
//
#include <hip/hip_runtime.h>
#include <hip/hip_bf16.h>

#define B_    8
#define NG    16906
#define KSEL  2048
#define D_    256
#define H_    8
#define DH    32
#define M_    110
#define DEPTH_ 6
#define DFF_  1024
#define N_    2049
#define BN_   (B_*N_)
#define QS    768          // fused qkv row stride
#define NC    8            // fctx chunks (blocks per (b,h))
#define NTILES 33          // ceil(2049/64)
#define CTXE  (M_*33)      // 3630 per (b,h)
#define CTXN2 (64*CTXE)    // 232320
#define NIT_TK 17          // ceil(16906/1024)

static constexpr float DN    = 0.42044820762685725f;  // 32^-0.25
static constexpr float DN2   = 0.17677669529663687f;  // 32^-0.5
static constexpr float RATIO = 0.09534625892455922f;  // 110^-0.5

typedef __attribute__((ext_vector_type(8))) short s8v;
typedef __attribute__((ext_vector_type(4))) float f4v;

__device__ __forceinline__ unsigned floatToOrdered(float f){
  unsigned b = __float_as_uint(f);
  return (b & 0x80000000u) ? ~b : (b | 0x80000000u);
}
__device__ __forceinline__ float orderedToFloat(unsigned u){
  unsigned b = (u & 0x80000000u) ? (u & 0x7FFFFFFFu) : ~u;
  return __uint_as_float(b);
}
__device__ __forceinline__ unsigned short f2us(float f){
  __hip_bfloat16 b = __float2bfloat16(f);
  return *reinterpret_cast<unsigned short*>(&b);
}

// ---------------- top-k: radix select, parallel suffix-scan threshold search ----------------
__global__ __launch_bounds__(1024) void topk_k(const float* __restrict__ expr,
                                               float* __restrict__ selected)
{
  __shared__ unsigned histw[16*256];
  __shared__ unsigned sPrefix;
  __shared__ int sKK;
  __shared__ unsigned cGT, cEQ;
  int b = blockIdx.x, tid = threadIdx.x;
  int wv = tid >> 6, lane = tid & 63;
  const float* row = expr + (long)b*NG;
  unsigned rb[NIT_TK];
  #pragma unroll
  for (int i = 0; i < NIT_TK; i++){
    int idx = tid + i*1024;
    rb[i] = (idx < NG) ? __float_as_uint(row[idx]) : 0u;
  }
  if (tid == 0){ sPrefix = 0u; sKK = KSEL; }
  for (int pass = 0; pass < 4; ++pass){
    int shift = 24 - pass*8;
    for (int i = tid; i < 16*256; i += 1024) histw[i] = 0u;
    __syncthreads();                       // orders sPrefix/sKK writes too
    unsigned pref = sPrefix;
    unsigned kk  = (unsigned)sKK;
    #pragma unroll
    for (int i = 0; i < NIT_TK; i++){
      int idx = tid + i*1024;
      unsigned bits = rb[i];
      bool ok = (idx < NG) && ((pass == 0) || ((bits >> (shift + 8)) == pref));
      if (ok) atomicAdd(&histw[wv*256 + ((bits >> shift) & 255u)], 1u);
    }
    __syncthreads();
    if (tid < 256){
      unsigned s = 0;
      #pragma unroll
      for (int w = 0; w < 16; w++) s += histw[w*256 + tid];
      histw[tid] = s;                      // thread j touches only index j — no hazard
    }
    __syncthreads();
    // parallel suffix-sum (Hillis-Steele, ping-pong in histw[0..511])
    unsigned* bufA = histw;
    unsigned* bufB = histw + 256;
    for (int d = 1; d < 256; d <<= 1){
      if (tid < 256)
        bufB[tid] = bufA[tid] + ((tid + d < 256) ? bufA[tid + d] : 0u);
      __syncthreads();
      unsigned* t = bufA; bufA = bufB; bufB = t;
    }
    // select: largest j with suffix[j] >= kk  (== serial top-down scan)
    if (tid < 256){
      unsigned sj  = bufA[tid];
      unsigned sj1 = (tid < 255) ? bufA[tid + 1] : 0u;
      if (sj >= kk && sj1 < kk){           // unique j
        sPrefix = (pref << 8) | (unsigned)tid;
        sKK = (int)(kk - sj1);
      }
    }
    __syncthreads();
  }
  unsigned T = sPrefix; int needEQ = sKK; int base = KSEL - needEQ;
  if (tid == 0){ cGT = 0u; cEQ = 0u; }
  __syncthreads();
  #pragma unroll
  for (int i = 0; i < NIT_TK; i++){
    int idx = tid + i*1024;
    bool v = (idx < NG);
    unsigned bits = rb[i];
    bool gt = v && (bits > T);
    unsigned long long mgt = __ballot(gt);
    if (mgt){
      int leader = __ffsll((long long)mgt) - 1;
      unsigned wbase = 0;
      if (lane == leader) wbase = atomicAdd(&cGT, (unsigned)__popcll(mgt));
      wbase = __shfl(wbase, leader);
      if (gt){
        int pre = __popcll(mgt & ((1ULL << lane) - 1ULL));
        selected[(long)b*KSEL + wbase + pre] = __uint_as_float(bits);
      }
    }
    bool eq = v && (bits == T);
    unsigned long long meq = __ballot(eq);
    if (meq){
      int leader = __ffsll((long long)meq) - 1;
      unsigned wbase = 0;
      if (lane == leader) wbase = atomicAdd(&cEQ, (unsigned)__popcll(meq));
      wbase = __shfl(wbase, leader);
      if (eq){
        int pos = (int)wbase + __popcll(meq & ((1ULL << lane) - 1ULL));
        if (pos < needEQ) selected[(long)b*KSEL + base + pos] = __uint_as_float(bits);
      }
    }
  }
}

// ---------------- per-batch sum + max of selected ----------------
__global__ __launch_bounds__(256) void nsum_k(const float* __restrict__ selected,
                                              float* __restrict__ bsum, float* __restrict__ bv0)
{
  __shared__ float rs[256], rm[256];
  int b = blockIdx.x, tid = threadIdx.x;
  float s = 0.f, m = -INFINITY;
  for (int i = tid; i < KSEL; i += 256){ float v = selected[(long)b*KSEL + i]; s += v; m = fmaxf(m, v); }
  rs[tid] = s; rm[tid] = m; __syncthreads();
  for (int k = 128; k > 0; k >>= 1){
    if (tid < k){ rs[tid] += rs[tid + k]; rm[tid] = fmaxf(rm[tid], rm[tid + k]); }
    __syncthreads();
  }
  if (tid == 0){ bsum[b] = rs[0]; bv0[b] = rm[0]; }
}

// ---------------- global max of e = log1p(v0/sum*1e4) ----------------
__global__ __launch_bounds__(64) void emax_k(const float* __restrict__ bsum,
                                             const float* __restrict__ bv0,
                                             float* __restrict__ emaxp)
{
  int tid = threadIdx.x;
  float e = -INFINITY;
  if (tid < B_) e = log1pf(bv0[tid] / fmaxf(bsum[tid], 1e-12f) * 10000.0f);
  #pragma unroll
  for (int m = 1; m < 64; m <<= 1) e = fmaxf(e, __shfl_xor(e, m));
  if (tid == 0) emaxp[0] = e;
}

// ---------------- tokenize + embed ----------------
__global__ __launch_bounds__(64) void embed_k(const float* __restrict__ selected,
    const float* __restrict__ bsum, const float* __restrict__ emaxp,
    const float* __restrict__ temb, const float* __restrict__ cls,
    float* __restrict__ x)
{
  int rowi = blockIdx.x;
  int b = rowi / N_, n = rowi % N_;
  int tid = threadIdx.x;
  const float* src;
  if (n == 0){
    src = cls;
  } else {
    float val = selected[(long)b*KSEL + (n - 1)];
    float e = log1pf(val / fmaxf(bsum[b], 1e-12f) * 10000.0f);
    float step = emaxp[0] / 7.0f;              // matches jnp.linspace step
    int cnt = 0;
    #pragma unroll
    for (int i = 0; i < 7; i++) cnt += (((float)i * step) < e) ? 1 : 0;  // searchsorted 'left'
    int tok = cnt > 6 ? 6 : cnt;
    src = temb + (long)tok * D_;
  }
  float4 o = *(const float4*)(src + tid*4);
  *(float4*)(x + (long)rowi*D_ + tid*4) = o;
}

// ---------------- LayerNorm: one wave per row, bf16 output ----------------
__global__ __launch_bounds__(256) void ln_k(const float* __restrict__ x,
    unsigned short* __restrict__ out,
    const float* __restrict__ g, const float* __restrict__ bb)
{
  int row = blockIdx.x*4 + (threadIdx.x >> 6);
  int lane = threadIdx.x & 63;
  float4 v = *(const float4*)(x + (long)row*D_ + lane*4);
  float s = v.x + v.y + v.z + v.w;
  float q = v.x*v.x + v.y*v.y + v.z*v.z + v.w*v.w;
  #pragma unroll
  for (int m = 1; m < 64; m <<= 1){ s += __shfl_xor(s, m); q += __shfl_xor(q, m); }
  float mu  = s * (1.0f/D_);
  float var = q * (1.0f/D_) - mu*mu;
  float inv = 1.0f / sqrtf(fmaxf(var, 0.f) + 1e-5f);
  float4 gu = *(const float4*)(g + lane*4);
  float4 bu = *(const float4*)(bb + lane*4);
  ushort4 o;
  o.x = f2us((v.x - mu)*inv*gu.x + bu.x);
  o.y = f2us((v.y - mu)*inv*gu.y + bu.y);
  o.z = f2us((v.z - mu)*inv*gu.z + bu.z);
  o.w = f2us((v.w - mu)*inv*gu.w + bu.w);
  *(ushort4*)(out + (long)row*D_ + lane*4) = o;
}

// ---------------- weight convert + transpose: dst[n][k] = bf16(src[k][n]) ----------------
__global__ __launch_bounds__(256) void wcvt_k(const float* __restrict__ src, long srcL,
    unsigned short* __restrict__ dst, long dstL, int K, int N)
{
  __shared__ float t[32][33];
  int n0 = blockIdx.x*32, k0 = blockIdx.y*32, L = blockIdx.z;
  int tx = threadIdx.x & 31, ty = threadIdx.x >> 5;
  const float* s = src + (long)L*srcL;
  for (int i = ty; i < 32; i += 8)
    t[i][tx] = s[(long)(k0+i)*N + n0 + tx];
  __syncthreads();
  unsigned short* d = dst + (long)L*dstL;
  for (int i = ty; i < 32; i += 8)
    d[(long)(n0 + i)*K + k0 + tx] = f2us(t[tx][i]);
}

// ---------------- proj convert + zero kmax slots ----------------
__global__ __launch_bounds__(256) void pcvt_k(const float* __restrict__ proj,
                                              unsigned short* __restrict__ projb,
                                              unsigned* __restrict__ kmaxb)
{
  int L = blockIdx.x;
  if (blockIdx.x == 0 && threadIdx.x < DEPTH_) kmaxb[threadIdx.x] = 0u;
  for (int i = threadIdx.x; i < 112*32; i += 256){
    int m = i >> 5, d = i & 31;
    float v = (m < M_) ? proj[(long)L*M_*DH + m*DH + d] : 0.f;
    projb[(long)L*112*32 + i] = f2us(v);
  }
}

// ---------------- bias concat: bqkv[L][768] = [bq|bk|bv] ----------------
__global__ __launch_bounds__(256) void bcat_k(const float* __restrict__ bq,
    const float* __restrict__ bk, const float* __restrict__ bv,
    float* __restrict__ bqkv)
{
  int L = blockIdx.x;
  for (int i = threadIdx.x; i < QS; i += 256){
    float v = (i < 256) ? bq[L*256 + i] : (i < 512) ? bk[L*256 + i - 256] : bv[L*256 + i - 512];
    bqkv[(long)L*QS + i] = v;
  }
}

// ---------------- bf16 MFMA GEMM: double-buffered LDS, one barrier per K-step ----------------
// grid: (colBlocks, rowBlocks) — consecutive blocks share the A row-tile (L2 locality)
template<int ACT, int RES, int OUTBF>
__global__ __launch_bounds__(256) void bgemm_k(
    const unsigned short* __restrict__ A, long lda,
    const unsigned short* __restrict__ Bt,
    const float* __restrict__ bias,
    const float* __restrict__ res,
    float* __restrict__ Cf, unsigned short* __restrict__ Cb,
    int M, int Nn, int K)
{
  // 2 buffers x (As+Bs) = 20480 shorts = 40 KB; OUTBF C-tile overlay (16896 shorts) fits
  __shared__ __attribute__((aligned(16))) unsigned short smem[2*2*128*40];
  int tid = threadIdx.x;
  int colBlk = blockIdx.x*128, rowBlk = blockIdx.y*128;
  int w = tid >> 6, lane = tid & 63;
  int wrow = (w >> 1)*64, wcol = (w & 1)*64;
  int fr = lane & 15, fk = (lane >> 4)*8, fq = lane >> 4;
  int srh = tid >> 2, sk8 = (tid & 3)*8;

  f4v acc[4][4];
  #pragma unroll
  for (int r = 0; r < 4; r++)
    #pragma unroll
    for (int c = 0; c < 4; c++) acc[r][c] = (f4v){0.f, 0.f, 0.f, 0.f};

  s8v pa[2], pb[2];
  #pragma unroll
  for (int half = 0; half < 2; half++){
    int r = half*64 + srh;
    int ar = rowBlk + r;
    pa[half] = (ar < M) ? *(const s8v*)(A + (long)ar*lda + sk8) : (s8v){0,0,0,0,0,0,0,0};
    pb[half] = *(const s8v*)(Bt + (long)(colBlk + r)*K + sk8);
  }

  int it = 0;
  for (int kt = 0; kt < K; kt += 32, ++it){
    unsigned short* As = smem + (it & 1)*(2*128*40);
    unsigned short* Bs = As + 128*40;
    #pragma unroll
    for (int half = 0; half < 2; half++){
      int r = half*64 + srh;
      *(s8v*)&As[r*40 + sk8] = pa[half];
      *(s8v*)&Bs[r*40 + sk8] = pb[half];
    }
    __syncthreads();                       // single barrier per K-step (double buffer)
    if (kt + 32 < K){
      int kn = kt + 32;
      #pragma unroll
      for (int half = 0; half < 2; half++){
        int r = half*64 + srh;
        int ar = rowBlk + r;
        pa[half] = (ar < M) ? *(const s8v*)(A + (long)ar*lda + kn + sk8) : (s8v){0,0,0,0,0,0,0,0};
        pb[half] = *(const s8v*)(Bt + (long)(colBlk + r)*K + kn + sk8);
      }
    }
    s8v a[4], b[4];
    #pragma unroll
    for (int r = 0; r < 4; r++) a[r] = *(s8v*)&As[(wrow + r*16 + fr)*40 + fk];
    #pragma unroll
    for (int c = 0; c < 4; c++) b[c] = *(s8v*)&Bs[(wcol + c*16 + fr)*40 + fk];
    #pragma unroll
    for (int r = 0; r < 4; r++)
      #pragma unroll
      for (int c = 0; c < 4; c++)
        acc[r][c] = __builtin_amdgcn_mfma_f32_16x16x32_bf16(a[r], b[c], acc[r][c], 0, 0, 0);
  }

  if (OUTBF){
    __syncthreads();                       // all fragment reads done; reuse smem as C tile
    unsigned short* Cs = smem;             // [128][132]
    #pragma unroll
    for (int c = 0; c < 4; c++){
      int col = wcol + c*16 + fr;
      float bz = bias[colBlk + col];
      #pragma unroll
      for (int r = 0; r < 4; r++){
        #pragma unroll
        for (int j = 0; j < 4; j++){
          int rrow = wrow + r*16 + fq*4 + j;
          float val = acc[r][c][j] + bz;
          if (ACT == 1) val = 0.5f * val * (1.0f + erff(val * 0.70710678118654752f));
          Cs[rrow*132 + col] = f2us(val);
        }
      }
    }
    __syncthreads();
    for (int ci = tid; ci < 128*16; ci += 256){
      int rrow = ci >> 4, ch = ci & 15;
      int grow = rowBlk + rrow;
      if (grow < M)
        *(s8v*)(Cb + (long)grow*Nn + colBlk + ch*8) = *(s8v*)&Cs[rrow*132 + ch*8];
    }
  } else {
    #pragma unroll
    for (int c = 0; c < 4; c++){
      int col = colBlk + wcol + c*16 + fr;
      float bz = bias[col];
      #pragma unroll
      for (int r = 0; r < 4; r++){
        #pragma unroll
        for (int j = 0; j < 4; j++){
          int row = rowBlk + wrow + r*16 + fq*4 + j;
          if (row < M){
            float val = acc[r][c][j] + bz;
            if (ACT == 1) val = 0.5f * val * (1.0f + erff(val * 0.70710678118654752f));
            if (RES) val += res[(long)row*Nn + col];
            Cf[(long)row*Nn + col] = val;
          }
        }
      }
    }
  }
}

// ---------------- fp32 GEMM (head only: 8 rows) ----------------
__global__ __launch_bounds__(256) void gemm_k(
    const float* __restrict__ A, long lda,
    const float* __restrict__ Bw, long ldb,
    const float* __restrict__ bias,
    float* __restrict__ Cf,
    int M, int Nn, int K)
{
  __shared__ float As[16][64];
  __shared__ float Bs[16][64];
  int tid = threadIdx.x;
  int tx = tid & 15, ty = tid >> 4;
  int rowBlk = blockIdx.x * 64, colBlk = blockIdx.y * 64;
  int am = tid >> 2, ak = (tid & 3) * 4;
  int bk = tid >> 4, bc = (tid & 15) * 4;
  float acc[4][4];
  #pragma unroll
  for (int i = 0; i < 4; i++)
    #pragma unroll
    for (int j = 0; j < 4; j++) acc[i][j] = 0.f;

  for (int kt = 0; kt < K; kt += 16){
    float4 av = make_float4(0.f, 0.f, 0.f, 0.f);
    int ar = rowBlk + am;
    if (ar < M) av = *(const float4*)(A + (long)ar*lda + kt + ak);
    As[ak+0][am] = av.x; As[ak+1][am] = av.y; As[ak+2][am] = av.z; As[ak+3][am] = av.w;
    float4 bv4 = *(const float4*)(Bw + (long)(kt + bk)*ldb + colBlk + bc);
    Bs[bk][bc+0] = bv4.x; Bs[bk][bc+1] = bv4.y;
    Bs[bk][bc+2] = bv4.z; Bs[bk][bc+3] = bv4.w;
    __syncthreads();
    #pragma unroll
    for (int kk = 0; kk < 16; kk++){
      float4 a4 = *(const float4*)&As[kk][ty*4];
      float4 b4 = *(const float4*)&Bs[kk][tx*4];
      acc[0][0] += a4.x*b4.x; acc[0][1] += a4.x*b4.y; acc[0][2] += a4.x*b4.z; acc[0][3] += a4.x*b4.w;
      acc[1][0] += a4.y*b4.x; acc[1][1] += a4.y*b4.y; acc[1][2] += a4.y*b4.z; acc[1][3] += a4.y*b4.w;
      acc[2][0] += a4.z*b4.x; acc[2][1] += a4.z*b4.y; acc[2][2] += a4.z*b4.z; acc[2][3] += a4.z*b4.w;
      acc[3][0] += a4.w*b4.x; acc[3][1] += a4.w*b4.y; acc[3][2] += a4.w*b4.z; acc[3][3] += a4.w*b4.w;
    }
    __syncthreads();
  }
  int r0 = rowBlk + ty*4, c0 = colBlk + tx*4;
  float bz[4];
  #pragma unroll
  for (int j = 0; j < 4; j++) bz[j] = bias[c0 + j];
  #pragma unroll
  for (int i = 0; i < 4; i++){
    int r = r0 + i;
    if (r < M){
      #pragma unroll
      for (int j = 0; j < 4; j++)
        Cf[(long)r*Nn + c0 + j] = acc[i][j] + bz[j];
    }
  }
}

// ---------------- kmax via MFMA (reads k slice of fused qkv) ----------------
__global__ __launch_bounds__(256) void kmax2_k(const float* __restrict__ qkv,
    const unsigned short* __restrict__ projb, unsigned* __restrict__ kmaxb)
{
  __shared__ __attribute__((aligned(16))) unsigned short ks[64*40];
  __shared__ float red[4];
  int t = blockIdx.x, h = blockIdx.y, b = blockIdx.z;
  int tid = threadIdx.x, w = tid >> 6, lane = tid & 63;
  int fr = lane & 15, fq = lane >> 4, fk = fq*8;
  int n0 = t*64;
  #pragma unroll
  for (int it = 0; it < 2; it++){
    int tok = it*32 + (tid >> 3), d4 = tid & 7;
    int n = n0 + tok;
    bool vld = (n < N_);
    long gb = ((long)(b*N_ + (vld ? n : 0)))*QS + 256 + h*DH + d4*4;
    float4 kv = vld ? *(const float4*)(qkv + gb) : make_float4(0,0,0,0);
    ushort4 ku; ku.x=f2us(kv.x); ku.y=f2us(kv.y); ku.z=f2us(kv.z); ku.w=f2us(kv.w);
    *(ushort4*)&ks[tok*40 + d4*4] = ku;
  }
  __syncthreads();
  s8v bk_ = *(s8v*)&ks[(w*16 + fr)*40 + fk];
  float mx = -INFINITY;
  int n_ = w*16 + fr;
  bool nv = (n0 + n_ < N_);
  #pragma unroll
  for (int mt = 0; mt < 7; mt++){
    s8v ap = *(const s8v*)(projb + (mt*16 + fr)*32 + fk);
    f4v z = (f4v){0.f,0.f,0.f,0.f};
    f4v xd = __builtin_amdgcn_mfma_f32_16x16x32_bf16(ap, bk_, z, 0, 0, 0);
    #pragma unroll
    for (int j = 0; j < 4; j++){
      int m = mt*16 + fq*4 + j;
      float v = (nv && m < M_) ? xd[j]*DN : -INFINITY;
      mx = fmaxf(mx, v);
    }
  }
  #pragma unroll
  for (int mk = 1; mk < 64; mk <<= 1) mx = fmaxf(mx, __shfl_xor(mx, mk));
  if (lane == 0) red[w] = mx;
  __syncthreads();
  if (tid == 0){
    float g = fmaxf(fmaxf(red[0], red[1]), fmaxf(red[2], red[3]));
    atomicMax(kmaxb, floatToOrdered(g));
  }
}

// ---------------- fused ctx via double MFMA (k/v from fused qkv) ----------------
__global__ __launch_bounds__(256) void fctx_k(const float* __restrict__ qkv,
    const unsigned short* __restrict__ projb,
    const unsigned* __restrict__ kmaxb, float* __restrict__ partials)
{
  __shared__ __attribute__((aligned(16))) unsigned short ks[64*40];
  __shared__ __attribute__((aligned(16))) unsigned short vt[48*72];
  __shared__ __attribute__((aligned(16))) unsigned short kps[112*72];
  __shared__ float diags[64];
  int c = blockIdx.x, h = blockIdx.y, b = blockIdx.z;
  int tid = threadIdx.x, w = tid >> 6, lane = tid & 63;
  int fr = lane & 15, fq = lane >> 4, fk = fq*8;
  float kmax = orderedToFloat(kmaxb[0]);

  for (int i = tid; i < 15*72; i += 256) vt[33*72 + i] = 0;
  if (tid < 64) vt[32*72 + tid] = f2us(1.0f);

  s8v ap[7];
  #pragma unroll
  for (int mt = 0; mt < 7; mt++)
    ap[mt] = *(const s8v*)(projb + (mt*16 + fr)*32 + fk);

  int mt0 = w, mt1 = w + 4;
  f4v acc0[3], acc1[3];
  #pragma unroll
  for (int dt = 0; dt < 3; dt++){ acc0[dt] = (f4v){0.f,0.f,0.f,0.f}; acc1[dt] = (f4v){0.f,0.f,0.f,0.f}; }

  for (int t = c; t < NTILES; t += NC){
    int n0 = t*64;
    __syncthreads();
    #pragma unroll
    for (int it = 0; it < 2; it++){
      int tok = it*32 + (tid >> 3), d4 = tid & 7;
      int n = n0 + tok;
      bool vld = (n < N_);
      long gb = ((long)(b*N_ + (vld ? n : 0)))*QS + 256 + h*DH + d4*4;
      float4 kv = vld ? *(const float4*)(qkv + gb) : make_float4(0,0,0,0);
      float4 vv = vld ? *(const float4*)(qkv + gb + 256) : make_float4(0,0,0,0);
      ushort4 ku; ku.x=f2us(kv.x); ku.y=f2us(kv.y); ku.z=f2us(kv.z); ku.w=f2us(kv.w);
      *(ushort4*)&ks[tok*40 + d4*4] = ku;
      vt[(d4*4+0)*72 + tok] = f2us(vv.x);
      vt[(d4*4+1)*72 + tok] = f2us(vv.y);
      vt[(d4*4+2)*72 + tok] = f2us(vv.z);
      vt[(d4*4+3)*72 + tok] = f2us(vv.w);
      float sq = kv.x*kv.x + kv.y*kv.y + kv.z*kv.z + kv.w*kv.w;
      sq += __shfl_xor(sq, 1); sq += __shfl_xor(sq, 2); sq += __shfl_xor(sq, 4);
      if (d4 == 0) diags[tok] = 0.5f * DN2 * sq;
    }
    __syncthreads();
    s8v bk_ = *(s8v*)&ks[(w*16 + fr)*40 + fk];
    int n_ = w*16 + fr;
    bool nv = (n0 + n_ < N_);
    float dgn = diags[n_];
    #pragma unroll
    for (int mt = 0; mt < 7; mt++){
      f4v z = (f4v){0.f,0.f,0.f,0.f};
      f4v xd = __builtin_amdgcn_mfma_f32_16x16x32_bf16(ap[mt], bk_, z, 0, 0, 0);
      #pragma unroll
      for (int j = 0; j < 4; j++){
        float kp = nv ? RATIO*(expf(xd[j]*DN - dgn - kmax) + 1e-3f) : 0.f;
        kps[(mt*16 + fq*4 + j)*72 + n_] = f2us(kp);
      }
    }
    __syncthreads();
    #pragma unroll
    for (int kst = 0; kst < 2; kst++){
      int ko = kst*32 + fk;
      s8v b0 = *(s8v*)&vt[( 0 + fr)*72 + ko];
      s8v b1 = *(s8v*)&vt[(16 + fr)*72 + ko];
      s8v b2 = *(s8v*)&vt[(32 + fr)*72 + ko];
      s8v a0 = *(s8v*)&kps[(mt0*16 + fr)*72 + ko];
      acc0[0] = __builtin_amdgcn_mfma_f32_16x16x32_bf16(a0, b0, acc0[0], 0, 0, 0);
      acc0[1] = __builtin_amdgcn_mfma_f32_16x16x32_bf16(a0, b1, acc0[1], 0, 0, 0);
      acc0[2] = __builtin_amdgcn_mfma_f32_16x16x32_bf16(a0, b2, acc0[2], 0, 0, 0);
      if (mt1 < 7){
        s8v a1 = *(s8v*)&kps[(mt1*16 + fr)*72 + ko];
        acc1[0] = __builtin_amdgcn_mfma_f32_16x16x32_bf16(a1, b0, acc1[0], 0, 0, 0);
        acc1[1] = __builtin_amdgcn_mfma_f32_16x16x32_bf16(a1, b1, acc1[1], 0, 0, 0);
        acc1[2] = __builtin_amdgcn_mfma_f32_16x16x32_bf16(a1, b2, acc1[2], 0, 0, 0);
      }
    }
  }
  long pb = ((long)c*64 + (b*H_ + h))*CTXE;
  #pragma unroll
  for (int dt = 0; dt < 3; dt++){
    int d = dt*16 + fr;
    if (d < 33){
      #pragma unroll
      for (int j = 0; j < 4; j++){
        int m0 = mt0*16 + fq*4 + j;
        if (m0 < M_) partials[pb + m0*33 + d] = acc0[dt][j];
        if (mt1 < 7){
          int m1 = mt1*16 + fq*4 + j;
          if (m1 < M_) partials[pb + m1*33 + d] = acc1[dt][j];
        }
      }
    }
  }
}

// ---------------- ctx partial reduce ----------------
__global__ __launch_bounds__(256) void ctxred2_k(const float* __restrict__ partials,
                                                 float* __restrict__ ctxf)
{
  int i = blockIdx.x*256 + threadIdx.x;
  if (i >= CTXN2) return;
  float s = 0.f;
  #pragma unroll
  for (int c = 0; c < NC; c++) s += partials[(long)c*CTXN2 + i];
  ctxf[i] = s;
}

// ---------------- attn v3: full-MFMA query side (q from fused qkv) ----------------
__global__ __launch_bounds__(256) void attn3_k(const float* __restrict__ qkv,
    const float* __restrict__ ctxf, const unsigned short* __restrict__ projb,
    unsigned short* __restrict__ ob)
{
  __shared__ __attribute__((aligned(16))) unsigned short qs[64*40];
  __shared__ __attribute__((aligned(16))) unsigned short qps[64*136];
  __shared__ __attribute__((aligned(16))) unsigned short cst[48*136];
  __shared__ float diags[64];
  __shared__ float dens[64];
  int t = blockIdx.x, h = blockIdx.y, b = blockIdx.z;
  int tid = threadIdx.x, w = tid >> 6, lane = tid & 63;
  int fr = lane & 15, fq = lane >> 4, fk = fq*8;
  int n0 = t*64;
  long cbase = ((long)(b*H_ + h))*CTXE;

  for (int i = tid; i < 64*16; i += 256)
    qps[(i >> 4)*136 + 112 + (i & 15)] = 0;

  #pragma unroll
  for (int it = 0; it < 2; it++){
    int tok = it*32 + (tid >> 3), d4 = tid & 7;
    int n = n0 + tok;
    bool vld = (n < N_);
    long gb = ((long)(b*N_ + (vld ? n : 0)))*QS + h*DH + d4*4;
    float4 qv = vld ? *(const float4*)(qkv + gb) : make_float4(0,0,0,0);
    ushort4 qu; qu.x=f2us(qv.x); qu.y=f2us(qv.y); qu.z=f2us(qv.z); qu.w=f2us(qv.w);
    *(ushort4*)&qs[tok*40 + d4*4] = qu;
    float sq = qv.x*qv.x + qv.y*qv.y + qv.z*qv.z + qv.w*qv.w;
    sq += __shfl_xor(sq, 1); sq += __shfl_xor(sq, 2); sq += __shfl_xor(sq, 4);
    if (d4 == 0) diags[tok] = 0.5f * DN2 * sq;
  }
  for (int i = tid; i < 48*128; i += 256){
    int d = i >> 7, m = i & 127;
    float v = (d < 33 && m < M_) ? ctxf[cbase + (long)m*33 + d] : 0.f;
    cst[d*136 + m] = f2us(v);
  }
  __syncthreads();

  s8v bq_ = *(s8v*)&qs[(w*16 + fr)*40 + fk];
  int n_ = w*16 + fr;
  bool nv = (n0 + n_ < N_);
  float dgn = diags[n_];
  f4v xdv[7];
  #pragma unroll
  for (int mt = 0; mt < 7; mt++){
    s8v ap = *(const s8v*)(projb + (mt*16 + fr)*32 + fk);
    f4v z = (f4v){0.f,0.f,0.f,0.f};
    xdv[mt] = __builtin_amdgcn_mfma_f32_16x16x32_bf16(ap, bq_, z, 0, 0, 0);
  }
  float mx = -INFINITY;
  #pragma unroll
  for (int mt = 0; mt < 7; mt++)
    #pragma unroll
    for (int j = 0; j < 4; j++){
      int m = mt*16 + fq*4 + j;
      if (m < M_) mx = fmaxf(mx, xdv[mt][j]*DN);
    }
  mx = fmaxf(mx, __shfl_xor(mx, 16));
  mx = fmaxf(mx, __shfl_xor(mx, 32));
  #pragma unroll
  for (int mt = 0; mt < 7; mt++)
    #pragma unroll
    for (int j = 0; j < 4; j++){
      int m = mt*16 + fq*4 + j;
      float qp = (nv && m < M_) ? RATIO*(expf(xdv[mt][j]*DN - dgn - mx) + 1e-3f) : 0.f;
      qps[n_*136 + m] = f2us(qp);
    }
  __syncthreads();

  f4v acc[3];
  acc[0] = (f4v){0,0,0,0}; acc[1] = (f4v){0,0,0,0}; acc[2] = (f4v){0,0,0,0};
  #pragma unroll
  for (int ks = 0; ks < 4; ks++){
    int ko = ks*32 + fk;
    s8v bqp = *(s8v*)&qps[(w*16 + fr)*136 + ko];
    #pragma unroll
    for (int dt = 0; dt < 3; dt++){
      s8v ac = *(s8v*)&cst[(dt*16 + fr)*136 + ko];
      acc[dt] = __builtin_amdgcn_mfma_f32_16x16x32_bf16(ac, bqp, acc[dt], 0, 0, 0);
    }
  }
  if (fq == 0) dens[n_] = acc[2][0];
  __syncthreads();
  float dinv = 1.0f / dens[n_];
  if (nv){
    long obase = ((long)(b*N_ + n0 + n_))*D_ + h*DH;
    #pragma unroll
    for (int dt = 0; dt < 2; dt++){
      ushort4 wv;
      wv.x = f2us(acc[dt][0]*dinv);
      wv.y = f2us(acc[dt][1]*dinv);
      wv.z = f2us(acc[dt][2]*dinv);
      wv.w = f2us(acc[dt][3]*dinv);
      *(ushort4*)(ob + obase + dt*16 + fq*4) = wv;
    }
  }
}

// ---------------- host ----------------
extern "C" void kernel_launch(void* const* d_in, const int* in_sizes, int n_in,
                              void* d_out, int out_size, void* d_ws, size_t ws_size,
                              hipStream_t stream)
{
  const float* expr = (const float*)d_in[0];
  const float* temb = (const float*)d_in[1];
  const float* cls  = (const float*)d_in[2];
  const float* ln1g = (const float*)d_in[3];
  const float* ln1b = (const float*)d_in[4];
  const float* Wq   = (const float*)d_in[5];
  const float* bq   = (const float*)d_in[6];
  const float* Wk   = (const float*)d_in[7];
  const float* bk   = (const float*)d_in[8];
  const float* Wv   = (const float*)d_in[9];
  const float* bv   = (const float*)d_in[10];
  const float* Wo   = (const float*)d_in[11];
  const float* bo   = (const float*)d_in[12];
  const float* ln2g = (const float*)d_in[13];
  const float* ln2b = (const float*)d_in[14];
  const float* W1   = (const float*)d_in[15];
  const float* b1   = (const float*)d_in[16];
  const float* W2   = (const float*)d_in[17];
  const float* b2   = (const float*)d_in[18];
  const float* proj = (const float*)d_in[19];
  const float* Wp   = (const float*)d_in[20];
  const float* bp   = (const float*)d_in[21];
  (void)in_sizes; (void)n_in; (void)out_size; (void)ws_size;

  char* w = (char*)d_ws;
  size_t off = 0;
  auto alloc = [&](size_t bytes) -> char* {
    char* p = w + off;
    off = (off + bytes + 255) & ~(size_t)255;
    return p;
  };
  float*    selected = (float*)alloc((size_t)B_*KSEL*4);
  float*    bsum     = (float*)alloc(B_*4);
  float*    bv0      = (float*)alloc(B_*4);
  float*    emaxp    = (float*)alloc(4);
  unsigned* kmaxb    = (unsigned*)alloc(DEPTH_*4);
  float*    ctxf     = (float*)alloc((size_t)CTXN2*4);
  float*          x  = (float*)alloc((size_t)BN_*D_*4);
  unsigned short* h  = (unsigned short*)alloc((size_t)BN_*D_*2);
  float*        qkv  = (float*)alloc((size_t)BN_*QS*4);
  unsigned short* Wqkvt = (unsigned short*)alloc((size_t)DEPTH_*QS*D_*2);
  unsigned short* Wot = (unsigned short*)alloc((size_t)DEPTH_*D_*D_*2);
  unsigned short* W1t = (unsigned short*)alloc((size_t)DEPTH_*D_*DFF_*2);
  unsigned short* W2t = (unsigned short*)alloc((size_t)DEPTH_*DFF_*D_*2);
  unsigned short* projb = (unsigned short*)alloc((size_t)DEPTH_*112*32*2);
  float*    bqkv     = (float*)alloc((size_t)DEPTH_*QS*4);
  unsigned short* ffi = (unsigned short*)qkv;  // bf16 [BN][1024] aliases qkv (dead during FFN)
  float*     partials = (float*)h;             // NC*CTXN2*4 = 7.44 MB <= h (8.39 MB)

  // one-time weight/proj conversions (Wq/Wk/Wv into one concatenated [768][256] bf16)
  wcvt_k<<<dim3(8, 8, DEPTH_),  256, 0, stream>>>(Wq, (long)D_*D_, Wqkvt + 0,      (long)QS*D_, D_, D_);
  wcvt_k<<<dim3(8, 8, DEPTH_),  256, 0, stream>>>(Wk, (long)D_*D_, Wqkvt + 256*D_, (long)QS*D_, D_, D_);
  wcvt_k<<<dim3(8, 8, DEPTH_),  256, 0, stream>>>(Wv, (long)D_*D_, Wqkvt + 512*D_, (long)QS*D_, D_, D_);
  wcvt_k<<<dim3(8, 8, DEPTH_),  256, 0, stream>>>(Wo, (long)D_*D_,   Wot, (long)D_*D_,   D_, D_);
  wcvt_k<<<dim3(32, 8, DEPTH_), 256, 0, stream>>>(W1, (long)D_*DFF_, W1t, (long)D_*DFF_, D_, DFF_);
  wcvt_k<<<dim3(8, 32, DEPTH_), 256, 0, stream>>>(W2, (long)DFF_*D_, W2t, (long)DFF_*D_, DFF_, D_);
  pcvt_k<<<DEPTH_, 256, 0, stream>>>(proj, projb, kmaxb);
  bcat_k<<<DEPTH_, 256, 0, stream>>>(bq, bk, bv, bqkv);

  topk_k<<<B_, 1024, 0, stream>>>(expr, selected);
  nsum_k<<<B_, 256, 0, stream>>>(selected, bsum, bv0);
  emax_k<<<1, 64, 0, stream>>>(bsum, bv0, emaxp);
  embed_k<<<BN_, 64, 0, stream>>>(selected, bsum, emaxp, temb, cls, x);

  for (int L = 0; L < DEPTH_; L++){
    const unsigned short* pjb = projb + (size_t)L*112*32;
    ln_k<<<BN_/4, 256, 0, stream>>>(x, h, ln1g + L*D_, ln1b + L*D_);
    bgemm_k<0,0,0><<<dim3(6,129), 256, 0, stream>>>(h, D_, Wqkvt + (size_t)L*QS*D_, bqkv + (size_t)L*QS, nullptr, qkv, nullptr, BN_, QS, D_);
    kmax2_k<<<dim3(NTILES, H_, B_), 256, 0, stream>>>(qkv, pjb, kmaxb + L);
    fctx_k<<<dim3(NC, H_, B_), 256, 0, stream>>>(qkv, pjb, kmaxb + L, partials);
    ctxred2_k<<<(CTXN2 + 255)/256, 256, 0, stream>>>(partials, ctxf);
    attn3_k<<<dim3(NTILES, H_, B_), 256, 0, stream>>>(qkv, ctxf, pjb, h);   // o -> h (bf16)
    bgemm_k<0,1,0><<<dim3(2,129), 256, 0, stream>>>(h, D_, Wot + (size_t)L*D_*D_, bo + L*D_, x, x, nullptr, BN_, D_, D_);
    ln_k<<<BN_/4, 256, 0, stream>>>(x, h, ln2g + L*D_, ln2b + L*D_);
    bgemm_k<1,0,1><<<dim3(8,129), 256, 0, stream>>>(h, D_, W1t + (size_t)L*D_*DFF_, b1 + L*DFF_, nullptr, nullptr, ffi, BN_, DFF_, D_);
    bgemm_k<0,1,0><<<dim3(2,129), 256, 0, stream>>>(ffi, DFF_, W2t + (size_t)L*DFF_*D_, b2 + L*D_, x, x, nullptr, BN_, D_, DFF_);
  }
  gemm_k<<<dim3(1,4), 256, 0, stream>>>(x, (long)N_*D_, Wp, D_, bp,
                                        (float*)d_out, B_, D_, D_);
}

// Round 15
// 1332.732 us; speedup vs baseline: 5.9035x; 1.0402x over previous
//
#include <hip/hip_runtime.h>
#include <hip/hip_bf16.h>

#define B_    8
#define NG    16906
#define KSEL  2048
#define D_    256
#define H_    8
#define DH    32
#define M_    110
#define DEPTH_ 6
#define DFF_  1024
#define N_    2049
#define BN_   (B_*N_)
#define QS    768          // fused qkv row stride (shorts)
#define NC    8            // fctx chunks (blocks per (b,h))
#define NTILES 33          // ceil(2049/64)
#define CTXE  (M_*33)      // 3630 per (b,h)
#define CTXN2 (64*CTXE)    // 232320
#define NIT_TK 17          // ceil(16906/1024)

static constexpr float DN    = 0.42044820762685725f;  // 32^-0.25
static constexpr float DN2   = 0.17677669529663687f;  // 32^-0.5
static constexpr float RATIO = 0.09534625892455922f;  // 110^-0.5

typedef __attribute__((ext_vector_type(8))) short s8v;
typedef __attribute__((ext_vector_type(4))) float f4v;

__device__ __forceinline__ unsigned floatToOrdered(float f){
  unsigned b = __float_as_uint(f);
  return (b & 0x80000000u) ? ~b : (b | 0x80000000u);
}
__device__ __forceinline__ float orderedToFloat(unsigned u){
  unsigned b = (u & 0x80000000u) ? (u & 0x7FFFFFFFu) : ~u;
  return __uint_as_float(b);
}
__device__ __forceinline__ unsigned short f2us(float f){
  __hip_bfloat16 b = __float2bfloat16(f);
  return *reinterpret_cast<unsigned short*>(&b);
}
__device__ __forceinline__ float us2f(unsigned short u){
  return __uint_as_float(((unsigned)u) << 16);
}

// ---------------- top-k: radix select, parallel suffix-scan threshold search ----------------
__global__ __launch_bounds__(1024) void topk_k(const float* __restrict__ expr,
                                               float* __restrict__ selected)
{
  __shared__ unsigned histw[16*256];
  __shared__ unsigned sPrefix;
  __shared__ int sKK;
  __shared__ unsigned cGT, cEQ;
  int b = blockIdx.x, tid = threadIdx.x;
  int wv = tid >> 6, lane = tid & 63;
  const float* row = expr + (long)b*NG;
  unsigned rb[NIT_TK];
  #pragma unroll
  for (int i = 0; i < NIT_TK; i++){
    int idx = tid + i*1024;
    rb[i] = (idx < NG) ? __float_as_uint(row[idx]) : 0u;
  }
  if (tid == 0){ sPrefix = 0u; sKK = KSEL; }
  for (int pass = 0; pass < 4; ++pass){
    int shift = 24 - pass*8;
    for (int i = tid; i < 16*256; i += 1024) histw[i] = 0u;
    __syncthreads();
    unsigned pref = sPrefix;
    unsigned kk  = (unsigned)sKK;
    #pragma unroll
    for (int i = 0; i < NIT_TK; i++){
      int idx = tid + i*1024;
      unsigned bits = rb[i];
      bool ok = (idx < NG) && ((pass == 0) || ((bits >> (shift + 8)) == pref));
      if (ok) atomicAdd(&histw[wv*256 + ((bits >> shift) & 255u)], 1u);
    }
    __syncthreads();
    if (tid < 256){
      unsigned s = 0;
      #pragma unroll
      for (int w = 0; w < 16; w++) s += histw[w*256 + tid];
      histw[tid] = s;
    }
    __syncthreads();
    unsigned* bufA = histw;
    unsigned* bufB = histw + 256;
    for (int d = 1; d < 256; d <<= 1){
      if (tid < 256)
        bufB[tid] = bufA[tid] + ((tid + d < 256) ? bufA[tid + d] : 0u);
      __syncthreads();
      unsigned* t = bufA; bufA = bufB; bufB = t;
    }
    if (tid < 256){
      unsigned sj  = bufA[tid];
      unsigned sj1 = (tid < 255) ? bufA[tid + 1] : 0u;
      if (sj >= kk && sj1 < kk){
        sPrefix = (pref << 8) | (unsigned)tid;
        sKK = (int)(kk - sj1);
      }
    }
    __syncthreads();
  }
  unsigned T = sPrefix; int needEQ = sKK; int base = KSEL - needEQ;
  if (tid == 0){ cGT = 0u; cEQ = 0u; }
  __syncthreads();
  #pragma unroll
  for (int i = 0; i < NIT_TK; i++){
    int idx = tid + i*1024;
    bool v = (idx < NG);
    unsigned bits = rb[i];
    bool gt = v && (bits > T);
    unsigned long long mgt = __ballot(gt);
    if (mgt){
      int leader = __ffsll((long long)mgt) - 1;
      unsigned wbase = 0;
      if (lane == leader) wbase = atomicAdd(&cGT, (unsigned)__popcll(mgt));
      wbase = __shfl(wbase, leader);
      if (gt){
        int pre = __popcll(mgt & ((1ULL << lane) - 1ULL));
        selected[(long)b*KSEL + wbase + pre] = __uint_as_float(bits);
      }
    }
    bool eq = v && (bits == T);
    unsigned long long meq = __ballot(eq);
    if (meq){
      int leader = __ffsll((long long)meq) - 1;
      unsigned wbase = 0;
      if (lane == leader) wbase = atomicAdd(&cEQ, (unsigned)__popcll(meq));
      wbase = __shfl(wbase, leader);
      if (eq){
        int pos = (int)wbase + __popcll(meq & ((1ULL << lane) - 1ULL));
        if (pos < needEQ) selected[(long)b*KSEL + base + pos] = __uint_as_float(bits);
      }
    }
  }
}

// ---------------- per-batch sum + max of selected ----------------
__global__ __launch_bounds__(256) void nsum_k(const float* __restrict__ selected,
                                              float* __restrict__ bsum, float* __restrict__ bv0)
{
  __shared__ float rs[256], rm[256];
  int b = blockIdx.x, tid = threadIdx.x;
  float s = 0.f, m = -INFINITY;
  for (int i = tid; i < KSEL; i += 256){ float v = selected[(long)b*KSEL + i]; s += v; m = fmaxf(m, v); }
  rs[tid] = s; rm[tid] = m; __syncthreads();
  for (int k = 128; k > 0; k >>= 1){
    if (tid < k){ rs[tid] += rs[tid + k]; rm[tid] = fmaxf(rm[tid], rm[tid + k]); }
    __syncthreads();
  }
  if (tid == 0){ bsum[b] = rs[0]; bv0[b] = rm[0]; }
}

// ---------------- global max of e = log1p(v0/sum*1e4) ----------------
__global__ __launch_bounds__(64) void emax_k(const float* __restrict__ bsum,
                                             const float* __restrict__ bv0,
                                             float* __restrict__ emaxp)
{
  int tid = threadIdx.x;
  float e = -INFINITY;
  if (tid < B_) e = log1pf(bv0[tid] / fmaxf(bsum[tid], 1e-12f) * 10000.0f);
  #pragma unroll
  for (int m = 1; m < 64; m <<= 1) e = fmaxf(e, __shfl_xor(e, m));
  if (tid == 0) emaxp[0] = e;
}

// ---------------- tokenize + embed: 4 rows per block ----------------
__global__ __launch_bounds__(256) void embed_k(const float* __restrict__ selected,
    const float* __restrict__ bsum, const float* __restrict__ emaxp,
    const float* __restrict__ temb, const float* __restrict__ cls,
    float* __restrict__ x)
{
  int rowi = blockIdx.x*4 + (threadIdx.x >> 6);
  int b = rowi / N_, n = rowi % N_;
  int lane = threadIdx.x & 63;
  const float* src;
  if (n == 0){
    src = cls;
  } else {
    float val = selected[(long)b*KSEL + (n - 1)];
    float e = log1pf(val / fmaxf(bsum[b], 1e-12f) * 10000.0f);
    float step = emaxp[0] / 7.0f;              // matches jnp.linspace step
    int cnt = 0;
    #pragma unroll
    for (int i = 0; i < 7; i++) cnt += (((float)i * step) < e) ? 1 : 0;  // searchsorted 'left'
    int tok = cnt > 6 ? 6 : cnt;
    src = temb + (long)tok * D_;
  }
  float4 o = *(const float4*)(src + lane*4);
  *(float4*)(x + (long)rowi*D_ + lane*4) = o;
}

// ---------------- LayerNorm: one wave per row, bf16 output ----------------
__global__ __launch_bounds__(256) void ln_k(const float* __restrict__ x,
    unsigned short* __restrict__ out,
    const float* __restrict__ g, const float* __restrict__ bb)
{
  int row = blockIdx.x*4 + (threadIdx.x >> 6);
  int lane = threadIdx.x & 63;
  float4 v = *(const float4*)(x + (long)row*D_ + lane*4);
  float s = v.x + v.y + v.z + v.w;
  float q = v.x*v.x + v.y*v.y + v.z*v.z + v.w*v.w;
  #pragma unroll
  for (int m = 1; m < 64; m <<= 1){ s += __shfl_xor(s, m); q += __shfl_xor(q, m); }
  float mu  = s * (1.0f/D_);
  float var = q * (1.0f/D_) - mu*mu;
  float inv = 1.0f / sqrtf(fmaxf(var, 0.f) + 1e-5f);
  float4 gu = *(const float4*)(g + lane*4);
  float4 bu = *(const float4*)(bb + lane*4);
  ushort4 o;
  o.x = f2us((v.x - mu)*inv*gu.x + bu.x);
  o.y = f2us((v.y - mu)*inv*gu.y + bu.y);
  o.z = f2us((v.z - mu)*inv*gu.z + bu.z);
  o.w = f2us((v.w - mu)*inv*gu.w + bu.w);
  *(ushort4*)(out + (long)row*D_ + lane*4) = o;
}

// ---------------- weight convert + transpose: dst[n][k] = bf16(src[k][n]) ----------------
__global__ __launch_bounds__(256) void wcvt_k(const float* __restrict__ src, long srcL,
    unsigned short* __restrict__ dst, long dstL, int K, int N)
{
  __shared__ float t[32][33];
  int n0 = blockIdx.x*32, k0 = blockIdx.y*32, L = blockIdx.z;
  int tx = threadIdx.x & 31, ty = threadIdx.x >> 5;
  const float* s = src + (long)L*srcL;
  for (int i = ty; i < 32; i += 8)
    t[i][tx] = s[(long)(k0+i)*N + n0 + tx];
  __syncthreads();
  unsigned short* d = dst + (long)L*dstL;
  for (int i = ty; i < 32; i += 8)
    d[(long)(n0 + i)*K + k0 + tx] = f2us(t[tx][i]);
}

// ---------------- proj convert + zero kmax slots ----------------
__global__ __launch_bounds__(256) void pcvt_k(const float* __restrict__ proj,
                                              unsigned short* __restrict__ projb,
                                              unsigned* __restrict__ kmaxb)
{
  int L = blockIdx.x;
  if (blockIdx.x == 0 && threadIdx.x < DEPTH_) kmaxb[threadIdx.x] = 0u;
  for (int i = threadIdx.x; i < 112*32; i += 256){
    int m = i >> 5, d = i & 31;
    float v = (m < M_) ? proj[(long)L*M_*DH + m*DH + d] : 0.f;
    projb[(long)L*112*32 + i] = f2us(v);
  }
}

// ---------------- bias concat: bqkv[L][768] = [bq|bk|bv] ----------------
__global__ __launch_bounds__(256) void bcat_k(const float* __restrict__ bq,
    const float* __restrict__ bk, const float* __restrict__ bv,
    float* __restrict__ bqkv)
{
  int L = blockIdx.x;
  for (int i = threadIdx.x; i < QS; i += 256){
    float v = (i < 256) ? bq[L*256 + i] : (i < 512) ? bk[L*256 + i - 256] : bv[L*256 + i - 512];
    bqkv[(long)L*QS + i] = v;
  }
}

// ---------------- bf16 MFMA GEMM: double-buffered LDS, one barrier per K-step ----------------
template<int ACT, int RES, int OUTBF>
__global__ __launch_bounds__(256) void bgemm_k(
    const unsigned short* __restrict__ A, long lda,
    const unsigned short* __restrict__ Bt,
    const float* __restrict__ bias,
    const float* __restrict__ res,
    float* __restrict__ Cf, unsigned short* __restrict__ Cb,
    int M, int Nn, int K)
{
  __shared__ __attribute__((aligned(16))) unsigned short smem[2*2*128*40];
  int tid = threadIdx.x;
  int colBlk = blockIdx.x*128, rowBlk = blockIdx.y*128;
  int w = tid >> 6, lane = tid & 63;
  int wrow = (w >> 1)*64, wcol = (w & 1)*64;
  int fr = lane & 15, fk = (lane >> 4)*8, fq = lane >> 4;
  int srh = tid >> 2, sk8 = (tid & 3)*8;

  f4v acc[4][4];
  #pragma unroll
  for (int r = 0; r < 4; r++)
    #pragma unroll
    for (int c = 0; c < 4; c++) acc[r][c] = (f4v){0.f, 0.f, 0.f, 0.f};

  s8v pa[2], pb[2];
  #pragma unroll
  for (int half = 0; half < 2; half++){
    int r = half*64 + srh;
    int ar = rowBlk + r;
    pa[half] = (ar < M) ? *(const s8v*)(A + (long)ar*lda + sk8) : (s8v){0,0,0,0,0,0,0,0};
    pb[half] = *(const s8v*)(Bt + (long)(colBlk + r)*K + sk8);
  }

  int it = 0;
  for (int kt = 0; kt < K; kt += 32, ++it){
    unsigned short* As = smem + (it & 1)*(2*128*40);
    unsigned short* Bs = As + 128*40;
    #pragma unroll
    for (int half = 0; half < 2; half++){
      int r = half*64 + srh;
      *(s8v*)&As[r*40 + sk8] = pa[half];
      *(s8v*)&Bs[r*40 + sk8] = pb[half];
    }
    __syncthreads();
    if (kt + 32 < K){
      int kn = kt + 32;
      #pragma unroll
      for (int half = 0; half < 2; half++){
        int r = half*64 + srh;
        int ar = rowBlk + r;
        pa[half] = (ar < M) ? *(const s8v*)(A + (long)ar*lda + kn + sk8) : (s8v){0,0,0,0,0,0,0,0};
        pb[half] = *(const s8v*)(Bt + (long)(colBlk + r)*K + kn + sk8);
      }
    }
    s8v a[4], b[4];
    #pragma unroll
    for (int r = 0; r < 4; r++) a[r] = *(s8v*)&As[(wrow + r*16 + fr)*40 + fk];
    #pragma unroll
    for (int c = 0; c < 4; c++) b[c] = *(s8v*)&Bs[(wcol + c*16 + fr)*40 + fk];
    #pragma unroll
    for (int r = 0; r < 4; r++)
      #pragma unroll
      for (int c = 0; c < 4; c++)
        acc[r][c] = __builtin_amdgcn_mfma_f32_16x16x32_bf16(a[r], b[c], acc[r][c], 0, 0, 0);
  }

  if (OUTBF){
    __syncthreads();
    unsigned short* Cs = smem;             // [128][132]
    #pragma unroll
    for (int c = 0; c < 4; c++){
      int col = wcol + c*16 + fr;
      float bz = bias[colBlk + col];
      #pragma unroll
      for (int r = 0; r < 4; r++){
        #pragma unroll
        for (int j = 0; j < 4; j++){
          int rrow = wrow + r*16 + fq*4 + j;
          float val = acc[r][c][j] + bz;
          if (ACT == 1) val = 0.5f * val * (1.0f + erff(val * 0.70710678118654752f));
          Cs[rrow*132 + col] = f2us(val);
        }
      }
    }
    __syncthreads();
    for (int ci = tid; ci < 128*16; ci += 256){
      int rrow = ci >> 4, ch = ci & 15;
      int grow = rowBlk + rrow;
      if (grow < M)
        *(s8v*)(Cb + (long)grow*Nn + colBlk + ch*8) = *(s8v*)&Cs[rrow*132 + ch*8];
    }
  } else {
    #pragma unroll
    for (int c = 0; c < 4; c++){
      int col = colBlk + wcol + c*16 + fr;
      float bz = bias[col];
      #pragma unroll
      for (int r = 0; r < 4; r++){
        #pragma unroll
        for (int j = 0; j < 4; j++){
          int row = rowBlk + wrow + r*16 + fq*4 + j;
          if (row < M){
            float val = acc[r][c][j] + bz;
            if (ACT == 1) val = 0.5f * val * (1.0f + erff(val * 0.70710678118654752f));
            if (RES) val += res[(long)row*Nn + col];
            Cf[(long)row*Nn + col] = val;
          }
        }
      }
    }
  }
}

// ---------------- fp32 GEMM (head only: 8 rows) ----------------
__global__ __launch_bounds__(256) void gemm_k(
    const float* __restrict__ A, long lda,
    const float* __restrict__ Bw, long ldb,
    const float* __restrict__ bias,
    float* __restrict__ Cf,
    int M, int Nn, int K)
{
  __shared__ float As[16][64];
  __shared__ float Bs[16][64];
  int tid = threadIdx.x;
  int tx = tid & 15, ty = tid >> 4;
  int rowBlk = blockIdx.x * 64, colBlk = blockIdx.y * 64;
  int am = tid >> 2, ak = (tid & 3) * 4;
  int bk = tid >> 4, bc = (tid & 15) * 4;
  float acc[4][4];
  #pragma unroll
  for (int i = 0; i < 4; i++)
    #pragma unroll
    for (int j = 0; j < 4; j++) acc[i][j] = 0.f;

  for (int kt = 0; kt < K; kt += 16){
    float4 av = make_float4(0.f, 0.f, 0.f, 0.f);
    int ar = rowBlk + am;
    if (ar < M) av = *(const float4*)(A + (long)ar*lda + kt + ak);
    As[ak+0][am] = av.x; As[ak+1][am] = av.y; As[ak+2][am] = av.z; As[ak+3][am] = av.w;
    float4 bv4 = *(const float4*)(Bw + (long)(kt + bk)*ldb + colBlk + bc);
    Bs[bk][bc+0] = bv4.x; Bs[bk][bc+1] = bv4.y;
    Bs[bk][bc+2] = bv4.z; Bs[bk][bc+3] = bv4.w;
    __syncthreads();
    #pragma unroll
    for (int kk = 0; kk < 16; kk++){
      float4 a4 = *(const float4*)&As[kk][ty*4];
      float4 b4 = *(const float4*)&Bs[kk][tx*4];
      acc[0][0] += a4.x*b4.x; acc[0][1] += a4.x*b4.y; acc[0][2] += a4.x*b4.z; acc[0][3] += a4.x*b4.w;
      acc[1][0] += a4.y*b4.x; acc[1][1] += a4.y*b4.y; acc[1][2] += a4.y*b4.z; acc[1][3] += a4.y*b4.w;
      acc[2][0] += a4.z*b4.x; acc[2][1] += a4.z*b4.y; acc[2][2] += a4.z*b4.z; acc[2][3] += a4.z*b4.w;
      acc[3][0] += a4.w*b4.x; acc[3][1] += a4.w*b4.y; acc[3][2] += a4.w*b4.z; acc[3][3] += a4.w*b4.w;
    }
    __syncthreads();
  }
  int r0 = rowBlk + ty*4, c0 = colBlk + tx*4;
  float bz[4];
  #pragma unroll
  for (int j = 0; j < 4; j++) bz[j] = bias[c0 + j];
  #pragma unroll
  for (int i = 0; i < 4; i++){
    int r = r0 + i;
    if (r < M){
      #pragma unroll
      for (int j = 0; j < 4; j++)
        Cf[(long)r*Nn + c0 + j] = acc[i][j] + bz[j];
    }
  }
}

// ---------------- kmax via MFMA (k slice of bf16 qkv) ----------------
__global__ __launch_bounds__(256) void kmax2_k(const unsigned short* __restrict__ qkvb,
    const unsigned short* __restrict__ projb, unsigned* __restrict__ kmaxb)
{
  __shared__ __attribute__((aligned(16))) unsigned short ks[64*40];
  __shared__ float red[4];
  int t = blockIdx.x, h = blockIdx.y, b = blockIdx.z;
  int tid = threadIdx.x, w = tid >> 6, lane = tid & 63;
  int fr = lane & 15, fq = lane >> 4, fk = fq*8;
  int n0 = t*64;
  {
    int tok = tid >> 2, d8 = (tid & 3)*8;
    int n = n0 + tok;
    bool vld = (n < N_);
    s8v kv8 = vld ? *(const s8v*)(qkvb + ((long)(b*N_ + n))*QS + 256 + h*DH + d8)
                  : (s8v){0,0,0,0,0,0,0,0};
    *(s8v*)&ks[tok*40 + d8] = kv8;
  }
  __syncthreads();
  s8v bk_ = *(s8v*)&ks[(w*16 + fr)*40 + fk];
  float mx = -INFINITY;
  int n_ = w*16 + fr;
  bool nv = (n0 + n_ < N_);
  #pragma unroll
  for (int mt = 0; mt < 7; mt++){
    s8v ap = *(const s8v*)(projb + (mt*16 + fr)*32 + fk);
    f4v z = (f4v){0.f,0.f,0.f,0.f};
    f4v xd = __builtin_amdgcn_mfma_f32_16x16x32_bf16(ap, bk_, z, 0, 0, 0);
    #pragma unroll
    for (int j = 0; j < 4; j++){
      int m = mt*16 + fq*4 + j;
      float v = (nv && m < M_) ? xd[j]*DN : -INFINITY;
      mx = fmaxf(mx, v);
    }
  }
  #pragma unroll
  for (int mk = 1; mk < 64; mk <<= 1) mx = fmaxf(mx, __shfl_xor(mx, mk));
  if (lane == 0) red[w] = mx;
  __syncthreads();
  if (tid == 0){
    float g = fmaxf(fmaxf(red[0], red[1]), fmaxf(red[2], red[3]));
    atomicMax(kmaxb, floatToOrdered(g));
  }
}

// ---------------- fused ctx via double MFMA (bf16 qkv) ----------------
__global__ __launch_bounds__(256) void fctx_k(const unsigned short* __restrict__ qkvb,
    const unsigned short* __restrict__ projb,
    const unsigned* __restrict__ kmaxb, float* __restrict__ partials)
{
  __shared__ __attribute__((aligned(16))) unsigned short ks[64*40];
  __shared__ __attribute__((aligned(16))) unsigned short vt[48*72];
  __shared__ __attribute__((aligned(16))) unsigned short kps[112*72];
  __shared__ float diags[64];
  int c = blockIdx.x, h = blockIdx.y, b = blockIdx.z;
  int tid = threadIdx.x, w = tid >> 6, lane = tid & 63;
  int fr = lane & 15, fq = lane >> 4, fk = fq*8;
  float kmax = orderedToFloat(kmaxb[0]);

  for (int i = tid; i < 15*72; i += 256) vt[33*72 + i] = 0;
  if (tid < 64) vt[32*72 + tid] = f2us(1.0f);

  s8v ap[7];
  #pragma unroll
  for (int mt = 0; mt < 7; mt++)
    ap[mt] = *(const s8v*)(projb + (mt*16 + fr)*32 + fk);

  int mt0 = w, mt1 = w + 4;
  f4v acc0[3], acc1[3];
  #pragma unroll
  for (int dt = 0; dt < 3; dt++){ acc0[dt] = (f4v){0.f,0.f,0.f,0.f}; acc1[dt] = (f4v){0.f,0.f,0.f,0.f}; }

  int stok = tid >> 2, sd8 = (tid & 3)*8;
  for (int t = c; t < NTILES; t += NC){
    int n0 = t*64;
    __syncthreads();
    {
      int n = n0 + stok;
      bool vld = (n < N_);
      long gb = ((long)(b*N_ + (vld ? n : 0)))*QS + h*DH + sd8;
      s8v kv8 = vld ? *(const s8v*)(qkvb + gb + 256) : (s8v){0,0,0,0,0,0,0,0};
      s8v vv8 = vld ? *(const s8v*)(qkvb + gb + 512) : (s8v){0,0,0,0,0,0,0,0};
      *(s8v*)&ks[stok*40 + sd8] = kv8;
      #pragma unroll
      for (int j = 0; j < 8; j++)
        vt[(sd8 + j)*72 + stok] = (unsigned short)vv8[j];
      float sq = 0.f;
      #pragma unroll
      for (int j = 0; j < 8; j++){
        float kx = us2f((unsigned short)kv8[j]);
        sq += kx*kx;
      }
      sq += __shfl_xor(sq, 1); sq += __shfl_xor(sq, 2);
      if ((tid & 3) == 0) diags[stok] = 0.5f * DN2 * sq;
    }
    __syncthreads();
    s8v bk_ = *(s8v*)&ks[(w*16 + fr)*40 + fk];
    int n_ = w*16 + fr;
    bool nv = (n0 + n_ < N_);
    float dgn = diags[n_];
    #pragma unroll
    for (int mt = 0; mt < 7; mt++){
      f4v z = (f4v){0.f,0.f,0.f,0.f};
      f4v xd = __builtin_amdgcn_mfma_f32_16x16x32_bf16(ap[mt], bk_, z, 0, 0, 0);
      #pragma unroll
      for (int j = 0; j < 4; j++){
        float kp = nv ? RATIO*(expf(xd[j]*DN - dgn - kmax) + 1e-3f) : 0.f;
        kps[(mt*16 + fq*4 + j)*72 + n_] = f2us(kp);
      }
    }
    __syncthreads();
    #pragma unroll
    for (int kst = 0; kst < 2; kst++){
      int ko = kst*32 + fk;
      s8v b0 = *(s8v*)&vt[( 0 + fr)*72 + ko];
      s8v b1 = *(s8v*)&vt[(16 + fr)*72 + ko];
      s8v b2 = *(s8v*)&vt[(32 + fr)*72 + ko];
      s8v a0 = *(s8v*)&kps[(mt0*16 + fr)*72 + ko];
      acc0[0] = __builtin_amdgcn_mfma_f32_16x16x32_bf16(a0, b0, acc0[0], 0, 0, 0);
      acc0[1] = __builtin_amdgcn_mfma_f32_16x16x32_bf16(a0, b1, acc0[1], 0, 0, 0);
      acc0[2] = __builtin_amdgcn_mfma_f32_16x16x32_bf16(a0, b2, acc0[2], 0, 0, 0);
      if (mt1 < 7){
        s8v a1 = *(s8v*)&kps[(mt1*16 + fr)*72 + ko];
        acc1[0] = __builtin_amdgcn_mfma_f32_16x16x32_bf16(a1, b0, acc1[0], 0, 0, 0);
        acc1[1] = __builtin_amdgcn_mfma_f32_16x16x32_bf16(a1, b1, acc1[1], 0, 0, 0);
        acc1[2] = __builtin_amdgcn_mfma_f32_16x16x32_bf16(a1, b2, acc1[2], 0, 0, 0);
      }
    }
  }
  long pb = ((long)c*64 + (b*H_ + h))*CTXE;
  #pragma unroll
  for (int dt = 0; dt < 3; dt++){
    int d = dt*16 + fr;
    if (d < 33){
      #pragma unroll
      for (int j = 0; j < 4; j++){
        int m0 = mt0*16 + fq*4 + j;
        if (m0 < M_) partials[pb + m0*33 + d] = acc0[dt][j];
        if (mt1 < 7){
          int m1 = mt1*16 + fq*4 + j;
          if (m1 < M_) partials[pb + m1*33 + d] = acc1[dt][j];
        }
      }
    }
  }
}

// ---------------- ctx partial reduce ----------------
__global__ __launch_bounds__(256) void ctxred2_k(const float* __restrict__ partials,
                                                 float* __restrict__ ctxf)
{
  int i = blockIdx.x*256 + threadIdx.x;
  if (i >= CTXN2) return;
  float s = 0.f;
  #pragma unroll
  for (int c = 0; c < NC; c++) s += partials[(long)c*CTXN2 + i];
  ctxf[i] = s;
}

// ---------------- attn v3: full-MFMA query side (bf16 qkv) ----------------
__global__ __launch_bounds__(256) void attn3_k(const unsigned short* __restrict__ qkvb,
    const float* __restrict__ ctxf, const unsigned short* __restrict__ projb,
    unsigned short* __restrict__ ob)
{
  __shared__ __attribute__((aligned(16))) unsigned short qs[64*40];
  __shared__ __attribute__((aligned(16))) unsigned short qps[64*136];
  __shared__ __attribute__((aligned(16))) unsigned short cst[48*136];
  __shared__ float diags[64];
  __shared__ float dens[64];
  int t = blockIdx.x, h = blockIdx.y, b = blockIdx.z;
  int tid = threadIdx.x, w = tid >> 6, lane = tid & 63;
  int fr = lane & 15, fq = lane >> 4, fk = fq*8;
  int n0 = t*64;
  long cbase = ((long)(b*H_ + h))*CTXE;

  for (int i = tid; i < 64*16; i += 256)
    qps[(i >> 4)*136 + 112 + (i & 15)] = 0;

  {
    int tok = tid >> 2, d8 = (tid & 3)*8;
    int n = n0 + tok;
    bool vld = (n < N_);
    s8v qv8 = vld ? *(const s8v*)(qkvb + ((long)(b*N_ + n))*QS + h*DH + d8)
                  : (s8v){0,0,0,0,0,0,0,0};
    *(s8v*)&qs[tok*40 + d8] = qv8;
    float sq = 0.f;
    #pragma unroll
    for (int j = 0; j < 8; j++){
      float qx = us2f((unsigned short)qv8[j]);
      sq += qx*qx;
    }
    sq += __shfl_xor(sq, 1); sq += __shfl_xor(sq, 2);
    if ((tid & 3) == 0) diags[tok] = 0.5f * DN2 * sq;
  }
  for (int i = tid; i < 48*128; i += 256){
    int d = i >> 7, m = i & 127;
    float v = (d < 33 && m < M_) ? ctxf[cbase + (long)m*33 + d] : 0.f;
    cst[d*136 + m] = f2us(v);
  }
  __syncthreads();

  s8v bq_ = *(s8v*)&qs[(w*16 + fr)*40 + fk];
  int n_ = w*16 + fr;
  bool nv = (n0 + n_ < N_);
  float dgn = diags[n_];
  f4v xdv[7];
  #pragma unroll
  for (int mt = 0; mt < 7; mt++){
    s8v ap = *(const s8v*)(projb + (mt*16 + fr)*32 + fk);
    f4v z = (f4v){0.f,0.f,0.f,0.f};
    xdv[mt] = __builtin_amdgcn_mfma_f32_16x16x32_bf16(ap, bq_, z, 0, 0, 0);
  }
  float mx = -INFINITY;
  #pragma unroll
  for (int mt = 0; mt < 7; mt++)
    #pragma unroll
    for (int j = 0; j < 4; j++){
      int m = mt*16 + fq*4 + j;
      if (m < M_) mx = fmaxf(mx, xdv[mt][j]*DN);
    }
  mx = fmaxf(mx, __shfl_xor(mx, 16));
  mx = fmaxf(mx, __shfl_xor(mx, 32));
  #pragma unroll
  for (int mt = 0; mt < 7; mt++)
    #pragma unroll
    for (int j = 0; j < 4; j++){
      int m = mt*16 + fq*4 + j;
      float qp = (nv && m < M_) ? RATIO*(expf(xdv[mt][j]*DN - dgn - mx) + 1e-3f) : 0.f;
      qps[n_*136 + m] = f2us(qp);
    }
  __syncthreads();

  f4v acc[3];
  acc[0] = (f4v){0,0,0,0}; acc[1] = (f4v){0,0,0,0}; acc[2] = (f4v){0,0,0,0};
  #pragma unroll
  for (int ks = 0; ks < 4; ks++){
    int ko = ks*32 + fk;
    s8v bqp = *(s8v*)&qps[(w*16 + fr)*136 + ko];
    #pragma unroll
    for (int dt = 0; dt < 3; dt++){
      s8v ac = *(s8v*)&cst[(dt*16 + fr)*136 + ko];
      acc[dt] = __builtin_amdgcn_mfma_f32_16x16x32_bf16(ac, bqp, acc[dt], 0, 0, 0);
    }
  }
  if (fq == 0) dens[n_] = acc[2][0];
  __syncthreads();
  float dinv = 1.0f / dens[n_];
  if (nv){
    long obase = ((long)(b*N_ + n0 + n_))*D_ + h*DH;
    #pragma unroll
    for (int dt = 0; dt < 2; dt++){
      ushort4 wv;
      wv.x = f2us(acc[dt][0]*dinv);
      wv.y = f2us(acc[dt][1]*dinv);
      wv.z = f2us(acc[dt][2]*dinv);
      wv.w = f2us(acc[dt][3]*dinv);
      *(ushort4*)(ob + obase + dt*16 + fq*4) = wv;
    }
  }
}

// ---------------- host ----------------
extern "C" void kernel_launch(void* const* d_in, const int* in_sizes, int n_in,
                              void* d_out, int out_size, void* d_ws, size_t ws_size,
                              hipStream_t stream)
{
  const float* expr = (const float*)d_in[0];
  const float* temb = (const float*)d_in[1];
  const float* cls  = (const float*)d_in[2];
  const float* ln1g = (const float*)d_in[3];
  const float* ln1b = (const float*)d_in[4];
  const float* Wq   = (const float*)d_in[5];
  const float* bq   = (const float*)d_in[6];
  const float* Wk   = (const float*)d_in[7];
  const float* bk   = (const float*)d_in[8];
  const float* Wv   = (const float*)d_in[9];
  const float* bv   = (const float*)d_in[10];
  const float* Wo   = (const float*)d_in[11];
  const float* bo   = (const float*)d_in[12];
  const float* ln2g = (const float*)d_in[13];
  const float* ln2b = (const float*)d_in[14];
  const float* W1   = (const float*)d_in[15];
  const float* b1   = (const float*)d_in[16];
  const float* W2   = (const float*)d_in[17];
  const float* b2   = (const float*)d_in[18];
  const float* proj = (const float*)d_in[19];
  const float* Wp   = (const float*)d_in[20];
  const float* bp   = (const float*)d_in[21];
  (void)in_sizes; (void)n_in; (void)out_size; (void)ws_size;

  char* w = (char*)d_ws;
  size_t off = 0;
  auto alloc = [&](size_t bytes) -> char* {
    char* p = w + off;
    off = (off + bytes + 255) & ~(size_t)255;
    return p;
  };
  float*    selected = (float*)alloc((size_t)B_*KSEL*4);
  float*    bsum     = (float*)alloc(B_*4);
  float*    bv0      = (float*)alloc(B_*4);
  float*    emaxp    = (float*)alloc(4);
  unsigned* kmaxb    = (unsigned*)alloc(DEPTH_*4);
  float*    ctxf     = (float*)alloc((size_t)CTXN2*4);
  float*          x  = (float*)alloc((size_t)BN_*D_*4);
  unsigned short* h  = (unsigned short*)alloc((size_t)BN_*D_*2);
  unsigned short* qkvb = (unsigned short*)alloc((size_t)BN_*DFF_*2);  // qkv bf16 (stride QS); ffi aliases (stride 1024)
  unsigned short* Wqkvt = (unsigned short*)alloc((size_t)DEPTH_*QS*D_*2);
  unsigned short* Wot = (unsigned short*)alloc((size_t)DEPTH_*D_*D_*2);
  unsigned short* W1t = (unsigned short*)alloc((size_t)DEPTH_*D_*DFF_*2);
  unsigned short* W2t = (unsigned short*)alloc((size_t)DEPTH_*DFF_*D_*2);
  unsigned short* projb = (unsigned short*)alloc((size_t)DEPTH_*112*32*2);
  float*    bqkv     = (float*)alloc((size_t)DEPTH_*QS*4);
  unsigned short* ffi = qkvb;                  // bf16 [BN][1024] aliases qkv (dead during FFN)
  float*     partials = (float*)h;             // NC*CTXN2*4 = 7.44 MB <= h (8.39 MB)

  wcvt_k<<<dim3(8, 8, DEPTH_),  256, 0, stream>>>(Wq, (long)D_*D_, Wqkvt + 0,      (long)QS*D_, D_, D_);
  wcvt_k<<<dim3(8, 8, DEPTH_),  256, 0, stream>>>(Wk, (long)D_*D_, Wqkvt + 256*D_, (long)QS*D_, D_, D_);
  wcvt_k<<<dim3(8, 8, DEPTH_),  256, 0, stream>>>(Wv, (long)D_*D_, Wqkvt + 512*D_, (long)QS*D_, D_, D_);
  wcvt_k<<<dim3(8, 8, DEPTH_),  256, 0, stream>>>(Wo, (long)D_*D_,   Wot, (long)D_*D_,   D_, D_);
  wcvt_k<<<dim3(32, 8, DEPTH_), 256, 0, stream>>>(W1, (long)D_*DFF_, W1t, (long)D_*DFF_, D_, DFF_);
  wcvt_k<<<dim3(8, 32, DEPTH_), 256, 0, stream>>>(W2, (long)DFF_*D_, W2t, (long)DFF_*D_, DFF_, D_);
  pcvt_k<<<DEPTH_, 256, 0, stream>>>(proj, projb, kmaxb);
  bcat_k<<<DEPTH_, 256, 0, stream>>>(bq, bk, bv, bqkv);

  topk_k<<<B_, 1024, 0, stream>>>(expr, selected);
  nsum_k<<<B_, 256, 0, stream>>>(selected, bsum, bv0);
  emax_k<<<1, 64, 0, stream>>>(bsum, bv0, emaxp);
  embed_k<<<BN_/4, 256, 0, stream>>>(selected, bsum, emaxp, temb, cls, x);

  for (int L = 0; L < DEPTH_; L++){
    const unsigned short* pjb = projb + (size_t)L*112*32;
    ln_k<<<BN_/4, 256, 0, stream>>>(x, h, ln1g + L*D_, ln1b + L*D_);
    bgemm_k<0,0,1><<<dim3(6,129), 256, 0, stream>>>(h, D_, Wqkvt + (size_t)L*QS*D_, bqkv + (size_t)L*QS, nullptr, nullptr, qkvb, BN_, QS, D_);
    kmax2_k<<<dim3(NTILES, H_, B_), 256, 0, stream>>>(qkvb, pjb, kmaxb + L);
    fctx_k<<<dim3(NC, H_, B_), 256, 0, stream>>>(qkvb, pjb, kmaxb + L, partials);
    ctxred2_k<<<(CTXN2 + 255)/256, 256, 0, stream>>>(partials, ctxf);
    attn3_k<<<dim3(NTILES, H_, B_), 256, 0, stream>>>(qkvb, ctxf, pjb, h);   // o -> h (bf16)
    bgemm_k<0,1,0><<<dim3(2,129), 256, 0, stream>>>(h, D_, Wot + (size_t)L*D_*D_, bo + L*D_, x, x, nullptr, BN_, D_, D_);
    ln_k<<<BN_/4, 256, 0, stream>>>(x, h, ln2g + L*D_, ln2b + L*D_);
    bgemm_k<1,0,1><<<dim3(8,129), 256, 0, stream>>>(h, D_, W1t + (size_t)L*D_*DFF_, b1 + L*DFF_, nullptr, nullptr, ffi, BN_, DFF_, D_);
    bgemm_k<0,1,0><<<dim3(2,129), 256, 0, stream>>>(ffi, DFF_, W2t + (size_t)L*DFF_*D_, b2 + L*D_, x, x, nullptr, BN_, D_, DFF_);
  }
  gemm_k<<<dim3(1,4), 256, 0, stream>>>(x, (long)N_*D_, Wp, D_, bp,
                                        (float*)d_out, B_, D_, D_);
}